// Round 14
// baseline (276.660 us; speedup 1.0000x reference)
//
#include <hip/hip_runtime.h>
#include <math.h>

#define BB 8
#define LL 512
#define CC 862
#define PP 96
#define DD 128
#define II 256
#define NHH 4
#define DHH 64
#define SS 862
#define BC (BB*CC)
#define VTS 864          // padded V^T row stride
#define NITEMS2 896      // attn work items = 28 pairs * 32 bh

typedef unsigned short u16;
using bf16x8 = __attribute__((ext_vector_type(8))) short;
using f32x4  = __attribute__((ext_vector_type(4))) float;

__device__ __forceinline__ u16 f2b(float x) {
  union { float f; unsigned u; } v; v.f = x;
  unsigned r = v.u + 0x7FFF + ((v.u >> 16) & 1);
  return (u16)(r >> 16);
}
__device__ __forceinline__ float b2f(u16 h) {
  union { unsigned u; float f; } v; v.u = ((unsigned)h) << 16;
  return v.f;
}

// chunk-XOR swizzle: u16 offset of 16B-chunk c within row r of a [64][64] tile
#define XCH(r, c) ((((c) ^ ((r) & 7)) << 3))

// ---------------------------------------------------------------------------
// merged weight-prep kernel (tc + gcomb + hbias + gprep)
// ---------------------------------------------------------------------------
__global__ __launch_bounds__(256) void prep_kernel(
    const float* __restrict__ Wup, const float* __restrict__ Wq,
    const float* __restrict__ Wk, const float* __restrict__ Wv,
    const float* __restrict__ Wdn, const float* __restrict__ Ws,
    const float* __restrict__ Wt, const float* __restrict__ Wp1,
    const float* __restrict__ bs, const float* __restrict__ bt,
    const float* __restrict__ bp1, const float* __restrict__ Wi,
    const float* __restrict__ Wf,
    u16* __restrict__ WupT, u16* __restrict__ WqkT,
    u16* __restrict__ WvT, u16* __restrict__ WdnT,
    u16* __restrict__ BTh, float* __restrict__ hbias,
    float* __restrict__ Gc, float* __restrict__ Gv)
{
  int gb = blockIdx.x;
  int tid = threadIdx.x;
  if (gb < 640) {
    int bx = gb & 63, by = gb >> 6;
    const float* src; u16* dst; int R, Cn; float scl = 1.f;
    switch (by) {
      case 0: src = Wup;          dst = WupT;            R = 128; Cn = 512; break;
      case 1: src = Wup + 65536;  dst = WupT + 65536;    R = 128; Cn = 512; break;
      case 2: src = Wq;           dst = WqkT;            R = 256; Cn = 256; scl = 0.125f; break;
      case 3: src = Wk;           dst = WqkT + 65536;    R = 256; Cn = 256; break;
      case 4: src = Wq + 65536;   dst = WqkT + 131072;   R = 256; Cn = 256; scl = 0.125f; break;
      case 5: src = Wk + 65536;   dst = WqkT + 196608;   R = 256; Cn = 256; break;
      case 6: src = Wv;           dst = WvT;             R = 256; Cn = 256; break;
      case 7: src = Wv + 65536;   dst = WvT + 65536;     R = 256; Cn = 256; break;
      case 8: src = Wdn;          dst = WdnT;            R = 256; Cn = 128; break;
      default: src = Wdn + 32768; dst = WdnT + 32768;    R = 256; Cn = 128; break;
    }
    int tpr = Cn >> 5;
    int tx = bx % tpr, ty_ = bx / tpr;
    if (ty_ >= (R >> 5)) return;
    __shared__ float t[32][33];
    int r0 = ty_ * 32, c0 = tx * 32;
    int cr = tid >> 5, cc = tid & 31;
    #pragma unroll
    for (int rr = 0; rr < 4; ++rr)
      t[cr + rr * 8][cc] = src[(size_t)(r0 + cr + rr * 8) * Cn + c0 + cc];
    __syncthreads();
    #pragma unroll
    for (int rr = 0; rr < 4; ++rr)
      dst[(size_t)(c0 + cr + rr * 8) * R + r0 + cc] = f2b(t[cc][cr + rr * 8] * scl);
  } else if (gb < 1152) {
    int i2 = gb - 640;
    int d = i2 & 127, byy = i2 >> 7;
    int lp = byy * 256 + tid;
    const float* wp = Wp1 + d * 96;
    float acc = 0.f;
    if (lp < 512) {
      for (int p = 0; p < 96; ++p) acc += Ws[p * 512 + lp] * wp[p];
    } else {
      int l = lp - 512;
      for (int p = 0; p < 96; ++p) acc += (Wt[p * 512 + l] - Ws[p * 512 + l]) * wp[p];
    }
    BTh[(size_t)d * 1024 + lp] = f2b(acc);
  } else if (gb == 1152) {
    if (tid < 128) {
      float acc = bp1[tid];
      for (int p = 0; p < 96; ++p) acc += (bs[p] + bt[p]) * Wp1[tid * 96 + p];
      hbias[tid] = acc;
    }
  } else {
    int i2 = gb - 1153;
    int i = i2 & 255, blk = i2 >> 8;
    int j = tid;
    float wq = Wq[(size_t)blk * 65536 + i * 256 + j];
    float wk = Wk[(size_t)blk * 65536 + i * 256 + j];
    float wv = Wv[(size_t)blk * 65536 + i * 256 + j];
    const float* wi = Wi + blk * 3072;
    const float* wf = Wf + blk * 3072;
    float pc[8], pv[8];
    #pragma unroll
    for (int o = 0; o < 4; ++o) {
      pc[o]     = wq * wi[j * 4 + o] + wk * wi[(256 + j) * 4 + o];
      pc[4 + o] = wq * wf[j * 4 + o] + wk * wf[(256 + j) * 4 + o];
      pv[o]     = wv * wi[(512 + j) * 4 + o];
      pv[4 + o] = wv * wf[(512 + j) * 4 + o];
    }
    #pragma unroll
    for (int o = 0; o < 8; ++o)
      #pragma unroll
      for (int d = 1; d < 64; d <<= 1) {
        pc[o] += __shfl_xor(pc[o], d);
        pv[o] += __shfl_xor(pv[o], d);
      }
    __shared__ float red[4][16];
    int wv_ = j >> 6, lane = j & 63;
    if (lane == 0) {
      #pragma unroll
      for (int o = 0; o < 8; ++o) { red[wv_][o] = pc[o]; red[wv_][8 + o] = pv[o]; }
    }
    __syncthreads();
    if (j < 16) {
      float s4 = red[0][j] + red[1][j] + red[2][j] + red[3][j];
      if (j < 8) Gc[((size_t)blk * 256 + i) * 8 + j] = s4;
      else       Gv[((size_t)blk * 256 + i) * 8 + j - 8] = s4;
    }
  }
}

// ---------------------------------------------------------------------------
// transpose + moving-average -> bf16 A_head [6896][1024] — coalesced
// ---------------------------------------------------------------------------
__global__ __launch_bounds__(256) void ta_kernel(
    const float* __restrict__ xe, u16* __restrict__ Ah)
{
  __shared__ float xel[16][545];
  __shared__ float mml[16][517];
  int tid = threadIdx.x;
  int b = blockIdx.x / 54, ct = blockIdx.x % 54;
  int c0 = ct * 16;
  for (int j = 0; j < 34; ++j) {
    int idx = tid + j * 256;
    if (idx < 8576) {
      int li = idx >> 4, cc = idx & 15;
      int l = li - 12; l = l < 0 ? 0 : (l > 511 ? 511 : l);
      int c = c0 + cc; if (c > 861) c = 861;
      xel[cc][li] = xe[((size_t)b * LL + l) * CC + c];
    }
  }
  __syncthreads();
  {
    int cl = tid & 15;
    int l0 = (tid >> 4) * 32;
    float win = 0.f;
    #pragma unroll 5
    for (int o = 0; o < 25; ++o) win += xel[cl][l0 + o];
    mml[cl][l0] = win * (1.f / 25.f);
    for (int i = 1; i < 32; ++i) {
      win += xel[cl][l0 + 24 + i] - xel[cl][l0 + i - 1];
      mml[cl][l0 + i] = win * (1.f / 25.f);
    }
  }
  __syncthreads();
  for (int j = 0; j < 32; ++j) {
    int idx = tid + j * 256;
    int cr = idx >> 9, l = idx & 511;
    int c = c0 + cr;
    if (c < CC) {
      size_t base = ((size_t)b * CC + c) * 1024;
      Ah[base + l] = f2b(xel[cr][12 + l]);
      Ah[base + 512 + l] = f2b(mml[cr][l]);
    }
  }
}

// ---------------------------------------------------------------------------
// bf16 MFMA GEMM core loop as a device function (BK=64, 64x64 tile)
// ---------------------------------------------------------------------------
__device__ __forceinline__ void gemm_core(
    const u16* __restrict__ A, int lda, const u16* __restrict__ BT, int ldbt,
    int M, int K, int m0, int n0, int tid,
    u16 (*As0)[40], u16 (*As1)[40], u16 (*Bs0)[40], u16 (*Bs1)[40],
    f32x4 acc[2][2])
{
  int wv = tid >> 6, lane = tid & 63;
  int wr = wv >> 1, wc = wv & 1;
  int lrow = lane & 15, lk = lane >> 4;
  int arow = tid >> 2, aseg = tid & 3;
  for (int k0 = 0; k0 < K; k0 += 64) {
    int gm = m0 + arow; if (gm > M - 1) gm = M - 1;
    const u16* ap = &A[(size_t)gm * lda + k0 + aseg * 8];
    *(uint4*)&As0[arow][aseg * 8] = *(const uint4*)ap;
    *(uint4*)&As1[arow][aseg * 8] = *(const uint4*)(ap + 32);
    const u16* bp = &BT[(size_t)(n0 + arow) * ldbt + k0 + aseg * 8];
    *(uint4*)&Bs0[arow][aseg * 8] = *(const uint4*)bp;
    *(uint4*)&Bs1[arow][aseg * 8] = *(const uint4*)(bp + 32);
    __syncthreads();
    bf16x8 af[2], bfr[2];
    #pragma unroll
    for (int fm = 0; fm < 2; ++fm) af[fm] = *(const bf16x8*)&As0[wr * 32 + fm * 16 + lrow][lk * 8];
    #pragma unroll
    for (int fn = 0; fn < 2; ++fn) bfr[fn] = *(const bf16x8*)&Bs0[wc * 32 + fn * 16 + lrow][lk * 8];
    #pragma unroll
    for (int fm = 0; fm < 2; ++fm)
      #pragma unroll
      for (int fn = 0; fn < 2; ++fn)
        acc[fm][fn] = __builtin_amdgcn_mfma_f32_16x16x32_bf16(af[fm], bfr[fn], acc[fm][fn], 0, 0, 0);
    #pragma unroll
    for (int fm = 0; fm < 2; ++fm) af[fm] = *(const bf16x8*)&As1[wr * 32 + fm * 16 + lrow][lk * 8];
    #pragma unroll
    for (int fn = 0; fn < 2; ++fn) bfr[fn] = *(const bf16x8*)&Bs1[wc * 32 + fn * 16 + lrow][lk * 8];
    #pragma unroll
    for (int fm = 0; fm < 2; ++fm)
      #pragma unroll
      for (int fn = 0; fn < 2; ++fn)
        acc[fm][fn] = __builtin_amdgcn_mfma_f32_16x16x32_bf16(af[fm], bfr[fn], acc[fm][fn], 0, 0, 0);
    __syncthreads();
  }
}

// ---------------------------------------------------------------------------
// generic 64x64 GEMM kernel. MODE 0: C=AB+bias; 1: C+=AB+bias
// ---------------------------------------------------------------------------
template<int MODE>
__global__ __launch_bounds__(256) void gemm_bf16(
    const u16* __restrict__ A, int lda,
    const u16* __restrict__ BT, int ldbt,
    float* __restrict__ C, int ldc, const float* __restrict__ bias,
    int M, int N, int K)
{
  __shared__ u16 As0[64][40], As1[64][40];
  __shared__ u16 Bs0[64][40], Bs1[64][40];
  int tid = threadIdx.x;
  int m0 = blockIdx.y * 64, n0 = blockIdx.x * 64;
  f32x4 acc[2][2] = {};
  gemm_core(A, lda, BT, ldbt, M, K, m0, n0, tid, As0, As1, Bs0, Bs1, acc);
  int wv = tid >> 6, lane = tid & 63;
  int wr = wv >> 1, wc = wv & 1;
  int lrow = lane & 15, lk = lane >> 4;
  #pragma unroll
  for (int fm = 0; fm < 2; ++fm) {
    #pragma unroll
    for (int fn = 0; fn < 2; ++fn) {
      int col = n0 + wc * 32 + fn * 16 + lrow;
      #pragma unroll
      for (int r = 0; r < 4; ++r) {
        int row = m0 + wr * 32 + fm * 16 + lk * 4 + r;
        if (row < M) {
          float vv = acc[fm][fn][r];
          if (bias) vv += bias[col];
          float* cp = &C[(size_t)row * ldc + col];
          if (MODE == 1) vv += *cp;
          *cp = vv;
        }
      }
    }
  }
}

// ---------------------------------------------------------------------------
// fused GEMM(N=128) + residual + row-LayerNorm.  32x128 tile, 216 blocks.
// MODE 0: x = A@BT + bias; 1: x += A@BT + bias.  Then LN(x) row-wise:
// OUTF32 0 -> y_bf (bf16, gain g); 1 -> y (fp32, gain g).
// ---------------------------------------------------------------------------
template<int MODE, int OUTF32>
__global__ __launch_bounds__(256) void gemm_ln(
    const u16* __restrict__ A, int lda,
    const u16* __restrict__ BT, int ldbt,
    float* __restrict__ x, const float* __restrict__ bias,
    const float* __restrict__ g,
    float* __restrict__ y, u16* __restrict__ y_bf,
    int M, int K)
{
  __shared__ u16 As0[32][40], As1[32][40];
  __shared__ u16 Bs0[128][40], Bs1[128][40];
  __shared__ float red_s[32][2], red_q[32][2];
  int tid = threadIdx.x;
  int m0 = blockIdx.x * 32;
  int wv = tid >> 6, lane = tid & 63;
  int wr = wv >> 1, wc = wv & 1;       // wr: row half (16), wc: col half (64)
  int lrow = lane & 15, lk = lane >> 4;
  f32x4 acc[4] = {};
  int arow = tid >> 3, aseg7 = tid & 7;        // A: 32 rows x 8 (4+4) segs
  int brow = tid >> 1, bhalf = tid & 1;        // B: 128 rows x 2 seg-pairs
  for (int k0 = 0; k0 < K; k0 += 64) {
    int gm = m0 + arow; if (gm > M - 1) gm = M - 1;
    const u16* ap = &A[(size_t)gm * lda + k0];
    if (aseg7 < 4) *(uint4*)&As0[arow][aseg7 * 8] = *(const uint4*)(ap + aseg7 * 8);
    else           *(uint4*)&As1[arow][(aseg7 - 4) * 8] = *(const uint4*)(ap + 32 + (aseg7 - 4) * 8);
    const u16* bp = &BT[(size_t)brow * ldbt + k0];
    #pragma unroll
    for (int j = 0; j < 2; ++j) {
      int seg = bhalf * 2 + j;
      *(uint4*)&Bs0[brow][seg * 8] = *(const uint4*)(bp + seg * 8);
      *(uint4*)&Bs1[brow][seg * 8] = *(const uint4*)(bp + 32 + seg * 8);
    }
    __syncthreads();
    bf16x8 af, bfr[4];
    af = *(const bf16x8*)&As0[wr * 16 + lrow][lk * 8];
    #pragma unroll
    for (int fn = 0; fn < 4; ++fn) bfr[fn] = *(const bf16x8*)&Bs0[wc * 64 + fn * 16 + lrow][lk * 8];
    #pragma unroll
    for (int fn = 0; fn < 4; ++fn)
      acc[fn] = __builtin_amdgcn_mfma_f32_16x16x32_bf16(af, bfr[fn], acc[fn], 0, 0, 0);
    af = *(const bf16x8*)&As1[wr * 16 + lrow][lk * 8];
    #pragma unroll
    for (int fn = 0; fn < 4; ++fn) bfr[fn] = *(const bf16x8*)&Bs1[wc * 64 + fn * 16 + lrow][lk * 8];
    #pragma unroll
    for (int fn = 0; fn < 4; ++fn)
      acc[fn] = __builtin_amdgcn_mfma_f32_16x16x32_bf16(af, bfr[fn], acc[fn], 0, 0, 0);
    __syncthreads();
  }
  // epilogue: bias + residual, fp32 x write, row sums
  #pragma unroll
  for (int r = 0; r < 4; ++r) {
    int lrid = wr * 16 + lk * 4 + r;
    int grow = m0 + lrid;
    float sr = 0.f, sq = 0.f;
    #pragma unroll
    for (int fn = 0; fn < 4; ++fn) {
      int col = wc * 64 + fn * 16 + lrow;
      float vv = acc[fn][r] + bias[col];
      if (MODE == 1) vv += x[(size_t)grow * DD + col];
      acc[fn][r] = vv;
      if (grow < M) x[(size_t)grow * DD + col] = vv;
      sr += vv; sq += vv * vv;
    }
    sr += __shfl_xor(sr, 1); sq += __shfl_xor(sq, 1);
    sr += __shfl_xor(sr, 2); sq += __shfl_xor(sq, 2);
    sr += __shfl_xor(sr, 4); sq += __shfl_xor(sq, 4);
    sr += __shfl_xor(sr, 8); sq += __shfl_xor(sq, 8);
    if (lrow == 0) { red_s[lrid][wc] = sr; red_q[lrid][wc] = sq; }
  }
  __syncthreads();
  #pragma unroll
  for (int r = 0; r < 4; ++r) {
    int lrid = wr * 16 + lk * 4 + r;
    int grow = m0 + lrid;
    if (grow >= M) continue;
    float s = red_s[lrid][0] + red_s[lrid][1];
    float q = red_q[lrid][0] + red_q[lrid][1];
    float mean = s * (1.f / 128.f);
    float var = q * (1.f / 128.f) - mean * mean;
    float rr = rsqrtf(var + 1e-5f);
    #pragma unroll
    for (int fn = 0; fn < 4; ++fn) {
      int col = wc * 64 + fn * 16 + lrow;
      float out = (acc[fn][r] - mean) * rr * g[col];
      if (OUTF32) y[(size_t)grow * DD + col] = out;
      else        y_bf[(size_t)grow * DD + col] = f2b(out);
    }
  }
}

// ---------------------------------------------------------------------------
// merged qk+v GEMM: blockIdx.x<8 -> qk (split->qkh/qkl, ldc=512);
// else -> v (split->transposed vhT/vlT).  Rows >= BC skipped (grid overshoot).
// ---------------------------------------------------------------------------
__global__ __launch_bounds__(256) void qkv_kernel(
    const u16* __restrict__ xc_bf, const u16* __restrict__ xin_bf,
    const u16* __restrict__ WqkT, const u16* __restrict__ WvT,
    u16* __restrict__ qkh, u16* __restrict__ qkl,
    u16* __restrict__ vhT, u16* __restrict__ vlT)
{
  __shared__ u16 As0[64][40], As1[64][40];
  __shared__ u16 Bs0[64][40], Bs1[64][40];
  int tid = threadIdx.x;
  int m0 = blockIdx.y * 64;
  bool is_qk = blockIdx.x < 8;
  int n0 = (is_qk ? blockIdx.x : blockIdx.x - 8) * 64;
  const u16* A  = is_qk ? xc_bf : xin_bf;
  const u16* BT = is_qk ? WqkT : WvT;
  f32x4 acc[2][2] = {};
  gemm_core(A, 256, BT, 256, BC, 256, m0, n0, tid, As0, As1, Bs0, Bs1, acc);
  int wv = tid >> 6, lane = tid & 63;
  int wr = wv >> 1, wc = wv & 1;
  int lrow = lane & 15, lk = lane >> 4;
  #pragma unroll
  for (int fm = 0; fm < 2; ++fm) {
    #pragma unroll
    for (int fn = 0; fn < 2; ++fn) {
      int col = n0 + wc * 32 + fn * 16 + lrow;
      int rbase = m0 + wr * 32 + fm * 16 + lk * 4;
      if (is_qk) {
        #pragma unroll
        for (int r = 0; r < 4; ++r) {
          int row = rbase + r;
          if (row < BC) {
            float vv = acc[fm][fn][r];
            u16 hi = f2b(vv);
            u16 lo = f2b(vv - b2f(hi));
            qkh[(size_t)row * 512 + col] = hi;
            qkl[(size_t)row * 512 + col] = lo;
          }
        }
      } else {
        u16 hi4[4], lo4[4];
        #pragma unroll
        for (int r = 0; r < 4; ++r) {
          float vv = acc[fm][fn][r];
          hi4[r] = f2b(vv);
          lo4[r] = f2b(vv - b2f(hi4[r]));
        }
        int bb0 = rbase / SS, s0_ = rbase - bb0 * SS;
        int bb3 = (rbase + 3) / SS;
        if (bb0 == bb3 && rbase + 3 < BC) {   // s0_ always even (SS=862)
          size_t o = ((size_t)bb0 * II + col) * VTS + s0_;
          *(unsigned*)&vhT[o]     = (unsigned)hi4[0] | ((unsigned)hi4[1] << 16);
          *(unsigned*)&vhT[o + 2] = (unsigned)hi4[2] | ((unsigned)hi4[3] << 16);
          *(unsigned*)&vlT[o]     = (unsigned)lo4[0] | ((unsigned)lo4[1] << 16);
          *(unsigned*)&vlT[o + 2] = (unsigned)lo4[2] | ((unsigned)lo4[3] << 16);
        } else {
          #pragma unroll
          for (int r = 0; r < 4; ++r) {
            int row = rbase + r;
            if (row < BC) {
              int bb = row / SS, s = row - bb * SS;
              size_t o = ((size_t)bb * II + col) * VTS + s;
              vhT[o] = hi4[r];
              vlT[o] = lo4[r];
            }
          }
        }
      }
    }
  }
}

// ---------------------------------------------------------------------------
// causal conv (k=4) + SiLU + fused gate preacts (via Gc/Gv)
// ---------------------------------------------------------------------------
__global__ __launch_bounds__(256) void conv_gates_kernel(
    const float* __restrict__ up, const float* __restrict__ Wc,
    const float* __restrict__ bc, const float* __restrict__ Gc,
    const float* __restrict__ Gv, const float* __restrict__ bi,
    const float* __restrict__ bfp,
    float* __restrict__ xc, u16* __restrict__ xc_bf, u16* __restrict__ xin_bf,
    float* __restrict__ ig, float* __restrict__ fg)
{
  __shared__ float red[4][8];
  int row = blockIdx.x;
  int i = threadIdx.x;
  int b = row / SS, s = row - b * SS;
  float acc = bc[i];
  float xin = 0.f;
  #pragma unroll
  for (int w2 = 0; w2 < 4; ++w2) {
    int sp = s - 3 + w2;
    if (sp >= 0) {
      float uv = up[((size_t)b * SS + sp) * 512 + i];
      acc += uv * Wc[w2 * 256 + i];
      if (w2 == 3) xin = uv;
    }
  }
  float sg = 1.f / (1.f + __expf(-acc));
  float val = acc * sg;
  xc[(size_t)row * II + i] = val;
  xc_bf[(size_t)row * II + i] = f2b(val);
  xin_bf[(size_t)row * II + i] = f2b(xin);
  float p[8];
  const float* gci = &Gc[i * 8];
  const float* gvi = &Gv[i * 8];
  #pragma unroll
  for (int o = 0; o < 8; ++o) p[o] = val * gci[o] + xin * gvi[o];
  #pragma unroll
  for (int o = 0; o < 8; ++o)
    #pragma unroll
    for (int d = 1; d < 64; d <<= 1) p[o] += __shfl_xor(p[o], d);
  int wv = i >> 6, lane = i & 63;
  if (lane == 0) {
    #pragma unroll
    for (int o = 0; o < 8; ++o) red[wv][o] = p[o];
  }
  __syncthreads();
  if (i < 8) {
    float sum = red[0][i] + red[1][i] + red[2][i] + red[3][i];
    if (i < 4) ig[((size_t)b * NHH + i) * SS + s] = sum + bi[i];
    else       fg[((size_t)b * NHH + i - 4) * SS + s] = sum + bfp[i - 4];
  }
}

// ---------------------------------------------------------------------------
// per-(b,h) scan
// ---------------------------------------------------------------------------
__device__ __forceinline__ float logsig(float x) {
  return fminf(x, 0.f) - log1pf(__expf(-fabsf(x)));
}

__global__ __launch_bounds__(64) void scan_kernel(
    const float* __restrict__ fg, const float* __restrict__ ig,
    float* __restrict__ cumf, float* __restrict__ aa, float* __restrict__ MMb)
{
  int bh = blockIdx.x;
  int lane = threadIdx.x;
  const float* f = fg + (size_t)bh * SS;
  const float* g = ig + (size_t)bh * SS;
  int s0 = lane * 14, s1 = s0 + 14; if (s1 > SS) s1 = SS;
  float loc = 0.f;
  for (int s = s0; s < s1; ++s) loc += logsig(f[s]);
  float v = loc;
  #pragma unroll
  for (int d = 1; d < 64; d <<= 1) { float o = __shfl_up(v, d); if (lane >= d) v += o; }
  float run = v - loc;
  float lmax = -1e30f;
  for (int s = s0; s < s1; ++s) {
    run += logsig(f[s]);
    cumf[(size_t)bh * SS + s] = run;
    float a = g[s] - run;
    aa[(size_t)bh * SS + s] = a;
    lmax = fmaxf(lmax, a);
  }
  float mv = lmax;
  #pragma unroll
  for (int d = 1; d < 64; d <<= 1) { float o = __shfl_up(mv, d); if (lane >= d) mv = fmaxf(mv, o); }
  float em = __shfl_up(mv, 1);
  if (lane == 0) em = -1e30f;
  float runm = em;
  for (int s = s0; s < s1; ++s) {
    runm = fmaxf(runm, aa[(size_t)bh * SS + s]);
    MMb[(size_t)bh * SS + s] = runm;
  }
}

// ---------------------------------------------------------------------------
// masked decay attention — split-precision MFMA, register-prefetch, 2-way
// s-split partials, W-overlay on K LDS tiles (4 barriers/tile).
// ---------------------------------------------------------------------------
__global__ __launch_bounds__(256) void attn_kernel(
    const u16* __restrict__ qkh, const u16* __restrict__ qkl,
    const u16* __restrict__ vhT, const u16* __restrict__ vlT,
    const float* __restrict__ aab, const float* __restrict__ MMb,
    float* __restrict__ pacc, float* __restrict__ pw)
{
  __shared__ u16 KWh[64][64], KWl[64][64];  // K during QK^T, then W for PV
  __shared__ u16 Vh[64][64], Vl[64][64];    // [d][s]
  __shared__ float a_lds[64];
  int tid = threadIdx.x;
  int wv = tid >> 6, lane = tid & 63;
  int lr = lane & 15, lg = lane >> 4;
  int item = blockIdx.x;
  int pp = item >> 5;                     // 0..27, heavy-first
  int tb = 13 - (pp >> 1);
  int part = pp & 1;
  int h = item & 3, b = (item >> 2) & 7;
  int t0 = tb * 64;
  int nt = tb + 1;
  int nt0 = (nt + 1) >> 1;
  int st_begin = part ? nt0 : 0;
  int st_end   = part ? nt : nt0;
  const float* aabh = aab + ((size_t)b * NHH + h) * SS;
  const float* Mbh  = MMb + ((size_t)b * NHH + h) * SS;

  int tq = t0 + wv * 16 + lr; if (tq > SS - 1) tq = SS - 1;
  const u16* qrow_h = qkh + ((size_t)b * SS + tq) * 512 + h * 64;
  const u16* qrow_l = qkl + ((size_t)b * SS + tq) * 512 + h * 64;
  bf16x8 qh0 = *(const bf16x8*)(qrow_h + lg * 8);
  bf16x8 qh1 = *(const bf16x8*)(qrow_h + 32 + lg * 8);
  bf16x8 ql0 = *(const bf16x8*)(qrow_l + lg * 8);
  bf16x8 ql1 = *(const bf16x8*)(qrow_l + 32 + lg * 8);

  float Mt[4];
  #pragma unroll
  for (int r = 0; r < 4; ++r) {
    int t = t0 + wv * 16 + lg * 4 + r; int tc = t < SS ? t : SS - 1;
    Mt[r] = Mbh[tc];
  }

  int row = tid >> 2, seg = tid & 3;
  const u16* vrow_h = vhT + ((size_t)(b * II + h * 64 + row)) * VTS + seg * 16;
  const u16* vrow_l = vlT + ((size_t)(b * II + h * 64 + row)) * VTS + seg * 16;

  f32x4 hacc[4] = {};
  float wsum[4] = {0.f, 0.f, 0.f, 0.f};

  uint4 rk0, rk1, rk2, rk3, rv0, rv1, rv2, rv3;
  float ra = -1e30f;
  if (st_begin < st_end) {
    int sg = st_begin * 64 + row;
    int sc = sg < SS ? sg : SS - 1;
    const u16* kp  = qkh + ((size_t)b * SS + sc) * 512 + 256 + h * 64 + seg * 16;
    const u16* klp = qkl + ((size_t)b * SS + sc) * 512 + 256 + h * 64 + seg * 16;
    rk0 = *(const uint4*)kp;  rk1 = *(const uint4*)(kp + 8);
    rk2 = *(const uint4*)klp; rk3 = *(const uint4*)(klp + 8);
    int sn = st_begin * 64;
    rv0 = *(const uint4*)(vrow_h + sn); rv1 = *(const uint4*)(vrow_h + sn + 8);
    rv2 = *(const uint4*)(vrow_l + sn); rv3 = *(const uint4*)(vrow_l + sn + 8);
    if (tid < 64) ra = (sn + tid < SS) ? aabh[sn + tid] : -1e30f;
  }

  for (int st = st_begin; st < st_end; ++st) {
    int s0 = st * 64;
    __syncthreads();
    *(uint4*)&KWh[row][XCH(row, 2 * seg)]     = rk0;
    *(uint4*)&KWh[row][XCH(row, 2 * seg + 1)] = rk1;
    *(uint4*)&KWl[row][XCH(row, 2 * seg)]     = rk2;
    *(uint4*)&KWl[row][XCH(row, 2 * seg + 1)] = rk3;
    *(uint4*)&Vh[row][XCH(row, 2 * seg)]     = rv0;
    *(uint4*)&Vh[row][XCH(row, 2 * seg + 1)] = rv1;
    *(uint4*)&Vl[row][XCH(row, 2 * seg)]     = rv2;
    *(uint4*)&Vl[row][XCH(row, 2 * seg + 1)] = rv3;
    if (tid < 64) a_lds[tid] = ra;
    if (st + 1 < st_end) {
      int sn = s0 + 64;
      int sg = sn + row;
      int sc = sg < SS ? sg : SS - 1;
      const u16* kp  = qkh + ((size_t)b * SS + sc) * 512 + 256 + h * 64 + seg * 16;
      const u16* klp = qkl + ((size_t)b * SS + sc) * 512 + 256 + h * 64 + seg * 16;
      rk0 = *(const uint4*)kp;  rk1 = *(const uint4*)(kp + 8);
      rk2 = *(const uint4*)klp; rk3 = *(const uint4*)(klp + 8);
      rv0 = *(const uint4*)(vrow_h + sn); rv1 = *(const uint4*)(vrow_h + sn + 8);
      rv2 = *(const uint4*)(vrow_l + sn); rv3 = *(const uint4*)(vrow_l + sn + 8);
      if (tid < 64) ra = (sn + tid < SS) ? aabh[sn + tid] : -1e30f;
    }
    __syncthreads();
    float am = a_lds[lane];
    #pragma unroll
    for (int dd = 1; dd < 64; dd <<= 1) am = fmaxf(am, __shfl_xor(am, dd));
    f32x4 p[4];
    #pragma unroll
    for (int sf = 0; sf < 4; ++sf) {
      int sr = sf * 16 + lr;
      bf16x8 kh0 = *(const bf16x8*)&KWh[sr][XCH(sr, lg)];
      bf16x8 kh1 = *(const bf16x8*)&KWh[sr][XCH(sr, lg + 4)];
      bf16x8 kl0 = *(const bf16x8*)&KWl[sr][XCH(sr, lg)];
      bf16x8 kl1 = *(const bf16x8*)&KWl[sr][XCH(sr, lg + 4)];
      f32x4 acc = {};
      acc = __builtin_amdgcn_mfma_f32_16x16x32_bf16(qh0, kl0, acc, 0, 0, 0);
      acc = __builtin_amdgcn_mfma_f32_16x16x32_bf16(qh1, kl1, acc, 0, 0, 0);
      acc = __builtin_amdgcn_mfma_f32_16x16x32_bf16(ql0, kh0, acc, 0, 0, 0);
      acc = __builtin_amdgcn_mfma_f32_16x16x32_bf16(ql1, kh1, acc, 0, 0, 0);
      acc = __builtin_amdgcn_mfma_f32_16x16x32_bf16(qh0, kh0, acc, 0, 0, 0);
      acc = __builtin_amdgcn_mfma_f32_16x16x32_bf16(qh1, kh1, acc, 0, 0, 0);
      p[sf] = acc;
    }
    __syncthreads();
    float ee[4], ft[4];
    #pragma unroll
    for (int sf = 0; sf < 4; ++sf) ee[sf] = __expf(a_lds[sf * 16 + lr] - am);
    #pragma unroll
    for (int r = 0; r < 4; ++r) ft[r] = __expf(fminf(am - Mt[r], 80.f));
    #pragma unroll
    for (int sf = 0; sf < 4; ++sf) {
      int s = s0 + sf * 16 + lr;
      int sc_ = sf * 2 + (lr >> 3), sb = lr & 7;
      #pragma unroll
      for (int r = 0; r < 4; ++r) {
        int tl_ = wv * 16 + lg * 4 + r;
        int t = t0 + tl_;
        float wval = (s <= t) ? p[sf][r] * ee[sf] * ft[r] : 0.f;
        wsum[r] += wval;
        u16 hi_ = f2b(wval);
        u16 lo_ = f2b(wval - b2f(hi_));
        KWh[tl_][XCH(tl_, sc_) + sb] = hi_;
        KWl[tl_][XCH(tl_, sc_) + sb] = lo_;
      }
    }
    __syncthreads();
    int tr = wv * 16 + lr;
    bf16x8 wh0 = *(const bf16x8*)&KWh[tr][XCH(tr, lg)];
    bf16x8 wh1 = *(const bf16x8*)&KWh[tr][XCH(tr, lg + 4)];
    bf16x8 wl0 = *(const bf16x8*)&KWl[tr][XCH(tr, lg)];
    bf16x8 wl1 = *(const bf16x8*)&KWl[tr][XCH(tr, lg + 4)];
    #pragma unroll
    for (int df = 0; df < 4; ++df) {
      int dr = df * 16 + lr;
      bf16x8 vh0 = *(const bf16x8*)&Vh[dr][XCH(dr, lg)];
      bf16x8 vh1 = *(const bf16x8*)&Vh[dr][XCH(dr, lg + 4)];
      bf16x8 vl0 = *(const bf16x8*)&Vl[dr][XCH(dr, lg)];
      bf16x8 vl1 = *(const bf16x8*)&Vl[dr][XCH(dr, lg + 4)];
      f32x4 a2 = hacc[df];
      a2 = __builtin_amdgcn_mfma_f32_16x16x32_bf16(wh0, vl0, a2, 0, 0, 0);
      a2 = __builtin_amdgcn_mfma_f32_16x16x32_bf16(wh1, vl1, a2, 0, 0, 0);
      a2 = __builtin_amdgcn_mfma_f32_16x16x32_bf16(wl0, vh0, a2, 0, 0, 0);
      a2 = __builtin_amdgcn_mfma_f32_16x16x32_bf16(wl1, vh1, a2, 0, 0, 0);
      a2 = __builtin_amdgcn_mfma_f32_16x16x32_bf16(wh0, vh0, a2, 0, 0, 0);
      a2 = __builtin_amdgcn_mfma_f32_16x16x32_bf16(wh1, vh1, a2, 0, 0, 0);
      hacc[df] = a2;
    }
  }
  #pragma unroll
  for (int r = 0; r < 4; ++r) {
    float sgn = wsum[r];
    sgn += __shfl_xor(sgn, 1); sgn += __shfl_xor(sgn, 2);
    sgn += __shfl_xor(sgn, 4); sgn += __shfl_xor(sgn, 8);
    wsum[r] = sgn;
  }
  float* pa = pacc + (size_t)part * BC * II;
  #pragma unroll
  for (int r = 0; r < 4; ++r) {
    int t = t0 + wv * 16 + lg * 4 + r;
    if (t < SS) {
      #pragma unroll
      for (int df = 0; df < 4; ++df)
        pa[((size_t)b * SS + t) * II + h * 64 + df * 16 + lr] = hacc[df][r];
      if (lr == 0)
        pw[(((size_t)part * BB + b) * NHH + h) * SS + t] = wsum[r];
    }
  }
}

// ---------------------------------------------------------------------------
// combine partials + normalize + per-head LN + skip*xc + *silu(z) -> bf16
// ---------------------------------------------------------------------------
__global__ __launch_bounds__(256) void combine_mhln_kernel(
    const float* __restrict__ pacc, const float* __restrict__ pw,
    const float* __restrict__ cumf, const float* __restrict__ MMb,
    const float* __restrict__ up, const float* __restrict__ xc,
    const float* __restrict__ mhg, const float* __restrict__ skip,
    u16* __restrict__ hb_bf)
{
  int row = blockIdx.x;
  int i = threadIdx.x;
  int h = i >> 6, lane = i & 63;
  int b = row / SS, s = row - b * SS;
  size_t bhS = ((size_t)b * NHH + h) * SS + s;
  float v = pacc[(size_t)row * II + i] + pacc[(size_t)BC * II + (size_t)row * II + i];
  float wsum = pw[bhS] + pw[(size_t)BB * NHH * SS + bhS];
  float nfl = __expf(-(cumf[bhS] + MMb[bhS]));
  float hv = v / fmaxf(fabsf(wsum), nfl);
  float sm = hv, sq = hv * hv;
  #pragma unroll
  for (int d = 1; d < 64; d <<= 1) { sm += __shfl_xor(sm, d); sq += __shfl_xor(sq, d); }
  float mu = sm * (1.f / 64.f);
  float var = sq * (1.f / 64.f) - mu * mu;
  float hn = (hv - mu) * rsqrtf(var + 1e-5f) * mhg[i];
  float z = up[(size_t)row * 512 + 256 + i];
  float sil = z / (1.f + __expf(-z));
  hb_bf[(size_t)row * II + i] = f2b((hn + skip[i] * xc[(size_t)row * II + i]) * sil);
}

// ---------------------------------------------------------------------------
// final: out[b,p,c] = y@Wp2^T + bp2 (y already LN'ed fp32)
// ---------------------------------------------------------------------------
__global__ __launch_bounds__(256) void final_kernel(
    const float* __restrict__ y, const float* __restrict__ Wp2,
    const float* __restrict__ bp2, float* __restrict__ out)
{
  __shared__ float yl[32 * 132];
  __shared__ float ol[96 * 32];
  int tid = threadIdx.x;
  int blk = blockIdx.x;
  int b = blk / 27, ct = blk % 27;
  int c0 = ct * 32;
  int nc = CC - c0; if (nc > 32) nc = 32;
  for (int j = 0; j < 16; ++j) {
    int idx = tid + j * 256;
    int cl = idx >> 7, d2 = idx & 127;
    yl[cl * 132 + d2] = (cl < nc) ? y[((size_t)b * CC + c0 + cl) * DD + d2] : 0.f;
  }
  __syncthreads();
  for (int j = 0; j < 12; ++j) {
    int o = tid + j * 256;
    int p = o >> 5, cl = o & 31;
    const float* wr = Wp2 + p * 128;
    float acc = bp2[p];
    #pragma unroll 8
    for (int d0 = 0; d0 < 128; d0 += 4) {
      float4 yv = *(const float4*)&yl[cl * 132 + d0];
      float4 wv = *(const float4*)&wr[d0];
      acc += yv.x * wv.x + yv.y * wv.y + yv.z * wv.z + yv.w * wv.w;
    }
    ol[p * 32 + cl] = acc;
  }
  __syncthreads();
  for (int j = 0; j < 12; ++j) {
    int o = tid + j * 256;
    int p = o >> 5, cl = o & 31;
    if (cl < nc) out[(size_t)b * PP * CC + (size_t)p * CC + c0 + cl] = ol[p * 32 + cl];
  }
}

// ---------------------------------------------------------------------------
extern "C" void kernel_launch(void* const* d_in, const int* in_sizes, int n_in,
                              void* d_out, int out_size, void* d_ws, size_t ws_size,
                              hipStream_t stream) {
  const float* xe   = (const float*)d_in[0];
  const float* Ws   = (const float*)d_in[4];
  const float* bs   = (const float*)d_in[5];
  const float* Wt_  = (const float*)d_in[6];
  const float* bt   = (const float*)d_in[7];
  const float* Wp1  = (const float*)d_in[8];
  const float* bp1  = (const float*)d_in[9];
  const float* Wp2  = (const float*)d_in[10];
  const float* bp2  = (const float*)d_in[11];
  const float* lng  = (const float*)d_in[12];
  const float* Wup  = (const float*)d_in[13];
  const float* bup  = (const float*)d_in[14];
  const float* Wcv  = (const float*)d_in[15];
  const float* bcv  = (const float*)d_in[16];
  const float* Wq   = (const float*)d_in[17];
  const float* Wk   = (const float*)d_in[18];
  const float* Wv   = (const float*)d_in[19];
  const float* Wi   = (const float*)d_in[20];
  const float* bi   = (const float*)d_in[21];
  const float* Wf   = (const float*)d_in[22];
  const float* bf_  = (const float*)d_in[23];
  const float* mhg  = (const float*)d_in[24];
  const float* skp  = (const float*)d_in[25];
  const float* Wdn  = (const float*)d_in[26];
  const float* bdn  = (const float*)d_in[27];
  const float* pg   = (const float*)d_in[28];
  float* out = (float*)d_out;

  float* w   = (float*)d_ws;
  float* x   = w;                       // [6896,128]
  float* y   = x   + 882688;
  float* up  = y   + 882688;            // [6896,512]  (aliased by A_head bf16)
  float* xc  = up  + 3530752;           // [6896,256]
  float* pacc = xc + 1765376;           // [2][6896,256] partial attn acc
  float* pw  = pacc + 3530752;          // [2][8][4][862]
  float* ig  = pw  + 55168;
  float* fg  = ig  + 27584;
  float* cum = fg  + 27584;
  float* aab = cum + 27584;
  float* MMb = aab + 27584;
  float* hbias = MMb + 27584;
  float* Gc  = hbias + 128;             // [2][256][8]
  float* Gv  = Gc + 4096;
  u16* ub    = (u16*)(Gv + 4096);
  u16* y_bf  = ub;            ub += 6896 * 128;
  u16* xc_bf = ub;            ub += 6896 * 256;
  u16* xin_bf = ub;           ub += 6896 * 256;
  u16* hb_bf = ub;            ub += 6896 * 256;
  u16* qkh   = ub;            ub += 6896 * 512;
  u16* qkl   = ub;            ub += 6896 * 512;
  u16* vhT   = ub;            ub += 8 * 256 * VTS;
  u16* vlT   = ub;            ub += 8 * 256 * VTS;
  u16* BTh   = ub;            ub += 131072;
  u16* WupT  = ub;            ub += 131072;
  u16* WqkT  = ub;            ub += 262144;
  u16* WvT   = ub;            ub += 131072;
  u16* WdnT  = ub;            ub += 65536;
  u16* Ah = (u16*)up;                   // A_head aliases up

  // merged weight prep
  prep_kernel<<<1665, 256, 0, stream>>>(
      Wup, Wq, Wk, Wv, Wdn, Ws, Wt_, Wp1, bs, bt, bp1, Wi, Wf,
      WupT, WqkT, WvT, WdnT, BTh, hbias, Gc, Gv);

  // head: x = A_head @ BTh + hbias, then y_bf = LN(x) with blk0 gains
  ta_kernel<<<432, 256, 0, stream>>>(xe, Ah);
  gemm_ln<0, 0><<<216, 256, 0, stream>>>(
      Ah, 1024, BTh, 1024, x, hbias, lng, nullptr, y_bf, BC, 1024);

  for (int blk = 0; blk < 2; ++blk) {
    gemm_bf16<0><<<dim3(8, 108), 256, 0, stream>>>(
        y_bf, 128, WupT + blk * 65536, 128, up, 512, bup + blk * 512, BC, 512, 128);
    conv_gates_kernel<<<6896, 256, 0, stream>>>(
        up, Wcv + blk * 1024, bcv + blk * 256, Gc + blk * 2048, Gv + blk * 2048,
        bi + blk * 4, bf_ + blk * 4, xc, xc_bf, xin_bf, ig, fg);
    qkv_kernel<<<dim3(12, 108), 256, 0, stream>>>(
        xc_bf, xin_bf, WqkT + blk * 131072, WvT + blk * 65536,
        qkh, qkl, vhT, vlT);
    scan_kernel<<<32, 64, 0, stream>>>(fg, ig, cum, aab, MMb);
    attn_kernel<<<NITEMS2, 256, 0, stream>>>(qkh, qkl, vhT, vlT, aab, MMb, pacc, pw);
    combine_mhln_kernel<<<6896, 256, 0, stream>>>(
        pacc, pw, cum, MMb, up, xc, mhg + blk * 256, skp + blk * 256, hb_bf);
    // dn GEMM + residual + LN fused: blk0 -> y_bf (blk1 gains); blk1 -> y fp32 (post_g)
    if (blk == 0)
      gemm_ln<1, 0><<<216, 256, 0, stream>>>(
          hb_bf, 256, WdnT, 256, x, bdn, lng + 128, nullptr, y_bf, BC, 256);
    else
      gemm_ln<1, 1><<<216, 256, 0, stream>>>(
          hb_bf, 256, WdnT + 32768, 256, x, bdn + 128, pg, y, nullptr, BC, 256);
  }

  final_kernel<<<216, 256, 0, stream>>>(y, Wp2, bp2, out);
}

// Round 15
// 255.266 us; speedup vs baseline: 1.0838x; 1.0838x over previous
//
#include <hip/hip_runtime.h>
#include <math.h>

#define BB 8
#define LL 512
#define CC 862
#define PP 96
#define DD 128
#define II 256
#define NHH 4
#define DHH 64
#define SS 862
#define BC (BB*CC)
#define VTS 864          // padded V^T row stride
#define NITEMS2 896      // attn work items = 28 pairs * 32 bh

typedef unsigned short u16;
using bf16x8 = __attribute__((ext_vector_type(8))) short;
using f32x4  = __attribute__((ext_vector_type(4))) float;

__device__ __forceinline__ u16 f2b(float x) {
  union { float f; unsigned u; } v; v.f = x;
  unsigned r = v.u + 0x7FFF + ((v.u >> 16) & 1);
  return (u16)(r >> 16);
}
__device__ __forceinline__ float b2f(u16 h) {
  union { unsigned u; float f; } v; v.u = ((unsigned)h) << 16;
  return v.f;
}

// chunk-XOR swizzle: u16 offset of 16B-chunk c within row r of a [64][64] tile
#define XCH(r, c) ((((c) ^ ((r) & 7)) << 3))

// ---------------------------------------------------------------------------
// merged weight-prep kernel (tc + gcomb + hbias + gprep)
// ---------------------------------------------------------------------------
__global__ __launch_bounds__(256) void prep_kernel(
    const float* __restrict__ Wup, const float* __restrict__ Wq,
    const float* __restrict__ Wk, const float* __restrict__ Wv,
    const float* __restrict__ Wdn, const float* __restrict__ Ws,
    const float* __restrict__ Wt, const float* __restrict__ Wp1,
    const float* __restrict__ bs, const float* __restrict__ bt,
    const float* __restrict__ bp1, const float* __restrict__ Wi,
    const float* __restrict__ Wf,
    u16* __restrict__ WupT, u16* __restrict__ WqkT,
    u16* __restrict__ WvT, u16* __restrict__ WdnT,
    u16* __restrict__ BTh, float* __restrict__ hbias,
    float* __restrict__ Gc, float* __restrict__ Gv)
{
  int gb = blockIdx.x;
  int tid = threadIdx.x;
  if (gb < 640) {
    int bx = gb & 63, by = gb >> 6;
    const float* src; u16* dst; int R, Cn; float scl = 1.f;
    switch (by) {
      case 0: src = Wup;          dst = WupT;            R = 128; Cn = 512; break;
      case 1: src = Wup + 65536;  dst = WupT + 65536;    R = 128; Cn = 512; break;
      case 2: src = Wq;           dst = WqkT;            R = 256; Cn = 256; scl = 0.125f; break;
      case 3: src = Wk;           dst = WqkT + 65536;    R = 256; Cn = 256; break;
      case 4: src = Wq + 65536;   dst = WqkT + 131072;   R = 256; Cn = 256; scl = 0.125f; break;
      case 5: src = Wk + 65536;   dst = WqkT + 196608;   R = 256; Cn = 256; break;
      case 6: src = Wv;           dst = WvT;             R = 256; Cn = 256; break;
      case 7: src = Wv + 65536;   dst = WvT + 65536;     R = 256; Cn = 256; break;
      case 8: src = Wdn;          dst = WdnT;            R = 256; Cn = 128; break;
      default: src = Wdn + 32768; dst = WdnT + 32768;    R = 256; Cn = 128; break;
    }
    int tpr = Cn >> 5;
    int tx = bx % tpr, ty_ = bx / tpr;
    if (ty_ >= (R >> 5)) return;
    __shared__ float t[32][33];
    int r0 = ty_ * 32, c0 = tx * 32;
    int cr = tid >> 5, cc = tid & 31;
    #pragma unroll
    for (int rr = 0; rr < 4; ++rr)
      t[cr + rr * 8][cc] = src[(size_t)(r0 + cr + rr * 8) * Cn + c0 + cc];
    __syncthreads();
    #pragma unroll
    for (int rr = 0; rr < 4; ++rr)
      dst[(size_t)(c0 + cr + rr * 8) * R + r0 + cc] = f2b(t[cc][cr + rr * 8] * scl);
  } else if (gb < 1152) {
    int i2 = gb - 640;
    int d = i2 & 127, byy = i2 >> 7;
    int lp = byy * 256 + tid;
    const float* wp = Wp1 + d * 96;
    float acc = 0.f;
    if (lp < 512) {
      for (int p = 0; p < 96; ++p) acc += Ws[p * 512 + lp] * wp[p];
    } else {
      int l = lp - 512;
      for (int p = 0; p < 96; ++p) acc += (Wt[p * 512 + l] - Ws[p * 512 + l]) * wp[p];
    }
    BTh[(size_t)d * 1024 + lp] = f2b(acc);
  } else if (gb == 1152) {
    if (tid < 128) {
      float acc = bp1[tid];
      for (int p = 0; p < 96; ++p) acc += (bs[p] + bt[p]) * Wp1[tid * 96 + p];
      hbias[tid] = acc;
    }
  } else {
    int i2 = gb - 1153;
    int i = i2 & 255, blk = i2 >> 8;
    int j = tid;
    float wq = Wq[(size_t)blk * 65536 + i * 256 + j];
    float wk = Wk[(size_t)blk * 65536 + i * 256 + j];
    float wv = Wv[(size_t)blk * 65536 + i * 256 + j];
    const float* wi = Wi + blk * 3072;
    const float* wf = Wf + blk * 3072;
    float pc[8], pv[8];
    #pragma unroll
    for (int o = 0; o < 4; ++o) {
      pc[o]     = wq * wi[j * 4 + o] + wk * wi[(256 + j) * 4 + o];
      pc[4 + o] = wq * wf[j * 4 + o] + wk * wf[(256 + j) * 4 + o];
      pv[o]     = wv * wi[(512 + j) * 4 + o];
      pv[4 + o] = wv * wf[(512 + j) * 4 + o];
    }
    #pragma unroll
    for (int o = 0; o < 8; ++o)
      #pragma unroll
      for (int d = 1; d < 64; d <<= 1) {
        pc[o] += __shfl_xor(pc[o], d);
        pv[o] += __shfl_xor(pv[o], d);
      }
    __shared__ float red[4][16];
    int wv_ = j >> 6, lane = j & 63;
    if (lane == 0) {
      #pragma unroll
      for (int o = 0; o < 8; ++o) { red[wv_][o] = pc[o]; red[wv_][8 + o] = pv[o]; }
    }
    __syncthreads();
    if (j < 16) {
      float s4 = red[0][j] + red[1][j] + red[2][j] + red[3][j];
      if (j < 8) Gc[((size_t)blk * 256 + i) * 8 + j] = s4;
      else       Gv[((size_t)blk * 256 + i) * 8 + j - 8] = s4;
    }
  }
}

// ---------------------------------------------------------------------------
// transpose + moving-average -> bf16 A_head [6896][1024] — coalesced
// ---------------------------------------------------------------------------
__global__ __launch_bounds__(256) void ta_kernel(
    const float* __restrict__ xe, u16* __restrict__ Ah)
{
  __shared__ float xel[16][545];
  __shared__ float mml[16][517];
  int tid = threadIdx.x;
  int b = blockIdx.x / 54, ct = blockIdx.x % 54;
  int c0 = ct * 16;
  for (int j = 0; j < 34; ++j) {
    int idx = tid + j * 256;
    if (idx < 8576) {
      int li = idx >> 4, cc = idx & 15;
      int l = li - 12; l = l < 0 ? 0 : (l > 511 ? 511 : l);
      int c = c0 + cc; if (c > 861) c = 861;
      xel[cc][li] = xe[((size_t)b * LL + l) * CC + c];
    }
  }
  __syncthreads();
  {
    int cl = tid & 15;
    int l0 = (tid >> 4) * 32;
    float win = 0.f;
    #pragma unroll 5
    for (int o = 0; o < 25; ++o) win += xel[cl][l0 + o];
    mml[cl][l0] = win * (1.f / 25.f);
    for (int i = 1; i < 32; ++i) {
      win += xel[cl][l0 + 24 + i] - xel[cl][l0 + i - 1];
      mml[cl][l0 + i] = win * (1.f / 25.f);
    }
  }
  __syncthreads();
  for (int j = 0; j < 32; ++j) {
    int idx = tid + j * 256;
    int cr = idx >> 9, l = idx & 511;
    int c = c0 + cr;
    if (c < CC) {
      size_t base = ((size_t)b * CC + c) * 1024;
      Ah[base + l] = f2b(xel[cr][12 + l]);
      Ah[base + 512 + l] = f2b(mml[cr][l]);
    }
  }
}

// ---------------------------------------------------------------------------
// bf16 MFMA GEMM core loop as a device function (BK=64, 64x64 tile)
// ---------------------------------------------------------------------------
__device__ __forceinline__ void gemm_core(
    const u16* __restrict__ A, int lda, const u16* __restrict__ BT, int ldbt,
    int M, int K, int m0, int n0, int tid,
    u16 (*As0)[40], u16 (*As1)[40], u16 (*Bs0)[40], u16 (*Bs1)[40],
    f32x4 acc[2][2])
{
  int wv = tid >> 6, lane = tid & 63;
  int wr = wv >> 1, wc = wv & 1;
  int lrow = lane & 15, lk = lane >> 4;
  int arow = tid >> 2, aseg = tid & 3;
  for (int k0 = 0; k0 < K; k0 += 64) {
    int gm = m0 + arow; if (gm > M - 1) gm = M - 1;
    const u16* ap = &A[(size_t)gm * lda + k0 + aseg * 8];
    *(uint4*)&As0[arow][aseg * 8] = *(const uint4*)ap;
    *(uint4*)&As1[arow][aseg * 8] = *(const uint4*)(ap + 32);
    const u16* bp = &BT[(size_t)(n0 + arow) * ldbt + k0 + aseg * 8];
    *(uint4*)&Bs0[arow][aseg * 8] = *(const uint4*)bp;
    *(uint4*)&Bs1[arow][aseg * 8] = *(const uint4*)(bp + 32);
    __syncthreads();
    bf16x8 af[2], bfr[2];
    #pragma unroll
    for (int fm = 0; fm < 2; ++fm) af[fm] = *(const bf16x8*)&As0[wr * 32 + fm * 16 + lrow][lk * 8];
    #pragma unroll
    for (int fn = 0; fn < 2; ++fn) bfr[fn] = *(const bf16x8*)&Bs0[wc * 32 + fn * 16 + lrow][lk * 8];
    #pragma unroll
    for (int fm = 0; fm < 2; ++fm)
      #pragma unroll
      for (int fn = 0; fn < 2; ++fn)
        acc[fm][fn] = __builtin_amdgcn_mfma_f32_16x16x32_bf16(af[fm], bfr[fn], acc[fm][fn], 0, 0, 0);
    #pragma unroll
    for (int fm = 0; fm < 2; ++fm) af[fm] = *(const bf16x8*)&As1[wr * 32 + fm * 16 + lrow][lk * 8];
    #pragma unroll
    for (int fn = 0; fn < 2; ++fn) bfr[fn] = *(const bf16x8*)&Bs1[wc * 32 + fn * 16 + lrow][lk * 8];
    #pragma unroll
    for (int fm = 0; fm < 2; ++fm)
      #pragma unroll
      for (int fn = 0; fn < 2; ++fn)
        acc[fm][fn] = __builtin_amdgcn_mfma_f32_16x16x32_bf16(af[fm], bfr[fn], acc[fm][fn], 0, 0, 0);
    __syncthreads();
  }
}

// ---------------------------------------------------------------------------
// generic 64x64 GEMM kernel. MODE 0: C=AB+bias; 1: C+=AB+bias
// ---------------------------------------------------------------------------
template<int MODE>
__global__ __launch_bounds__(256) void gemm_bf16(
    const u16* __restrict__ A, int lda,
    const u16* __restrict__ BT, int ldbt,
    float* __restrict__ C, int ldc, const float* __restrict__ bias,
    int M, int N, int K)
{
  __shared__ u16 As0[64][40], As1[64][40];
  __shared__ u16 Bs0[64][40], Bs1[64][40];
  int tid = threadIdx.x;
  int m0 = blockIdx.y * 64, n0 = blockIdx.x * 64;
  f32x4 acc[2][2] = {};
  gemm_core(A, lda, BT, ldbt, M, K, m0, n0, tid, As0, As1, Bs0, Bs1, acc);
  int wv = tid >> 6, lane = tid & 63;
  int wr = wv >> 1, wc = wv & 1;
  int lrow = lane & 15, lk = lane >> 4;
  #pragma unroll
  for (int fm = 0; fm < 2; ++fm) {
    #pragma unroll
    for (int fn = 0; fn < 2; ++fn) {
      int col = n0 + wc * 32 + fn * 16 + lrow;
      #pragma unroll
      for (int r = 0; r < 4; ++r) {
        int row = m0 + wr * 32 + fm * 16 + lk * 4 + r;
        if (row < M) {
          float vv = acc[fm][fn][r];
          if (bias) vv += bias[col];
          float* cp = &C[(size_t)row * ldc + col];
          if (MODE == 1) vv += *cp;
          *cp = vv;
        }
      }
    }
  }
}

// ---------------------------------------------------------------------------
// fused GEMM(N=128) + residual + row-LayerNorm.  32x128 tile, 216 blocks.
// MODE 0: x = A@BT + bias; 1: x += A@BT + bias.  Then LN(x) row-wise:
// OUTF32 0 -> y_bf (bf16, gain g); 1 -> y (fp32, gain g).
// FUSEC 1: A is computed on the fly from attention partials (combine+mhln):
//   per 64-col K-chunk (= one head), normalize pacc by wsum/nfl, per-head LN,
//   gate with silu(z) and skip*xc  (replaces combine_mhln_kernel).
// ---------------------------------------------------------------------------
template<int MODE, int OUTF32, int FUSEC>
__global__ __launch_bounds__(256) void gemm_ln(
    const u16* __restrict__ A, int lda,
    const u16* __restrict__ BT, int ldbt,
    float* __restrict__ x, const float* __restrict__ bias,
    const float* __restrict__ g,
    float* __restrict__ y, u16* __restrict__ y_bf,
    int M, int K,
    const float* __restrict__ pacc, const float* __restrict__ pw,
    const float* __restrict__ cumf, const float* __restrict__ MMb,
    const float* __restrict__ up2, const float* __restrict__ xc2,
    const float* __restrict__ mhg, const float* __restrict__ skip)
{
  __shared__ u16 As0[32][40], As1[32][40];
  __shared__ u16 Bs0[128][40], Bs1[128][40];
  __shared__ float red_s[32][2], red_q[32][2];
  int tid = threadIdx.x;
  int m0 = blockIdx.x * 32;
  int wv = tid >> 6, lane = tid & 63;
  int wr = wv >> 1, wc = wv & 1;       // wr: row half (16), wc: col half (64)
  int lrow = lane & 15, lk = lane >> 4;
  f32x4 acc[4] = {};
  int arow = tid >> 3, aseg7 = tid & 7;        // A: 32 rows x 8 segs
  int brow = tid >> 1, bhalf = tid & 1;        // B: 128 rows x 2 seg-pairs
  for (int k0 = 0; k0 < K; k0 += 64) {
    int gm = m0 + arow; if (gm > M - 1) gm = M - 1;
    if (FUSEC == 0) {
      const u16* ap = &A[(size_t)gm * lda + k0];
      if (aseg7 < 4) *(uint4*)&As0[arow][aseg7 * 8] = *(const uint4*)(ap + aseg7 * 8);
      else           *(uint4*)&As1[arow][(aseg7 - 4) * 8] = *(const uint4*)(ap + 32 + (aseg7 - 4) * 8);
    } else {
      // combine + per-head LN + gate, head = k0/64
      int bb = gm / SS, sx = gm - bb * SS;
      int hh = k0 >> 6;
      size_t bhS = ((size_t)bb * NHH + hh) * SS + sx;
      float wsum = pw[bhS] + pw[(size_t)BB * NHH * SS + bhS];
      float nfl = __expf(-(cumf[bhS] + MMb[bhS]));
      float rden = 1.f / fmaxf(fabsf(wsum), nfl);
      int colb = k0 + aseg7 * 8;
      const float* p0 = &pacc[(size_t)gm * II + colb];
      const float* p1 = p0 + (size_t)BC * II;
      float hv[8], sr = 0.f, sq2 = 0.f;
      #pragma unroll
      for (int j = 0; j < 8; ++j) {
        hv[j] = (p0[j] + p1[j]) * rden;
        sr += hv[j]; sq2 += hv[j] * hv[j];
      }
      sr += __shfl_xor(sr, 1); sq2 += __shfl_xor(sq2, 1);
      sr += __shfl_xor(sr, 2); sq2 += __shfl_xor(sq2, 2);
      sr += __shfl_xor(sr, 4); sq2 += __shfl_xor(sq2, 4);
      float mu = sr * (1.f / 64.f);
      float var = sq2 * (1.f / 64.f) - mu * mu;
      float rr2 = rsqrtf(var + 1e-5f);
      u16 o8[8];
      #pragma unroll
      for (int j = 0; j < 8; ++j) {
        int col = colb + j;
        float hn = (hv[j] - mu) * rr2 * mhg[col];
        float z = up2[(size_t)gm * 512 + 256 + col];
        float sil = z / (1.f + __expf(-z));
        o8[j] = f2b((hn + skip[col] * xc2[(size_t)gm * II + col]) * sil);
      }
      if (aseg7 < 4) *(uint4*)&As0[arow][aseg7 * 8] = *(const uint4*)o8;
      else           *(uint4*)&As1[arow][(aseg7 - 4) * 8] = *(const uint4*)o8;
    }
    const u16* bp = &BT[(size_t)brow * ldbt + k0];
    #pragma unroll
    for (int j = 0; j < 2; ++j) {
      int seg = bhalf * 2 + j;
      *(uint4*)&Bs0[brow][seg * 8] = *(const uint4*)(bp + seg * 8);
      *(uint4*)&Bs1[brow][seg * 8] = *(const uint4*)(bp + 32 + seg * 8);
    }
    __syncthreads();
    bf16x8 af, bfr[4];
    af = *(const bf16x8*)&As0[wr * 16 + lrow][lk * 8];
    #pragma unroll
    for (int fn = 0; fn < 4; ++fn) bfr[fn] = *(const bf16x8*)&Bs0[wc * 64 + fn * 16 + lrow][lk * 8];
    #pragma unroll
    for (int fn = 0; fn < 4; ++fn)
      acc[fn] = __builtin_amdgcn_mfma_f32_16x16x32_bf16(af, bfr[fn], acc[fn], 0, 0, 0);
    af = *(const bf16x8*)&As1[wr * 16 + lrow][lk * 8];
    #pragma unroll
    for (int fn = 0; fn < 4; ++fn) bfr[fn] = *(const bf16x8*)&Bs1[wc * 64 + fn * 16 + lrow][lk * 8];
    #pragma unroll
    for (int fn = 0; fn < 4; ++fn)
      acc[fn] = __builtin_amdgcn_mfma_f32_16x16x32_bf16(af, bfr[fn], acc[fn], 0, 0, 0);
    __syncthreads();
  }
  // epilogue: bias + residual, fp32 x write, row sums
  #pragma unroll
  for (int r = 0; r < 4; ++r) {
    int lrid = wr * 16 + lk * 4 + r;
    int grow = m0 + lrid;
    float sr = 0.f, sq = 0.f;
    #pragma unroll
    for (int fn = 0; fn < 4; ++fn) {
      int col = wc * 64 + fn * 16 + lrow;
      float vv = acc[fn][r] + bias[col];
      if (MODE == 1) vv += x[(size_t)grow * DD + col];
      acc[fn][r] = vv;
      if (grow < M) x[(size_t)grow * DD + col] = vv;
      sr += vv; sq += vv * vv;
    }
    sr += __shfl_xor(sr, 1); sq += __shfl_xor(sq, 1);
    sr += __shfl_xor(sr, 2); sq += __shfl_xor(sq, 2);
    sr += __shfl_xor(sr, 4); sq += __shfl_xor(sq, 4);
    sr += __shfl_xor(sr, 8); sq += __shfl_xor(sq, 8);
    if (lrow == 0) { red_s[lrid][wc] = sr; red_q[lrid][wc] = sq; }
  }
  __syncthreads();
  #pragma unroll
  for (int r = 0; r < 4; ++r) {
    int lrid = wr * 16 + lk * 4 + r;
    int grow = m0 + lrid;
    if (grow >= M) continue;
    float s = red_s[lrid][0] + red_s[lrid][1];
    float q = red_q[lrid][0] + red_q[lrid][1];
    float mean = s * (1.f / 128.f);
    float var = q * (1.f / 128.f) - mean * mean;
    float rr = rsqrtf(var + 1e-5f);
    #pragma unroll
    for (int fn = 0; fn < 4; ++fn) {
      int col = wc * 64 + fn * 16 + lrow;
      float out = (acc[fn][r] - mean) * rr * g[col];
      if (OUTF32) y[(size_t)grow * DD + col] = out;
      else        y_bf[(size_t)grow * DD + col] = f2b(out);
    }
  }
}

// ---------------------------------------------------------------------------
// per-(b,h) scan helper
// ---------------------------------------------------------------------------
__device__ __forceinline__ float logsig(float x) {
  return fminf(x, 0.f) - log1pf(__expf(-fabsf(x)));
}

// ---------------------------------------------------------------------------
// merged qk+v GEMM + gate scan.  bx<1296: GEMM (nrole=bx%12, m=bx/12);
// bx>=1296: per-(b,h) scan with 64 threads.  Rows >= BC skipped.
// ---------------------------------------------------------------------------
__global__ __launch_bounds__(256) void qkv_scan_kernel(
    const u16* __restrict__ xc_bf, const u16* __restrict__ xin_bf,
    const u16* __restrict__ WqkT, const u16* __restrict__ WvT,
    u16* __restrict__ qkh, u16* __restrict__ qkl,
    u16* __restrict__ vhT, u16* __restrict__ vlT,
    const float* __restrict__ fg, const float* __restrict__ ig,
    float* __restrict__ cumf, float* __restrict__ aa, float* __restrict__ MMb)
{
  __shared__ u16 As0[64][40], As1[64][40];
  __shared__ u16 Bs0[64][40], Bs1[64][40];
  int tid = threadIdx.x;
  int bx = blockIdx.x;
  if (bx >= 1296) {
    // ---- scan role (1 wave) ----
    if (tid >= 64) return;
    int bh = bx - 1296;
    int lane = tid;
    const float* f = fg + (size_t)bh * SS;
    const float* gg = ig + (size_t)bh * SS;
    int s0 = lane * 14, s1 = s0 + 14; if (s1 > SS) s1 = SS;
    float loc = 0.f;
    for (int s = s0; s < s1; ++s) loc += logsig(f[s]);
    float v = loc;
    #pragma unroll
    for (int d = 1; d < 64; d <<= 1) { float o = __shfl_up(v, d); if (lane >= d) v += o; }
    float run = v - loc;
    float lmax = -1e30f;
    for (int s = s0; s < s1; ++s) {
      run += logsig(f[s]);
      cumf[(size_t)bh * SS + s] = run;
      float a = gg[s] - run;
      aa[(size_t)bh * SS + s] = a;
      lmax = fmaxf(lmax, a);
    }
    float mv = lmax;
    #pragma unroll
    for (int d = 1; d < 64; d <<= 1) { float o = __shfl_up(mv, d); if (lane >= d) mv = fmaxf(mv, o); }
    float em = __shfl_up(mv, 1);
    if (lane == 0) em = -1e30f;
    float runm = em;
    for (int s = s0; s < s1; ++s) {
      runm = fmaxf(runm, aa[(size_t)bh * SS + s]);
      MMb[(size_t)bh * SS + s] = runm;
    }
    return;
  }
  // ---- GEMM role ----
  int m0 = (bx / 12) * 64;
  int nrole = bx % 12;
  bool is_qk = nrole < 8;
  int n0 = (is_qk ? nrole : nrole - 8) * 64;
  const u16* A  = is_qk ? xc_bf : xin_bf;
  const u16* BT = is_qk ? WqkT : WvT;
  f32x4 acc[2][2] = {};
  gemm_core(A, 256, BT, 256, BC, 256, m0, n0, tid, As0, As1, Bs0, Bs1, acc);
  int wv = tid >> 6, lane = tid & 63;
  int wr = wv >> 1, wc = wv & 1;
  int lrow = lane & 15, lk = lane >> 4;
  #pragma unroll
  for (int fm = 0; fm < 2; ++fm) {
    #pragma unroll
    for (int fn = 0; fn < 2; ++fn) {
      int col = n0 + wc * 32 + fn * 16 + lrow;
      int rbase = m0 + wr * 32 + fm * 16 + lk * 4;
      if (is_qk) {
        #pragma unroll
        for (int r = 0; r < 4; ++r) {
          int row = rbase + r;
          if (row < BC) {
            float vv = acc[fm][fn][r];
            u16 hi = f2b(vv);
            u16 lo = f2b(vv - b2f(hi));
            qkh[(size_t)row * 512 + col] = hi;
            qkl[(size_t)row * 512 + col] = lo;
          }
        }
      } else {
        u16 hi4[4], lo4[4];
        #pragma unroll
        for (int r = 0; r < 4; ++r) {
          float vv = acc[fm][fn][r];
          hi4[r] = f2b(vv);
          lo4[r] = f2b(vv - b2f(hi4[r]));
        }
        int bb0 = rbase / SS, s0_ = rbase - bb0 * SS;
        int bb3 = (rbase + 3) / SS;
        if (bb0 == bb3 && rbase + 3 < BC) {   // s0_ always even (SS=862)
          size_t o = ((size_t)bb0 * II + col) * VTS + s0_;
          *(unsigned*)&vhT[o]     = (unsigned)hi4[0] | ((unsigned)hi4[1] << 16);
          *(unsigned*)&vhT[o + 2] = (unsigned)hi4[2] | ((unsigned)hi4[3] << 16);
          *(unsigned*)&vlT[o]     = (unsigned)lo4[0] | ((unsigned)lo4[1] << 16);
          *(unsigned*)&vlT[o + 2] = (unsigned)lo4[2] | ((unsigned)lo4[3] << 16);
        } else {
          #pragma unroll
          for (int r = 0; r < 4; ++r) {
            int row = rbase + r;
            if (row < BC) {
              int bb = row / SS, s = row - bb * SS;
              size_t o = ((size_t)bb * II + col) * VTS + s;
              vhT[o] = hi4[r];
              vlT[o] = lo4[r];
            }
          }
        }
      }
    }
  }
}

// ---------------------------------------------------------------------------
// causal conv (k=4) + SiLU + fused gate preacts (via Gc/Gv)
// ---------------------------------------------------------------------------
__global__ __launch_bounds__(256) void conv_gates_kernel(
    const float* __restrict__ up, const float* __restrict__ Wc,
    const float* __restrict__ bc, const float* __restrict__ Gc,
    const float* __restrict__ Gv, const float* __restrict__ bi,
    const float* __restrict__ bfp,
    float* __restrict__ xc, u16* __restrict__ xc_bf, u16* __restrict__ xin_bf,
    float* __restrict__ ig, float* __restrict__ fg)
{
  __shared__ float red[4][8];
  int row = blockIdx.x;
  int i = threadIdx.x;
  int b = row / SS, s = row - b * SS;
  float acc = bc[i];
  float xin = 0.f;
  #pragma unroll
  for (int w2 = 0; w2 < 4; ++w2) {
    int sp = s - 3 + w2;
    if (sp >= 0) {
      float uv = up[((size_t)b * SS + sp) * 512 + i];
      acc += uv * Wc[w2 * 256 + i];
      if (w2 == 3) xin = uv;
    }
  }
  float sg = 1.f / (1.f + __expf(-acc));
  float val = acc * sg;
  xc[(size_t)row * II + i] = val;
  xc_bf[(size_t)row * II + i] = f2b(val);
  xin_bf[(size_t)row * II + i] = f2b(xin);
  float p[8];
  const float* gci = &Gc[i * 8];
  const float* gvi = &Gv[i * 8];
  #pragma unroll
  for (int o = 0; o < 8; ++o) p[o] = val * gci[o] + xin * gvi[o];
  #pragma unroll
  for (int o = 0; o < 8; ++o)
    #pragma unroll
    for (int d = 1; d < 64; d <<= 1) p[o] += __shfl_xor(p[o], d);
  int wv = i >> 6, lane = i & 63;
  if (lane == 0) {
    #pragma unroll
    for (int o = 0; o < 8; ++o) red[wv][o] = p[o];
  }
  __syncthreads();
  if (i < 8) {
    float sum = red[0][i] + red[1][i] + red[2][i] + red[3][i];
    if (i < 4) ig[((size_t)b * NHH + i) * SS + s] = sum + bi[i];
    else       fg[((size_t)b * NHH + i - 4) * SS + s] = sum + bfp[i - 4];
  }
}

// ---------------------------------------------------------------------------
// masked decay attention — split-precision MFMA, register-prefetch, 2-way
// s-split partials, W-overlay on K LDS tiles (4 barriers/tile).
// ---------------------------------------------------------------------------
__global__ __launch_bounds__(256) void attn_kernel(
    const u16* __restrict__ qkh, const u16* __restrict__ qkl,
    const u16* __restrict__ vhT, const u16* __restrict__ vlT,
    const float* __restrict__ aab, const float* __restrict__ MMb,
    float* __restrict__ pacc, float* __restrict__ pw)
{
  __shared__ u16 KWh[64][64], KWl[64][64];  // K during QK^T, then W for PV
  __shared__ u16 Vh[64][64], Vl[64][64];    // [d][s]
  __shared__ float a_lds[64];
  int tid = threadIdx.x;
  int wv = tid >> 6, lane = tid & 63;
  int lr = lane & 15, lg = lane >> 4;
  int item = blockIdx.x;
  int pp = item >> 5;                     // 0..27, heavy-first
  int tb = 13 - (pp >> 1);
  int part = pp & 1;
  int h = item & 3, b = (item >> 2) & 7;
  int t0 = tb * 64;
  int nt = tb + 1;
  int nt0 = (nt + 1) >> 1;
  int st_begin = part ? nt0 : 0;
  int st_end   = part ? nt : nt0;
  const float* aabh = aab + ((size_t)b * NHH + h) * SS;
  const float* Mbh  = MMb + ((size_t)b * NHH + h) * SS;

  int tq = t0 + wv * 16 + lr; if (tq > SS - 1) tq = SS - 1;
  const u16* qrow_h = qkh + ((size_t)b * SS + tq) * 512 + h * 64;
  const u16* qrow_l = qkl + ((size_t)b * SS + tq) * 512 + h * 64;
  bf16x8 qh0 = *(const bf16x8*)(qrow_h + lg * 8);
  bf16x8 qh1 = *(const bf16x8*)(qrow_h + 32 + lg * 8);
  bf16x8 ql0 = *(const bf16x8*)(qrow_l + lg * 8);
  bf16x8 ql1 = *(const bf16x8*)(qrow_l + 32 + lg * 8);

  float Mt[4];
  #pragma unroll
  for (int r = 0; r < 4; ++r) {
    int t = t0 + wv * 16 + lg * 4 + r; int tc = t < SS ? t : SS - 1;
    Mt[r] = Mbh[tc];
  }

  int row = tid >> 2, seg = tid & 3;
  const u16* vrow_h = vhT + ((size_t)(b * II + h * 64 + row)) * VTS + seg * 16;
  const u16* vrow_l = vlT + ((size_t)(b * II + h * 64 + row)) * VTS + seg * 16;

  f32x4 hacc[4] = {};
  float wsum[4] = {0.f, 0.f, 0.f, 0.f};

  uint4 rk0, rk1, rk2, rk3, rv0, rv1, rv2, rv3;
  float ra = -1e30f;
  if (st_begin < st_end) {
    int sg = st_begin * 64 + row;
    int sc = sg < SS ? sg : SS - 1;
    const u16* kp  = qkh + ((size_t)b * SS + sc) * 512 + 256 + h * 64 + seg * 16;
    const u16* klp = qkl + ((size_t)b * SS + sc) * 512 + 256 + h * 64 + seg * 16;
    rk0 = *(const uint4*)kp;  rk1 = *(const uint4*)(kp + 8);
    rk2 = *(const uint4*)klp; rk3 = *(const uint4*)(klp + 8);
    int sn = st_begin * 64;
    rv0 = *(const uint4*)(vrow_h + sn); rv1 = *(const uint4*)(vrow_h + sn + 8);
    rv2 = *(const uint4*)(vrow_l + sn); rv3 = *(const uint4*)(vrow_l + sn + 8);
    if (tid < 64) ra = (sn + tid < SS) ? aabh[sn + tid] : -1e30f;
  }

  for (int st = st_begin; st < st_end; ++st) {
    int s0 = st * 64;
    __syncthreads();
    *(uint4*)&KWh[row][XCH(row, 2 * seg)]     = rk0;
    *(uint4*)&KWh[row][XCH(row, 2 * seg + 1)] = rk1;
    *(uint4*)&KWl[row][XCH(row, 2 * seg)]     = rk2;
    *(uint4*)&KWl[row][XCH(row, 2 * seg + 1)] = rk3;
    *(uint4*)&Vh[row][XCH(row, 2 * seg)]     = rv0;
    *(uint4*)&Vh[row][XCH(row, 2 * seg + 1)] = rv1;
    *(uint4*)&Vl[row][XCH(row, 2 * seg)]     = rv2;
    *(uint4*)&Vl[row][XCH(row, 2 * seg + 1)] = rv3;
    if (tid < 64) a_lds[tid] = ra;
    if (st + 1 < st_end) {
      int sn = s0 + 64;
      int sg = sn + row;
      int sc = sg < SS ? sg : SS - 1;
      const u16* kp  = qkh + ((size_t)b * SS + sc) * 512 + 256 + h * 64 + seg * 16;
      const u16* klp = qkl + ((size_t)b * SS + sc) * 512 + 256 + h * 64 + seg * 16;
      rk0 = *(const uint4*)kp;  rk1 = *(const uint4*)(kp + 8);
      rk2 = *(const uint4*)klp; rk3 = *(const uint4*)(klp + 8);
      rv0 = *(const uint4*)(vrow_h + sn); rv1 = *(const uint4*)(vrow_h + sn + 8);
      rv2 = *(const uint4*)(vrow_l + sn); rv3 = *(const uint4*)(vrow_l + sn + 8);
      if (tid < 64) ra = (sn + tid < SS) ? aabh[sn + tid] : -1e30f;
    }
    __syncthreads();
    float am = a_lds[lane];
    #pragma unroll
    for (int dd = 1; dd < 64; dd <<= 1) am = fmaxf(am, __shfl_xor(am, dd));
    f32x4 p[4];
    #pragma unroll
    for (int sf = 0; sf < 4; ++sf) {
      int sr = sf * 16 + lr;
      bf16x8 kh0 = *(const bf16x8*)&KWh[sr][XCH(sr, lg)];
      bf16x8 kh1 = *(const bf16x8*)&KWh[sr][XCH(sr, lg + 4)];
      bf16x8 kl0 = *(const bf16x8*)&KWl[sr][XCH(sr, lg)];
      bf16x8 kl1 = *(const bf16x8*)&KWl[sr][XCH(sr, lg + 4)];
      f32x4 acc = {};
      acc = __builtin_amdgcn_mfma_f32_16x16x32_bf16(qh0, kl0, acc, 0, 0, 0);
      acc = __builtin_amdgcn_mfma_f32_16x16x32_bf16(qh1, kl1, acc, 0, 0, 0);
      acc = __builtin_amdgcn_mfma_f32_16x16x32_bf16(ql0, kh0, acc, 0, 0, 0);
      acc = __builtin_amdgcn_mfma_f32_16x16x32_bf16(ql1, kh1, acc, 0, 0, 0);
      acc = __builtin_amdgcn_mfma_f32_16x16x32_bf16(qh0, kh0, acc, 0, 0, 0);
      acc = __builtin_amdgcn_mfma_f32_16x16x32_bf16(qh1, kh1, acc, 0, 0, 0);
      p[sf] = acc;
    }
    __syncthreads();
    float ee[4], ft[4];
    #pragma unroll
    for (int sf = 0; sf < 4; ++sf) ee[sf] = __expf(a_lds[sf * 16 + lr] - am);
    #pragma unroll
    for (int r = 0; r < 4; ++r) ft[r] = __expf(fminf(am - Mt[r], 80.f));
    #pragma unroll
    for (int sf = 0; sf < 4; ++sf) {
      int s = s0 + sf * 16 + lr;
      int sc_ = sf * 2 + (lr >> 3), sb = lr & 7;
      #pragma unroll
      for (int r = 0; r < 4; ++r) {
        int tl_ = wv * 16 + lg * 4 + r;
        int t = t0 + tl_;
        float wval = (s <= t) ? p[sf][r] * ee[sf] * ft[r] : 0.f;
        wsum[r] += wval;
        u16 hi_ = f2b(wval);
        u16 lo_ = f2b(wval - b2f(hi_));
        KWh[tl_][XCH(tl_, sc_) + sb] = hi_;
        KWl[tl_][XCH(tl_, sc_) + sb] = lo_;
      }
    }
    __syncthreads();
    int tr = wv * 16 + lr;
    bf16x8 wh0 = *(const bf16x8*)&KWh[tr][XCH(tr, lg)];
    bf16x8 wh1 = *(const bf16x8*)&KWh[tr][XCH(tr, lg + 4)];
    bf16x8 wl0 = *(const bf16x8*)&KWl[tr][XCH(tr, lg)];
    bf16x8 wl1 = *(const bf16x8*)&KWl[tr][XCH(tr, lg + 4)];
    #pragma unroll
    for (int df = 0; df < 4; ++df) {
      int dr = df * 16 + lr;
      bf16x8 vh0 = *(const bf16x8*)&Vh[dr][XCH(dr, lg)];
      bf16x8 vh1 = *(const bf16x8*)&Vh[dr][XCH(dr, lg + 4)];
      bf16x8 vl0 = *(const bf16x8*)&Vl[dr][XCH(dr, lg)];
      bf16x8 vl1 = *(const bf16x8*)&Vl[dr][XCH(dr, lg + 4)];
      f32x4 a2 = hacc[df];
      a2 = __builtin_amdgcn_mfma_f32_16x16x32_bf16(wh0, vl0, a2, 0, 0, 0);
      a2 = __builtin_amdgcn_mfma_f32_16x16x32_bf16(wh1, vl1, a2, 0, 0, 0);
      a2 = __builtin_amdgcn_mfma_f32_16x16x32_bf16(wl0, vh0, a2, 0, 0, 0);
      a2 = __builtin_amdgcn_mfma_f32_16x16x32_bf16(wl1, vh1, a2, 0, 0, 0);
      a2 = __builtin_amdgcn_mfma_f32_16x16x32_bf16(wh0, vh0, a2, 0, 0, 0);
      a2 = __builtin_amdgcn_mfma_f32_16x16x32_bf16(wh1, vh1, a2, 0, 0, 0);
      hacc[df] = a2;
    }
  }
  #pragma unroll
  for (int r = 0; r < 4; ++r) {
    float sgn = wsum[r];
    sgn += __shfl_xor(sgn, 1); sgn += __shfl_xor(sgn, 2);
    sgn += __shfl_xor(sgn, 4); sgn += __shfl_xor(sgn, 8);
    wsum[r] = sgn;
  }
  float* pa = pacc + (size_t)part * BC * II;
  #pragma unroll
  for (int r = 0; r < 4; ++r) {
    int t = t0 + wv * 16 + lg * 4 + r;
    if (t < SS) {
      #pragma unroll
      for (int df = 0; df < 4; ++df)
        pa[((size_t)b * SS + t) * II + h * 64 + df * 16 + lr] = hacc[df][r];
      if (lr == 0)
        pw[(((size_t)part * BB + b) * NHH + h) * SS + t] = wsum[r];
    }
  }
}

// ---------------------------------------------------------------------------
// final: out[b,p,c] = y@Wp2^T + bp2 (y already LN'ed fp32)
// ---------------------------------------------------------------------------
__global__ __launch_bounds__(256) void final_kernel(
    const float* __restrict__ y, const float* __restrict__ Wp2,
    const float* __restrict__ bp2, float* __restrict__ out)
{
  __shared__ float yl[32 * 132];
  __shared__ float ol[96 * 32];
  int tid = threadIdx.x;
  int blk = blockIdx.x;
  int b = blk / 27, ct = blk % 27;
  int c0 = ct * 32;
  int nc = CC - c0; if (nc > 32) nc = 32;
  for (int j = 0; j < 16; ++j) {
    int idx = tid + j * 256;
    int cl = idx >> 7, d2 = idx & 127;
    yl[cl * 132 + d2] = (cl < nc) ? y[((size_t)b * CC + c0 + cl) * DD + d2] : 0.f;
  }
  __syncthreads();
  for (int j = 0; j < 12; ++j) {
    int o = tid + j * 256;
    int p = o >> 5, cl = o & 31;
    const float* wr = Wp2 + p * 128;
    float acc = bp2[p];
    #pragma unroll 8
    for (int d0 = 0; d0 < 128; d0 += 4) {
      float4 yv = *(const float4*)&yl[cl * 132 + d0];
      float4 wv = *(const float4*)&wr[d0];
      acc += yv.x * wv.x + yv.y * wv.y + yv.z * wv.z + yv.w * wv.w;
    }
    ol[p * 32 + cl] = acc;
  }
  __syncthreads();
  for (int j = 0; j < 12; ++j) {
    int o = tid + j * 256;
    int p = o >> 5, cl = o & 31;
    if (cl < nc) out[(size_t)b * PP * CC + (size_t)p * CC + c0 + cl] = ol[p * 32 + cl];
  }
}

// ---------------------------------------------------------------------------
extern "C" void kernel_launch(void* const* d_in, const int* in_sizes, int n_in,
                              void* d_out, int out_size, void* d_ws, size_t ws_size,
                              hipStream_t stream) {
  const float* xe   = (const float*)d_in[0];
  const float* Ws   = (const float*)d_in[4];
  const float* bs   = (const float*)d_in[5];
  const float* Wt_  = (const float*)d_in[6];
  const float* bt   = (const float*)d_in[7];
  const float* Wp1  = (const float*)d_in[8];
  const float* bp1  = (const float*)d_in[9];
  const float* Wp2  = (const float*)d_in[10];
  const float* bp2  = (const float*)d_in[11];
  const float* lng  = (const float*)d_in[12];
  const float* Wup  = (const float*)d_in[13];
  const float* bup  = (const float*)d_in[14];
  const float* Wcv  = (const float*)d_in[15];
  const float* bcv  = (const float*)d_in[16];
  const float* Wq   = (const float*)d_in[17];
  const float* Wk   = (const float*)d_in[18];
  const float* Wv   = (const float*)d_in[19];
  const float* Wi   = (const float*)d_in[20];
  const float* bi   = (const float*)d_in[21];
  const float* Wf   = (const float*)d_in[22];
  const float* bf_  = (const float*)d_in[23];
  const float* mhg  = (const float*)d_in[24];
  const float* skp  = (const float*)d_in[25];
  const float* Wdn  = (const float*)d_in[26];
  const float* bdn  = (const float*)d_in[27];
  const float* pg   = (const float*)d_in[28];
  float* out = (float*)d_out;

  float* w   = (float*)d_ws;
  float* x   = w;                       // [6896,128]
  float* y   = x   + 882688;
  float* up  = y   + 882688;            // [6896,512]  (aliased by A_head bf16)
  float* xc  = up  + 3530752;           // [6896,256]
  float* pacc = xc + 1765376;           // [2][6896,256] partial attn acc
  float* pw  = pacc + 3530752;          // [2][8][4][862]
  float* ig  = pw  + 55168;
  float* fg  = ig  + 27584;
  float* cum = fg  + 27584;
  float* aab = cum + 27584;
  float* MMb = aab + 27584;
  float* hbias = MMb + 27584;
  float* Gc  = hbias + 128;             // [2][256][8]
  float* Gv  = Gc + 4096;
  u16* ub    = (u16*)(Gv + 4096);
  u16* y_bf  = ub;            ub += 6896 * 128;
  u16* xc_bf = ub;            ub += 6896 * 256;
  u16* xin_bf = ub;           ub += 6896 * 256;
  u16* qkh   = ub;            ub += 6896 * 512;
  u16* qkl   = ub;            ub += 6896 * 512;
  u16* vhT   = ub;            ub += 8 * 256 * VTS;
  u16* vlT   = ub;            ub += 8 * 256 * VTS;
  u16* BTh   = ub;            ub += 131072;
  u16* WupT  = ub;            ub += 131072;
  u16* WqkT  = ub;            ub += 262144;
  u16* WvT   = ub;            ub += 131072;
  u16* WdnT  = ub;            ub += 65536;
  u16* Ah = (u16*)up;                   // A_head aliases up

  // merged weight prep
  prep_kernel<<<1665, 256, 0, stream>>>(
      Wup, Wq, Wk, Wv, Wdn, Ws, Wt_, Wp1, bs, bt, bp1, Wi, Wf,
      WupT, WqkT, WvT, WdnT, BTh, hbias, Gc, Gv);

  // head: x = A_head @ BTh + hbias, then y_bf = LN(x) with blk0 gains
  ta_kernel<<<432, 256, 0, stream>>>(xe, Ah);
  gemm_ln<0, 0, 0><<<216, 256, 0, stream>>>(
      Ah, 1024, BTh, 1024, x, hbias, lng, nullptr, y_bf, BC, 1024,
      nullptr, nullptr, nullptr, nullptr, nullptr, nullptr, nullptr, nullptr);

  for (int blk = 0; blk < 2; ++blk) {
    gemm_bf16<0><<<dim3(8, 108), 256, 0, stream>>>(
        y_bf, 128, WupT + blk * 65536, 128, up, 512, bup + blk * 512, BC, 512, 128);
    conv_gates_kernel<<<6896, 256, 0, stream>>>(
        up, Wcv + blk * 1024, bcv + blk * 256, Gc + blk * 2048, Gv + blk * 2048,
        bi + blk * 4, bf_ + blk * 4, xc, xc_bf, xin_bf, ig, fg);
    qkv_scan_kernel<<<1328, 256, 0, stream>>>(
        xc_bf, xin_bf, WqkT + blk * 131072, WvT + blk * 65536,
        qkh, qkl, vhT, vlT, fg, ig, cum, aab, MMb);
    attn_kernel<<<NITEMS2, 256, 0, stream>>>(qkh, qkl, vhT, vlT, aab, MMb, pacc, pw);
    // dn GEMM + fused combine/mhln on A-stage + residual + LN epilogue
    if (blk == 0)
      gemm_ln<1, 0, 1><<<216, 256, 0, stream>>>(
          nullptr, 0, WdnT, 256, x, bdn, lng + 128, nullptr, y_bf, BC, 256,
          pacc, pw, cum, MMb, up, xc, mhg, skp);
    else
      gemm_ln<1, 1, 1><<<216, 256, 0, stream>>>(
          nullptr, 0, WdnT + 32768, 256, x, bdn + 128, pg, y, nullptr, BC, 256,
          pacc, pw, cum, MMb, up, xc, mhg + 256, skp + 256);
  }

  final_kernel<<<216, 256, 0, stream>>>(y, Wp2, bp2, out);
}

// Round 16
// 250.542 us; speedup vs baseline: 1.1042x; 1.0189x over previous
//
#include <hip/hip_runtime.h>
#include <math.h>

#define BB 8
#define LL 512
#define CC 862
#define PP 96
#define DD 128
#define II 256
#define NHH 4
#define DHH 64
#define SS 862
#define BC (BB*CC)
#define VTS 864          // padded V^T row stride
#define NITEMS2 896      // attn work items = 28 pairs * 32 bh

typedef unsigned short u16;
using bf16x8 = __attribute__((ext_vector_type(8))) short;
using f32x4  = __attribute__((ext_vector_type(4))) float;

__device__ __forceinline__ u16 f2b(float x) {
  union { float f; unsigned u; } v; v.f = x;
  unsigned r = v.u + 0x7FFF + ((v.u >> 16) & 1);
  return (u16)(r >> 16);
}
__device__ __forceinline__ float b2f(u16 h) {
  union { unsigned u; float f; } v; v.u = ((unsigned)h) << 16;
  return v.f;
}

// chunk-XOR swizzle: u16 offset of 16B-chunk c within row r of a [64][64] tile
#define XCH(r, c) ((((c) ^ ((r) & 7)) << 3))

// ---------------------------------------------------------------------------
// merged prep + ta kernel.  gb<640: tc; <1152: gcomb; ==1152: hbias;
// <1665: gprep; >=1665: ta (transpose + moving-average -> A_head bf16).
// ---------------------------------------------------------------------------
__global__ __launch_bounds__(256) void prep_ta_kernel(
    const float* __restrict__ Wup, const float* __restrict__ Wq,
    const float* __restrict__ Wk, const float* __restrict__ Wv,
    const float* __restrict__ Wdn, const float* __restrict__ Ws,
    const float* __restrict__ Wt, const float* __restrict__ Wp1,
    const float* __restrict__ bs, const float* __restrict__ bt,
    const float* __restrict__ bp1, const float* __restrict__ Wi,
    const float* __restrict__ Wf, const float* __restrict__ xe,
    u16* __restrict__ WupT, u16* __restrict__ WqkT,
    u16* __restrict__ WvT, u16* __restrict__ WdnT,
    u16* __restrict__ BTh, float* __restrict__ hbias,
    float* __restrict__ Gc, float* __restrict__ Gv,
    u16* __restrict__ Ah)
{
  __shared__ float smem[16 * 545 + 16 * 517];
  int gb = blockIdx.x;
  int tid = threadIdx.x;
  if (gb >= 1665) {
    // ---- ta role ----
    float (*xel)[545] = (float(*)[545])smem;
    float (*mml)[517] = (float(*)[517])(smem + 16 * 545);
    int bx = gb - 1665;
    int b = bx / 54, ct = bx % 54;
    int c0 = ct * 16;
    for (int j = 0; j < 34; ++j) {
      int idx = tid + j * 256;
      if (idx < 8576) {
        int li = idx >> 4, cc = idx & 15;
        int l = li - 12; l = l < 0 ? 0 : (l > 511 ? 511 : l);
        int c = c0 + cc; if (c > 861) c = 861;
        xel[cc][li] = xe[((size_t)b * LL + l) * CC + c];
      }
    }
    __syncthreads();
    {
      int cl = tid & 15;
      int l0 = (tid >> 4) * 32;
      float win = 0.f;
      #pragma unroll 5
      for (int o = 0; o < 25; ++o) win += xel[cl][l0 + o];
      mml[cl][l0] = win * (1.f / 25.f);
      for (int i = 1; i < 32; ++i) {
        win += xel[cl][l0 + 24 + i] - xel[cl][l0 + i - 1];
        mml[cl][l0 + i] = win * (1.f / 25.f);
      }
    }
    __syncthreads();
    for (int j = 0; j < 32; ++j) {
      int idx = tid + j * 256;
      int cr = idx >> 9, l = idx & 511;
      int c = c0 + cr;
      if (c < CC) {
        size_t base = ((size_t)b * CC + c) * 1024;
        Ah[base + l] = f2b(xel[cr][12 + l]);
        Ah[base + 512 + l] = f2b(mml[cr][l]);
      }
    }
    return;
  }
  if (gb < 640) {
    float (*t)[33] = (float(*)[33])smem;
    int bx = gb & 63, by = gb >> 6;
    const float* src; u16* dst; int R, Cn; float scl = 1.f;
    switch (by) {
      case 0: src = Wup;          dst = WupT;            R = 128; Cn = 512; break;
      case 1: src = Wup + 65536;  dst = WupT + 65536;    R = 128; Cn = 512; break;
      case 2: src = Wq;           dst = WqkT;            R = 256; Cn = 256; scl = 0.125f; break;
      case 3: src = Wk;           dst = WqkT + 65536;    R = 256; Cn = 256; break;
      case 4: src = Wq + 65536;   dst = WqkT + 131072;   R = 256; Cn = 256; scl = 0.125f; break;
      case 5: src = Wk + 65536;   dst = WqkT + 196608;   R = 256; Cn = 256; break;
      case 6: src = Wv;           dst = WvT;             R = 256; Cn = 256; break;
      case 7: src = Wv + 65536;   dst = WvT + 65536;     R = 256; Cn = 256; break;
      case 8: src = Wdn;          dst = WdnT;            R = 256; Cn = 128; break;
      default: src = Wdn + 32768; dst = WdnT + 32768;    R = 256; Cn = 128; break;
    }
    int tpr = Cn >> 5;
    int tx = bx % tpr, ty_ = bx / tpr;
    if (ty_ >= (R >> 5)) return;
    int r0 = ty_ * 32, c0 = tx * 32;
    int cr = tid >> 5, cc = tid & 31;
    #pragma unroll
    for (int rr = 0; rr < 4; ++rr)
      t[cr + rr * 8][cc] = src[(size_t)(r0 + cr + rr * 8) * Cn + c0 + cc];
    __syncthreads();
    #pragma unroll
    for (int rr = 0; rr < 4; ++rr)
      dst[(size_t)(c0 + cr + rr * 8) * R + r0 + cc] = f2b(t[cc][cr + rr * 8] * scl);
  } else if (gb < 1152) {
    int i2 = gb - 640;
    int d = i2 & 127, byy = i2 >> 7;
    int lp = byy * 256 + tid;
    const float* wp = Wp1 + d * 96;
    float acc = 0.f;
    if (lp < 512) {
      for (int p = 0; p < 96; ++p) acc += Ws[p * 512 + lp] * wp[p];
    } else {
      int l = lp - 512;
      for (int p = 0; p < 96; ++p) acc += (Wt[p * 512 + l] - Ws[p * 512 + l]) * wp[p];
    }
    BTh[(size_t)d * 1024 + lp] = f2b(acc);
  } else if (gb == 1152) {
    if (tid < 128) {
      float acc = bp1[tid];
      for (int p = 0; p < 96; ++p) acc += (bs[p] + bt[p]) * Wp1[tid * 96 + p];
      hbias[tid] = acc;
    }
  } else {
    float (*red)[16] = (float(*)[16])smem;
    int i2 = gb - 1153;
    int i = i2 & 255, blk = i2 >> 8;
    int j = tid;
    float wq = Wq[(size_t)blk * 65536 + i * 256 + j];
    float wk = Wk[(size_t)blk * 65536 + i * 256 + j];
    float wv = Wv[(size_t)blk * 65536 + i * 256 + j];
    const float* wi = Wi + blk * 3072;
    const float* wf = Wf + blk * 3072;
    float pc[8], pv[8];
    #pragma unroll
    for (int o = 0; o < 4; ++o) {
      pc[o]     = wq * wi[j * 4 + o] + wk * wi[(256 + j) * 4 + o];
      pc[4 + o] = wq * wf[j * 4 + o] + wk * wf[(256 + j) * 4 + o];
      pv[o]     = wv * wi[(512 + j) * 4 + o];
      pv[4 + o] = wv * wf[(512 + j) * 4 + o];
    }
    #pragma unroll
    for (int o = 0; o < 8; ++o)
      #pragma unroll
      for (int d = 1; d < 64; d <<= 1) {
        pc[o] += __shfl_xor(pc[o], d);
        pv[o] += __shfl_xor(pv[o], d);
      }
    int wv_ = j >> 6, lane = j & 63;
    if (lane == 0) {
      #pragma unroll
      for (int o = 0; o < 8; ++o) { red[wv_][o] = pc[o]; red[wv_][8 + o] = pv[o]; }
    }
    __syncthreads();
    if (j < 16) {
      float s4 = red[0][j] + red[1][j] + red[2][j] + red[3][j];
      if (j < 8) Gc[((size_t)blk * 256 + i) * 8 + j] = s4;
      else       Gv[((size_t)blk * 256 + i) * 8 + j - 8] = s4;
    }
  }
}

// ---------------------------------------------------------------------------
// bf16 MFMA GEMM core loop as a device function (BK=64, 64x64 tile)
// ---------------------------------------------------------------------------
__device__ __forceinline__ void gemm_core(
    const u16* __restrict__ A, int lda, const u16* __restrict__ BT, int ldbt,
    int M, int K, int m0, int n0, int tid,
    u16 (*As0)[40], u16 (*As1)[40], u16 (*Bs0)[40], u16 (*Bs1)[40],
    f32x4 acc[2][2])
{
  int wv = tid >> 6, lane = tid & 63;
  int wr = wv >> 1, wc = wv & 1;
  int lrow = lane & 15, lk = lane >> 4;
  int arow = tid >> 2, aseg = tid & 3;
  for (int k0 = 0; k0 < K; k0 += 64) {
    int gm = m0 + arow; if (gm > M - 1) gm = M - 1;
    const u16* ap = &A[(size_t)gm * lda + k0 + aseg * 8];
    *(uint4*)&As0[arow][aseg * 8] = *(const uint4*)ap;
    *(uint4*)&As1[arow][aseg * 8] = *(const uint4*)(ap + 32);
    const u16* bp = &BT[(size_t)(n0 + arow) * ldbt + k0 + aseg * 8];
    *(uint4*)&Bs0[arow][aseg * 8] = *(const uint4*)bp;
    *(uint4*)&Bs1[arow][aseg * 8] = *(const uint4*)(bp + 32);
    __syncthreads();
    bf16x8 af[2], bfr[2];
    #pragma unroll
    for (int fm = 0; fm < 2; ++fm) af[fm] = *(const bf16x8*)&As0[wr * 32 + fm * 16 + lrow][lk * 8];
    #pragma unroll
    for (int fn = 0; fn < 2; ++fn) bfr[fn] = *(const bf16x8*)&Bs0[wc * 32 + fn * 16 + lrow][lk * 8];
    #pragma unroll
    for (int fm = 0; fm < 2; ++fm)
      #pragma unroll
      for (int fn = 0; fn < 2; ++fn)
        acc[fm][fn] = __builtin_amdgcn_mfma_f32_16x16x32_bf16(af[fm], bfr[fn], acc[fm][fn], 0, 0, 0);
    #pragma unroll
    for (int fm = 0; fm < 2; ++fm) af[fm] = *(const bf16x8*)&As1[wr * 32 + fm * 16 + lrow][lk * 8];
    #pragma unroll
    for (int fn = 0; fn < 2; ++fn) bfr[fn] = *(const bf16x8*)&Bs1[wc * 32 + fn * 16 + lrow][lk * 8];
    #pragma unroll
    for (int fm = 0; fm < 2; ++fm)
      #pragma unroll
      for (int fn = 0; fn < 2; ++fn)
        acc[fm][fn] = __builtin_amdgcn_mfma_f32_16x16x32_bf16(af[fm], bfr[fn], acc[fm][fn], 0, 0, 0);
    __syncthreads();
  }
}

// ---------------------------------------------------------------------------
// generic 64x64 GEMM kernel. MODE 0: C=AB+bias; 1: C+=AB+bias
// ---------------------------------------------------------------------------
template<int MODE>
__global__ __launch_bounds__(256) void gemm_bf16(
    const u16* __restrict__ A, int lda,
    const u16* __restrict__ BT, int ldbt,
    float* __restrict__ C, int ldc, const float* __restrict__ bias,
    int M, int N, int K)
{
  __shared__ u16 As0[64][40], As1[64][40];
  __shared__ u16 Bs0[64][40], Bs1[64][40];
  int tid = threadIdx.x;
  int m0 = blockIdx.y * 64, n0 = blockIdx.x * 64;
  f32x4 acc[2][2] = {};
  gemm_core(A, lda, BT, ldbt, M, K, m0, n0, tid, As0, As1, Bs0, Bs1, acc);
  int wv = tid >> 6, lane = tid & 63;
  int wr = wv >> 1, wc = wv & 1;
  int lrow = lane & 15, lk = lane >> 4;
  #pragma unroll
  for (int fm = 0; fm < 2; ++fm) {
    #pragma unroll
    for (int fn = 0; fn < 2; ++fn) {
      int col = n0 + wc * 32 + fn * 16 + lrow;
      #pragma unroll
      for (int r = 0; r < 4; ++r) {
        int row = m0 + wr * 32 + fm * 16 + lk * 4 + r;
        if (row < M) {
          float vv = acc[fm][fn][r];
          if (bias) vv += bias[col];
          float* cp = &C[(size_t)row * ldc + col];
          if (MODE == 1) vv += *cp;
          *cp = vv;
        }
      }
    }
  }
}

// ---------------------------------------------------------------------------
// fused GEMM(N=128) + residual + row-LayerNorm (+ optional final projection).
// 32x128 tile, 216 blocks.
// MODE 0: x = A@BT + bias; 1: x += A@BT + bias.
// FUSEC 1: A computed on the fly from attention partials (combine+mhln).
// FINAL 0: LN -> y_bf (OUTF32=0) or y fp32 (OUTF32=1).
// FINAL 1: LN -> LDS, then out[b,p,c] = LN(x)@Wp2^T + bp2 (replaces final_kernel).
// ---------------------------------------------------------------------------
template<int MODE, int OUTF32, int FUSEC, int FINAL>
__global__ __launch_bounds__(256) void gemm_ln(
    const u16* __restrict__ A, int lda,
    const u16* __restrict__ BT, int ldbt,
    float* __restrict__ x, const float* __restrict__ bias,
    const float* __restrict__ g,
    float* __restrict__ y, u16* __restrict__ y_bf,
    int M, int K,
    const float* __restrict__ pacc, const float* __restrict__ pw,
    const float* __restrict__ cumf, const float* __restrict__ MMb,
    const float* __restrict__ up2, const float* __restrict__ xc2,
    const float* __restrict__ mhg, const float* __restrict__ skip,
    const float* __restrict__ Wp2, const float* __restrict__ bp2,
    float* __restrict__ out)
{
  __shared__ u16 As0[32][40], As1[32][40];
  __shared__ u16 Bs0[128][40], Bs1[128][40];
  __shared__ float red_s[32][2], red_q[32][2];
  __shared__ float yl[32][132];
  int tid = threadIdx.x;
  int m0 = blockIdx.x * 32;
  int wv = tid >> 6, lane = tid & 63;
  int wr = wv >> 1, wc = wv & 1;       // wr: row half (16), wc: col half (64)
  int lrow = lane & 15, lk = lane >> 4;
  f32x4 acc[4] = {};
  int arow = tid >> 3, aseg7 = tid & 7;        // A: 32 rows x 8 segs
  int brow = tid >> 1, bhalf = tid & 1;        // B: 128 rows x 2 seg-pairs
  for (int k0 = 0; k0 < K; k0 += 64) {
    int gm = m0 + arow; if (gm > M - 1) gm = M - 1;
    if (FUSEC == 0) {
      const u16* ap = &A[(size_t)gm * lda + k0];
      if (aseg7 < 4) *(uint4*)&As0[arow][aseg7 * 8] = *(const uint4*)(ap + aseg7 * 8);
      else           *(uint4*)&As1[arow][(aseg7 - 4) * 8] = *(const uint4*)(ap + 32 + (aseg7 - 4) * 8);
    } else {
      // combine + per-head LN + gate, head = k0/64
      int bb = gm / SS, sx = gm - bb * SS;
      int hh = k0 >> 6;
      size_t bhS = ((size_t)bb * NHH + hh) * SS + sx;
      float wsum = pw[bhS] + pw[(size_t)BB * NHH * SS + bhS];
      float nfl = __expf(-(cumf[bhS] + MMb[bhS]));
      float rden = 1.f / fmaxf(fabsf(wsum), nfl);
      int colb = k0 + aseg7 * 8;
      const float* p0 = &pacc[(size_t)gm * II + colb];
      const float* p1 = p0 + (size_t)BC * II;
      float hv[8], sr = 0.f, sq2 = 0.f;
      #pragma unroll
      for (int j = 0; j < 8; ++j) {
        hv[j] = (p0[j] + p1[j]) * rden;
        sr += hv[j]; sq2 += hv[j] * hv[j];
      }
      sr += __shfl_xor(sr, 1); sq2 += __shfl_xor(sq2, 1);
      sr += __shfl_xor(sr, 2); sq2 += __shfl_xor(sq2, 2);
      sr += __shfl_xor(sr, 4); sq2 += __shfl_xor(sq2, 4);
      float mu = sr * (1.f / 64.f);
      float var = sq2 * (1.f / 64.f) - mu * mu;
      float rr2 = rsqrtf(var + 1e-5f);
      u16 o8[8];
      #pragma unroll
      for (int j = 0; j < 8; ++j) {
        int col = colb + j;
        float hn = (hv[j] - mu) * rr2 * mhg[col];
        float z = up2[(size_t)gm * 512 + 256 + col];
        float sil = z / (1.f + __expf(-z));
        o8[j] = f2b((hn + skip[col] * xc2[(size_t)gm * II + col]) * sil);
      }
      if (aseg7 < 4) *(uint4*)&As0[arow][aseg7 * 8] = *(const uint4*)o8;
      else           *(uint4*)&As1[arow][(aseg7 - 4) * 8] = *(const uint4*)o8;
    }
    const u16* bp = &BT[(size_t)brow * ldbt + k0];
    #pragma unroll
    for (int j = 0; j < 2; ++j) {
      int seg = bhalf * 2 + j;
      *(uint4*)&Bs0[brow][seg * 8] = *(const uint4*)(bp + seg * 8);
      *(uint4*)&Bs1[brow][seg * 8] = *(const uint4*)(bp + 32 + seg * 8);
    }
    __syncthreads();
    bf16x8 af, bfr[4];
    af = *(const bf16x8*)&As0[wr * 16 + lrow][lk * 8];
    #pragma unroll
    for (int fn = 0; fn < 4; ++fn) bfr[fn] = *(const bf16x8*)&Bs0[wc * 64 + fn * 16 + lrow][lk * 8];
    #pragma unroll
    for (int fn = 0; fn < 4; ++fn)
      acc[fn] = __builtin_amdgcn_mfma_f32_16x16x32_bf16(af, bfr[fn], acc[fn], 0, 0, 0);
    af = *(const bf16x8*)&As1[wr * 16 + lrow][lk * 8];
    #pragma unroll
    for (int fn = 0; fn < 4; ++fn) bfr[fn] = *(const bf16x8*)&Bs1[wc * 64 + fn * 16 + lrow][lk * 8];
    #pragma unroll
    for (int fn = 0; fn < 4; ++fn)
      acc[fn] = __builtin_amdgcn_mfma_f32_16x16x32_bf16(af, bfr[fn], acc[fn], 0, 0, 0);
    __syncthreads();
  }
  // epilogue: bias + residual, fp32 x write, row sums
  #pragma unroll
  for (int r = 0; r < 4; ++r) {
    int lrid = wr * 16 + lk * 4 + r;
    int grow = m0 + lrid;
    float sr = 0.f, sq = 0.f;
    #pragma unroll
    for (int fn = 0; fn < 4; ++fn) {
      int col = wc * 64 + fn * 16 + lrow;
      float vv = acc[fn][r] + bias[col];
      if (MODE == 1) vv += x[(size_t)grow * DD + col];
      acc[fn][r] = vv;
      if (grow < M) x[(size_t)grow * DD + col] = vv;
      sr += vv; sq += vv * vv;
    }
    sr += __shfl_xor(sr, 1); sq += __shfl_xor(sq, 1);
    sr += __shfl_xor(sr, 2); sq += __shfl_xor(sq, 2);
    sr += __shfl_xor(sr, 4); sq += __shfl_xor(sq, 4);
    sr += __shfl_xor(sr, 8); sq += __shfl_xor(sq, 8);
    if (lrow == 0) { red_s[lrid][wc] = sr; red_q[lrid][wc] = sq; }
  }
  __syncthreads();
  #pragma unroll
  for (int r = 0; r < 4; ++r) {
    int lrid = wr * 16 + lk * 4 + r;
    int grow = m0 + lrid;
    if (FINAL == 0 && grow >= M) continue;
    float s = red_s[lrid][0] + red_s[lrid][1];
    float q = red_q[lrid][0] + red_q[lrid][1];
    float mean = s * (1.f / 128.f);
    float var = q * (1.f / 128.f) - mean * mean;
    float rr = rsqrtf(var + 1e-5f);
    #pragma unroll
    for (int fn = 0; fn < 4; ++fn) {
      int col = wc * 64 + fn * 16 + lrow;
      float outv = (acc[fn][r] - mean) * rr * g[col];
      if (FINAL) {
        yl[lrid][col] = outv;
      } else if (OUTF32) {
        y[(size_t)grow * DD + col] = outv;
      } else {
        y_bf[(size_t)grow * DD + col] = f2b(outv);
      }
    }
  }
  if (FINAL) {
    __syncthreads();
    // out[b,p,c] = yl@Wp2^T + bp2 (same dot order as old final_kernel)
    for (int j = 0; j < 12; ++j) {
      int o = tid + j * 256;          // 3072 = 96 p x 32 rows
      int p = o >> 5, cl = o & 31;
      int grow = m0 + cl;
      if (grow >= M) continue;
      const float* wr2 = Wp2 + p * 128;
      float accf = bp2[p];
      #pragma unroll 8
      for (int d0 = 0; d0 < 128; d0 += 4) {
        float4 yv = *(const float4*)&yl[cl][d0];
        float4 wv2 = *(const float4*)&wr2[d0];
        accf += yv.x * wv2.x + yv.y * wv2.y + yv.z * wv2.z + yv.w * wv2.w;
      }
      int b = grow / SS, c = grow - b * SS;
      out[(size_t)b * PP * CC + (size_t)p * CC + c] = accf;
    }
  }
}

// ---------------------------------------------------------------------------
// per-(b,h) scan helper
// ---------------------------------------------------------------------------
__device__ __forceinline__ float logsig(float x) {
  return fminf(x, 0.f) - log1pf(__expf(-fabsf(x)));
}

// ---------------------------------------------------------------------------
// merged qk+v GEMM + gate scan.  bx<1296: GEMM (nrole=bx%12, m=bx/12);
// bx>=1296: per-(b,h) scan with 64 threads.  Rows >= BC skipped.
// ---------------------------------------------------------------------------
__global__ __launch_bounds__(256) void qkv_scan_kernel(
    const u16* __restrict__ xc_bf, const u16* __restrict__ xin_bf,
    const u16* __restrict__ WqkT, const u16* __restrict__ WvT,
    u16* __restrict__ qkh, u16* __restrict__ qkl,
    u16* __restrict__ vhT, u16* __restrict__ vlT,
    const float* __restrict__ fg, const float* __restrict__ ig,
    float* __restrict__ cumf, float* __restrict__ aa, float* __restrict__ MMb)
{
  __shared__ u16 As0[64][40], As1[64][40];
  __shared__ u16 Bs0[64][40], Bs1[64][40];
  int tid = threadIdx.x;
  int bx = blockIdx.x;
  if (bx >= 1296) {
    if (tid >= 64) return;
    int bh = bx - 1296;
    int lane = tid;
    const float* f = fg + (size_t)bh * SS;
    const float* gg = ig + (size_t)bh * SS;
    int s0 = lane * 14, s1 = s0 + 14; if (s1 > SS) s1 = SS;
    float loc = 0.f;
    for (int s = s0; s < s1; ++s) loc += logsig(f[s]);
    float v = loc;
    #pragma unroll
    for (int d = 1; d < 64; d <<= 1) { float o = __shfl_up(v, d); if (lane >= d) v += o; }
    float run = v - loc;
    float lmax = -1e30f;
    for (int s = s0; s < s1; ++s) {
      run += logsig(f[s]);
      cumf[(size_t)bh * SS + s] = run;
      float a = gg[s] - run;
      aa[(size_t)bh * SS + s] = a;
      lmax = fmaxf(lmax, a);
    }
    float mv = lmax;
    #pragma unroll
    for (int d = 1; d < 64; d <<= 1) { float o = __shfl_up(mv, d); if (lane >= d) mv = fmaxf(mv, o); }
    float em = __shfl_up(mv, 1);
    if (lane == 0) em = -1e30f;
    float runm = em;
    for (int s = s0; s < s1; ++s) {
      runm = fmaxf(runm, aa[(size_t)bh * SS + s]);
      MMb[(size_t)bh * SS + s] = runm;
    }
    return;
  }
  int m0 = (bx / 12) * 64;
  int nrole = bx % 12;
  bool is_qk = nrole < 8;
  int n0 = (is_qk ? nrole : nrole - 8) * 64;
  const u16* A  = is_qk ? xc_bf : xin_bf;
  const u16* BT = is_qk ? WqkT : WvT;
  f32x4 acc[2][2] = {};
  gemm_core(A, 256, BT, 256, BC, 256, m0, n0, tid, As0, As1, Bs0, Bs1, acc);
  int wv = tid >> 6, lane = tid & 63;
  int wr = wv >> 1, wc = wv & 1;
  int lrow = lane & 15, lk = lane >> 4;
  #pragma unroll
  for (int fm = 0; fm < 2; ++fm) {
    #pragma unroll
    for (int fn = 0; fn < 2; ++fn) {
      int col = n0 + wc * 32 + fn * 16 + lrow;
      int rbase = m0 + wr * 32 + fm * 16 + lk * 4;
      if (is_qk) {
        #pragma unroll
        for (int r = 0; r < 4; ++r) {
          int row = rbase + r;
          if (row < BC) {
            float vv = acc[fm][fn][r];
            u16 hi = f2b(vv);
            u16 lo = f2b(vv - b2f(hi));
            qkh[(size_t)row * 512 + col] = hi;
            qkl[(size_t)row * 512 + col] = lo;
          }
        }
      } else {
        u16 hi4[4], lo4[4];
        #pragma unroll
        for (int r = 0; r < 4; ++r) {
          float vv = acc[fm][fn][r];
          hi4[r] = f2b(vv);
          lo4[r] = f2b(vv - b2f(hi4[r]));
        }
        int bb0 = rbase / SS, s0_ = rbase - bb0 * SS;
        int bb3 = (rbase + 3) / SS;
        if (bb0 == bb3 && rbase + 3 < BC) {   // s0_ always even (SS=862)
          size_t o = ((size_t)bb0 * II + col) * VTS + s0_;
          *(unsigned*)&vhT[o]     = (unsigned)hi4[0] | ((unsigned)hi4[1] << 16);
          *(unsigned*)&vhT[o + 2] = (unsigned)hi4[2] | ((unsigned)hi4[3] << 16);
          *(unsigned*)&vlT[o]     = (unsigned)lo4[0] | ((unsigned)lo4[1] << 16);
          *(unsigned*)&vlT[o + 2] = (unsigned)lo4[2] | ((unsigned)lo4[3] << 16);
        } else {
          #pragma unroll
          for (int r = 0; r < 4; ++r) {
            int row = rbase + r;
            if (row < BC) {
              int bb = row / SS, s = row - bb * SS;
              size_t o = ((size_t)bb * II + col) * VTS + s;
              vhT[o] = hi4[r];
              vlT[o] = lo4[r];
            }
          }
        }
      }
    }
  }
}

// ---------------------------------------------------------------------------
// causal conv (k=4) + SiLU + fused gate preacts (via Gc/Gv)
// ---------------------------------------------------------------------------
__global__ __launch_bounds__(256) void conv_gates_kernel(
    const float* __restrict__ up, const float* __restrict__ Wc,
    const float* __restrict__ bc, const float* __restrict__ Gc,
    const float* __restrict__ Gv, const float* __restrict__ bi,
    const float* __restrict__ bfp,
    float* __restrict__ xc, u16* __restrict__ xc_bf, u16* __restrict__ xin_bf,
    float* __restrict__ ig, float* __restrict__ fg)
{
  __shared__ float red[4][8];
  int row = blockIdx.x;
  int i = threadIdx.x;
  int b = row / SS, s = row - b * SS;
  float acc = bc[i];
  float xin = 0.f;
  #pragma unroll
  for (int w2 = 0; w2 < 4; ++w2) {
    int sp = s - 3 + w2;
    if (sp >= 0) {
      float uv = up[((size_t)b * SS + sp) * 512 + i];
      acc += uv * Wc[w2 * 256 + i];
      if (w2 == 3) xin = uv;
    }
  }
  float sg = 1.f / (1.f + __expf(-acc));
  float val = acc * sg;
  xc[(size_t)row * II + i] = val;
  xc_bf[(size_t)row * II + i] = f2b(val);
  xin_bf[(size_t)row * II + i] = f2b(xin);
  float p[8];
  const float* gci = &Gc[i * 8];
  const float* gvi = &Gv[i * 8];
  #pragma unroll
  for (int o = 0; o < 8; ++o) p[o] = val * gci[o] + xin * gvi[o];
  #pragma unroll
  for (int o = 0; o < 8; ++o)
    #pragma unroll
    for (int d = 1; d < 64; d <<= 1) p[o] += __shfl_xor(p[o], d);
  int wv = i >> 6, lane = i & 63;
  if (lane == 0) {
    #pragma unroll
    for (int o = 0; o < 8; ++o) red[wv][o] = p[o];
  }
  __syncthreads();
  if (i < 8) {
    float sum = red[0][i] + red[1][i] + red[2][i] + red[3][i];
    if (i < 4) ig[((size_t)b * NHH + i) * SS + s] = sum + bi[i];
    else       fg[((size_t)b * NHH + i - 4) * SS + s] = sum + bfp[i - 4];
  }
}

// ---------------------------------------------------------------------------
// masked decay attention — split-precision MFMA, register-prefetch, 2-way
// s-split partials, W-overlay on K LDS tiles (4 barriers/tile).
// ---------------------------------------------------------------------------
__global__ __launch_bounds__(256) void attn_kernel(
    const u16* __restrict__ qkh, const u16* __restrict__ qkl,
    const u16* __restrict__ vhT, const u16* __restrict__ vlT,
    const float* __restrict__ aab, const float* __restrict__ MMb,
    float* __restrict__ pacc, float* __restrict__ pw)
{
  __shared__ u16 KWh[64][64], KWl[64][64];  // K during QK^T, then W for PV
  __shared__ u16 Vh[64][64], Vl[64][64];    // [d][s]
  __shared__ float a_lds[64];
  int tid = threadIdx.x;
  int wv = tid >> 6, lane = tid & 63;
  int lr = lane & 15, lg = lane >> 4;
  int item = blockIdx.x;
  int pp = item >> 5;                     // 0..27, heavy-first
  int tb = 13 - (pp >> 1);
  int part = pp & 1;
  int h = item & 3, b = (item >> 2) & 7;
  int t0 = tb * 64;
  int nt = tb + 1;
  int nt0 = (nt + 1) >> 1;
  int st_begin = part ? nt0 : 0;
  int st_end   = part ? nt : nt0;
  const float* aabh = aab + ((size_t)b * NHH + h) * SS;
  const float* Mbh  = MMb + ((size_t)b * NHH + h) * SS;

  int tq = t0 + wv * 16 + lr; if (tq > SS - 1) tq = SS - 1;
  const u16* qrow_h = qkh + ((size_t)b * SS + tq) * 512 + h * 64;
  const u16* qrow_l = qkl + ((size_t)b * SS + tq) * 512 + h * 64;
  bf16x8 qh0 = *(const bf16x8*)(qrow_h + lg * 8);
  bf16x8 qh1 = *(const bf16x8*)(qrow_h + 32 + lg * 8);
  bf16x8 ql0 = *(const bf16x8*)(qrow_l + lg * 8);
  bf16x8 ql1 = *(const bf16x8*)(qrow_l + 32 + lg * 8);

  float Mt[4];
  #pragma unroll
  for (int r = 0; r < 4; ++r) {
    int t = t0 + wv * 16 + lg * 4 + r; int tc = t < SS ? t : SS - 1;
    Mt[r] = Mbh[tc];
  }

  int row = tid >> 2, seg = tid & 3;
  const u16* vrow_h = vhT + ((size_t)(b * II + h * 64 + row)) * VTS + seg * 16;
  const u16* vrow_l = vlT + ((size_t)(b * II + h * 64 + row)) * VTS + seg * 16;

  f32x4 hacc[4] = {};
  float wsum[4] = {0.f, 0.f, 0.f, 0.f};

  uint4 rk0, rk1, rk2, rk3, rv0, rv1, rv2, rv3;
  float ra = -1e30f;
  if (st_begin < st_end) {
    int sg = st_begin * 64 + row;
    int sc = sg < SS ? sg : SS - 1;
    const u16* kp  = qkh + ((size_t)b * SS + sc) * 512 + 256 + h * 64 + seg * 16;
    const u16* klp = qkl + ((size_t)b * SS + sc) * 512 + 256 + h * 64 + seg * 16;
    rk0 = *(const uint4*)kp;  rk1 = *(const uint4*)(kp + 8);
    rk2 = *(const uint4*)klp; rk3 = *(const uint4*)(klp + 8);
    int sn = st_begin * 64;
    rv0 = *(const uint4*)(vrow_h + sn); rv1 = *(const uint4*)(vrow_h + sn + 8);
    rv2 = *(const uint4*)(vrow_l + sn); rv3 = *(const uint4*)(vrow_l + sn + 8);
    if (tid < 64) ra = (sn + tid < SS) ? aabh[sn + tid] : -1e30f;
  }

  for (int st = st_begin; st < st_end; ++st) {
    int s0 = st * 64;
    __syncthreads();
    *(uint4*)&KWh[row][XCH(row, 2 * seg)]     = rk0;
    *(uint4*)&KWh[row][XCH(row, 2 * seg + 1)] = rk1;
    *(uint4*)&KWl[row][XCH(row, 2 * seg)]     = rk2;
    *(uint4*)&KWl[row][XCH(row, 2 * seg + 1)] = rk3;
    *(uint4*)&Vh[row][XCH(row, 2 * seg)]     = rv0;
    *(uint4*)&Vh[row][XCH(row, 2 * seg + 1)] = rv1;
    *(uint4*)&Vl[row][XCH(row, 2 * seg)]     = rv2;
    *(uint4*)&Vl[row][XCH(row, 2 * seg + 1)] = rv3;
    if (tid < 64) a_lds[tid] = ra;
    if (st + 1 < st_end) {
      int sn = s0 + 64;
      int sg = sn + row;
      int sc = sg < SS ? sg : SS - 1;
      const u16* kp  = qkh + ((size_t)b * SS + sc) * 512 + 256 + h * 64 + seg * 16;
      const u16* klp = qkl + ((size_t)b * SS + sc) * 512 + 256 + h * 64 + seg * 16;
      rk0 = *(const uint4*)kp;  rk1 = *(const uint4*)(kp + 8);
      rk2 = *(const uint4*)klp; rk3 = *(const uint4*)(klp + 8);
      rv0 = *(const uint4*)(vrow_h + sn); rv1 = *(const uint4*)(vrow_h + sn + 8);
      rv2 = *(const uint4*)(vrow_l + sn); rv3 = *(const uint4*)(vrow_l + sn + 8);
      if (tid < 64) ra = (sn + tid < SS) ? aabh[sn + tid] : -1e30f;
    }
    __syncthreads();
    float am = a_lds[lane];
    #pragma unroll
    for (int dd = 1; dd < 64; dd <<= 1) am = fmaxf(am, __shfl_xor(am, dd));
    f32x4 p[4];
    #pragma unroll
    for (int sf = 0; sf < 4; ++sf) {
      int sr = sf * 16 + lr;
      bf16x8 kh0 = *(const bf16x8*)&KWh[sr][XCH(sr, lg)];
      bf16x8 kh1 = *(const bf16x8*)&KWh[sr][XCH(sr, lg + 4)];
      bf16x8 kl0 = *(const bf16x8*)&KWl[sr][XCH(sr, lg)];
      bf16x8 kl1 = *(const bf16x8*)&KWl[sr][XCH(sr, lg + 4)];
      f32x4 acc = {};
      acc = __builtin_amdgcn_mfma_f32_16x16x32_bf16(qh0, kl0, acc, 0, 0, 0);
      acc = __builtin_amdgcn_mfma_f32_16x16x32_bf16(qh1, kl1, acc, 0, 0, 0);
      acc = __builtin_amdgcn_mfma_f32_16x16x32_bf16(ql0, kh0, acc, 0, 0, 0);
      acc = __builtin_amdgcn_mfma_f32_16x16x32_bf16(ql1, kh1, acc, 0, 0, 0);
      acc = __builtin_amdgcn_mfma_f32_16x16x32_bf16(qh0, kh0, acc, 0, 0, 0);
      acc = __builtin_amdgcn_mfma_f32_16x16x32_bf16(qh1, kh1, acc, 0, 0, 0);
      p[sf] = acc;
    }
    __syncthreads();
    float ee[4], ft[4];
    #pragma unroll
    for (int sf = 0; sf < 4; ++sf) ee[sf] = __expf(a_lds[sf * 16 + lr] - am);
    #pragma unroll
    for (int r = 0; r < 4; ++r) ft[r] = __expf(fminf(am - Mt[r], 80.f));
    #pragma unroll
    for (int sf = 0; sf < 4; ++sf) {
      int s = s0 + sf * 16 + lr;
      int sc_ = sf * 2 + (lr >> 3), sb = lr & 7;
      #pragma unroll
      for (int r = 0; r < 4; ++r) {
        int tl_ = wv * 16 + lg * 4 + r;
        int t = t0 + tl_;
        float wval = (s <= t) ? p[sf][r] * ee[sf] * ft[r] : 0.f;
        wsum[r] += wval;
        u16 hi_ = f2b(wval);
        u16 lo_ = f2b(wval - b2f(hi_));
        KWh[tl_][XCH(tl_, sc_) + sb] = hi_;
        KWl[tl_][XCH(tl_, sc_) + sb] = lo_;
      }
    }
    __syncthreads();
    int tr = wv * 16 + lr;
    bf16x8 wh0 = *(const bf16x8*)&KWh[tr][XCH(tr, lg)];
    bf16x8 wh1 = *(const bf16x8*)&KWh[tr][XCH(tr, lg + 4)];
    bf16x8 wl0 = *(const bf16x8*)&KWl[tr][XCH(tr, lg)];
    bf16x8 wl1 = *(const bf16x8*)&KWl[tr][XCH(tr, lg + 4)];
    #pragma unroll
    for (int df = 0; df < 4; ++df) {
      int dr = df * 16 + lr;
      bf16x8 vh0 = *(const bf16x8*)&Vh[dr][XCH(dr, lg)];
      bf16x8 vh1 = *(const bf16x8*)&Vh[dr][XCH(dr, lg + 4)];
      bf16x8 vl0 = *(const bf16x8*)&Vl[dr][XCH(dr, lg)];
      bf16x8 vl1 = *(const bf16x8*)&Vl[dr][XCH(dr, lg + 4)];
      f32x4 a2 = hacc[df];
      a2 = __builtin_amdgcn_mfma_f32_16x16x32_bf16(wh0, vl0, a2, 0, 0, 0);
      a2 = __builtin_amdgcn_mfma_f32_16x16x32_bf16(wh1, vl1, a2, 0, 0, 0);
      a2 = __builtin_amdgcn_mfma_f32_16x16x32_bf16(wl0, vh0, a2, 0, 0, 0);
      a2 = __builtin_amdgcn_mfma_f32_16x16x32_bf16(wl1, vh1, a2, 0, 0, 0);
      a2 = __builtin_amdgcn_mfma_f32_16x16x32_bf16(wh0, vh0, a2, 0, 0, 0);
      a2 = __builtin_amdgcn_mfma_f32_16x16x32_bf16(wh1, vh1, a2, 0, 0, 0);
      hacc[df] = a2;
    }
  }
  #pragma unroll
  for (int r = 0; r < 4; ++r) {
    float sgn = wsum[r];
    sgn += __shfl_xor(sgn, 1); sgn += __shfl_xor(sgn, 2);
    sgn += __shfl_xor(sgn, 4); sgn += __shfl_xor(sgn, 8);
    wsum[r] = sgn;
  }
  float* pa = pacc + (size_t)part * BC * II;
  #pragma unroll
  for (int r = 0; r < 4; ++r) {
    int t = t0 + wv * 16 + lg * 4 + r;
    if (t < SS) {
      #pragma unroll
      for (int df = 0; df < 4; ++df)
        pa[((size_t)b * SS + t) * II + h * 64 + df * 16 + lr] = hacc[df][r];
      if (lr == 0)
        pw[(((size_t)part * BB + b) * NHH + h) * SS + t] = wsum[r];
    }
  }
}

// ---------------------------------------------------------------------------
extern "C" void kernel_launch(void* const* d_in, const int* in_sizes, int n_in,
                              void* d_out, int out_size, void* d_ws, size_t ws_size,
                              hipStream_t stream) {
  const float* xe   = (const float*)d_in[0];
  const float* Ws   = (const float*)d_in[4];
  const float* bs   = (const float*)d_in[5];
  const float* Wt_  = (const float*)d_in[6];
  const float* bt   = (const float*)d_in[7];
  const float* Wp1  = (const float*)d_in[8];
  const float* bp1  = (const float*)d_in[9];
  const float* Wp2  = (const float*)d_in[10];
  const float* bp2  = (const float*)d_in[11];
  const float* lng  = (const float*)d_in[12];
  const float* Wup  = (const float*)d_in[13];
  const float* bup  = (const float*)d_in[14];
  const float* Wcv  = (const float*)d_in[15];
  const float* bcv  = (const float*)d_in[16];
  const float* Wq   = (const float*)d_in[17];
  const float* Wk   = (const float*)d_in[18];
  const float* Wv   = (const float*)d_in[19];
  const float* Wi   = (const float*)d_in[20];
  const float* bi   = (const float*)d_in[21];
  const float* Wf   = (const float*)d_in[22];
  const float* bf_  = (const float*)d_in[23];
  const float* mhg  = (const float*)d_in[24];
  const float* skp  = (const float*)d_in[25];
  const float* Wdn  = (const float*)d_in[26];
  const float* bdn  = (const float*)d_in[27];
  const float* pg   = (const float*)d_in[28];
  float* out = (float*)d_out;

  float* w   = (float*)d_ws;
  float* x   = w;                       // [6896,128]
  float* y   = x   + 882688;
  float* up  = y   + 882688;            // [6896,512]  (aliased by A_head bf16)
  float* xc  = up  + 3530752;           // [6896,256]
  float* pacc = xc + 1765376;           // [2][6896,256] partial attn acc
  float* pw  = pacc + 3530752;          // [2][8][4][862]
  float* ig  = pw  + 55168;
  float* fg  = ig  + 27584;
  float* cum = fg  + 27584;
  float* aab = cum + 27584;
  float* MMb = aab + 27584;
  float* hbias = MMb + 27584;
  float* Gc  = hbias + 128;             // [2][256][8]
  float* Gv  = Gc + 4096;
  u16* ub    = (u16*)(Gv + 4096);
  u16* y_bf  = ub;            ub += 6896 * 128;
  u16* xc_bf = ub;            ub += 6896 * 256;
  u16* xin_bf = ub;           ub += 6896 * 256;
  u16* qkh   = ub;            ub += 6896 * 512;
  u16* qkl   = ub;            ub += 6896 * 512;
  u16* vhT   = ub;            ub += 8 * 256 * VTS;
  u16* vlT   = ub;            ub += 8 * 256 * VTS;
  u16* BTh   = ub;            ub += 131072;
  u16* WupT  = ub;            ub += 131072;
  u16* WqkT  = ub;            ub += 262144;
  u16* WvT   = ub;            ub += 131072;
  u16* WdnT  = ub;            ub += 65536;
  u16* Ah = (u16*)up;                   // A_head aliases up

  // merged weight prep + ta (independent roles, one dispatch)
  prep_ta_kernel<<<2097, 256, 0, stream>>>(
      Wup, Wq, Wk, Wv, Wdn, Ws, Wt_, Wp1, bs, bt, bp1, Wi, Wf, xe,
      WupT, WqkT, WvT, WdnT, BTh, hbias, Gc, Gv, Ah);

  // head: x = A_head @ BTh + hbias, then y_bf = LN(x) with blk0 gains
  gemm_ln<0, 0, 0, 0><<<216, 256, 0, stream>>>(
      Ah, 1024, BTh, 1024, x, hbias, lng, nullptr, y_bf, BC, 1024,
      nullptr, nullptr, nullptr, nullptr, nullptr, nullptr, nullptr, nullptr,
      nullptr, nullptr, nullptr);

  for (int blk = 0; blk < 2; ++blk) {
    gemm_bf16<0><<<dim3(8, 108), 256, 0, stream>>>(
        y_bf, 128, WupT + blk * 65536, 128, up, 512, bup + blk * 512, BC, 512, 128);
    conv_gates_kernel<<<6896, 256, 0, stream>>>(
        up, Wcv + blk * 1024, bcv + blk * 256, Gc + blk * 2048, Gv + blk * 2048,
        bi + blk * 4, bf_ + blk * 4, xc, xc_bf, xin_bf, ig, fg);
    qkv_scan_kernel<<<1328, 256, 0, stream>>>(
        xc_bf, xin_bf, WqkT + blk * 131072, WvT + blk * 65536,
        qkh, qkl, vhT, vlT, fg, ig, cum, aab, MMb);
    attn_kernel<<<NITEMS2, 256, 0, stream>>>(qkh, qkl, vhT, vlT, aab, MMb, pacc, pw);
    // dn GEMM + fused combine/mhln + residual + LN (+ final projection on blk1)
    if (blk == 0)
      gemm_ln<1, 0, 1, 0><<<216, 256, 0, stream>>>(
          nullptr, 0, WdnT, 256, x, bdn, lng + 128, nullptr, y_bf, BC, 256,
          pacc, pw, cum, MMb, up, xc, mhg, skp, nullptr, nullptr, nullptr);
    else
      gemm_ln<1, 0, 1, 1><<<216, 256, 0, stream>>>(
          nullptr, 0, WdnT + 32768, 256, x, bdn + 128, pg, nullptr, nullptr, BC, 256,
          pacc, pw, cum, MMb, up, xc, mhg + 256, skp + 256, Wp2, bp2, out);
  }
}

// Round 17
// 239.955 us; speedup vs baseline: 1.1530x; 1.0441x over previous
//
#include <hip/hip_runtime.h>
#include <math.h>

#define BB 8
#define LL 512
#define CC 862
#define PP 96
#define DD 128
#define II 256
#define NHH 4
#define DHH 64
#define SS 862
#define BC (BB*CC)
#define VTS 864          // padded V^T row stride
#define NITEMS2 896      // attn work items = 28 pairs * 32 bh

typedef unsigned short u16;
using bf16x8 = __attribute__((ext_vector_type(8))) short;
using f32x4  = __attribute__((ext_vector_type(4))) float;

__device__ __forceinline__ u16 f2b(float x) {
  union { float f; unsigned u; } v; v.f = x;
  unsigned r = v.u + 0x7FFF + ((v.u >> 16) & 1);
  return (u16)(r >> 16);
}
__device__ __forceinline__ float b2f(u16 h) {
  union { unsigned u; float f; } v; v.u = ((unsigned)h) << 16;
  return v.f;
}

// chunk-XOR swizzle: u16 offset of 16B-chunk c within row r of a [64][64] tile
#define XCH(r, c) ((((c) ^ ((r) & 7)) << 3))

// ---------------------------------------------------------------------------
// merged prep + ta kernel.  gb<640: tc; <1152: gcomb; ==1152: hbias;
// <1665: gprep; >=1665: ta (transpose + moving-average -> A_head bf16).
// ---------------------------------------------------------------------------
__global__ __launch_bounds__(256) void prep_ta_kernel(
    const float* __restrict__ Wup, const float* __restrict__ Wq,
    const float* __restrict__ Wk, const float* __restrict__ Wv,
    const float* __restrict__ Wdn, const float* __restrict__ Ws,
    const float* __restrict__ Wt, const float* __restrict__ Wp1,
    const float* __restrict__ bs, const float* __restrict__ bt,
    const float* __restrict__ bp1, const float* __restrict__ Wi,
    const float* __restrict__ Wf, const float* __restrict__ xe,
    u16* __restrict__ WupT, u16* __restrict__ WqkT,
    u16* __restrict__ WvT, u16* __restrict__ WdnT,
    u16* __restrict__ BTh, float* __restrict__ hbias,
    float* __restrict__ Gc, float* __restrict__ Gv,
    u16* __restrict__ Ah)
{
  __shared__ float smem[16 * 545 + 16 * 517];
  int gb = blockIdx.x;
  int tid = threadIdx.x;
  if (gb >= 1665) {
    // ---- ta role ----
    float (*xel)[545] = (float(*)[545])smem;
    float (*mml)[517] = (float(*)[517])(smem + 16 * 545);
    int bx = gb - 1665;
    int b = bx / 54, ct = bx % 54;
    int c0 = ct * 16;
    for (int j = 0; j < 34; ++j) {
      int idx = tid + j * 256;
      if (idx < 8576) {
        int li = idx >> 4, cc = idx & 15;
        int l = li - 12; l = l < 0 ? 0 : (l > 511 ? 511 : l);
        int c = c0 + cc; if (c > 861) c = 861;
        xel[cc][li] = xe[((size_t)b * LL + l) * CC + c];
      }
    }
    __syncthreads();
    {
      int cl = tid & 15;
      int l0 = (tid >> 4) * 32;
      float win = 0.f;
      #pragma unroll 5
      for (int o = 0; o < 25; ++o) win += xel[cl][l0 + o];
      mml[cl][l0] = win * (1.f / 25.f);
      for (int i = 1; i < 32; ++i) {
        win += xel[cl][l0 + 24 + i] - xel[cl][l0 + i - 1];
        mml[cl][l0 + i] = win * (1.f / 25.f);
      }
    }
    __syncthreads();
    for (int j = 0; j < 32; ++j) {
      int idx = tid + j * 256;
      int cr = idx >> 9, l = idx & 511;
      int c = c0 + cr;
      if (c < CC) {
        size_t base = ((size_t)b * CC + c) * 1024;
        Ah[base + l] = f2b(xel[cr][12 + l]);
        Ah[base + 512 + l] = f2b(mml[cr][l]);
      }
    }
    return;
  }
  if (gb < 640) {
    float (*t)[33] = (float(*)[33])smem;
    int bx = gb & 63, by = gb >> 6;
    const float* src; u16* dst; int R, Cn; float scl = 1.f;
    switch (by) {
      case 0: src = Wup;          dst = WupT;            R = 128; Cn = 512; break;
      case 1: src = Wup + 65536;  dst = WupT + 65536;    R = 128; Cn = 512; break;
      case 2: src = Wq;           dst = WqkT;            R = 256; Cn = 256; scl = 0.125f; break;
      case 3: src = Wk;           dst = WqkT + 65536;    R = 256; Cn = 256; break;
      case 4: src = Wq + 65536;   dst = WqkT + 131072;   R = 256; Cn = 256; scl = 0.125f; break;
      case 5: src = Wk + 65536;   dst = WqkT + 196608;   R = 256; Cn = 256; break;
      case 6: src = Wv;           dst = WvT;             R = 256; Cn = 256; break;
      case 7: src = Wv + 65536;   dst = WvT + 65536;     R = 256; Cn = 256; break;
      case 8: src = Wdn;          dst = WdnT;            R = 256; Cn = 128; break;
      default: src = Wdn + 32768; dst = WdnT + 32768;    R = 256; Cn = 128; break;
    }
    int tpr = Cn >> 5;
    int tx = bx % tpr, ty_ = bx / tpr;
    if (ty_ >= (R >> 5)) return;
    int r0 = ty_ * 32, c0 = tx * 32;
    int cr = tid >> 5, cc = tid & 31;
    #pragma unroll
    for (int rr = 0; rr < 4; ++rr)
      t[cr + rr * 8][cc] = src[(size_t)(r0 + cr + rr * 8) * Cn + c0 + cc];
    __syncthreads();
    #pragma unroll
    for (int rr = 0; rr < 4; ++rr)
      dst[(size_t)(c0 + cr + rr * 8) * R + r0 + cc] = f2b(t[cc][cr + rr * 8] * scl);
  } else if (gb < 1152) {
    int i2 = gb - 640;
    int d = i2 & 127, byy = i2 >> 7;
    int lp = byy * 256 + tid;
    const float* wp = Wp1 + d * 96;
    float acc = 0.f;
    if (lp < 512) {
      for (int p = 0; p < 96; ++p) acc += Ws[p * 512 + lp] * wp[p];
    } else {
      int l = lp - 512;
      for (int p = 0; p < 96; ++p) acc += (Wt[p * 512 + l] - Ws[p * 512 + l]) * wp[p];
    }
    BTh[(size_t)d * 1024 + lp] = f2b(acc);
  } else if (gb == 1152) {
    if (tid < 128) {
      float acc = bp1[tid];
      for (int p = 0; p < 96; ++p) acc += (bs[p] + bt[p]) * Wp1[tid * 96 + p];
      hbias[tid] = acc;
    }
  } else {
    float (*red)[16] = (float(*)[16])smem;
    int i2 = gb - 1153;
    int i = i2 & 255, blk = i2 >> 8;
    int j = tid;
    float wq = Wq[(size_t)blk * 65536 + i * 256 + j];
    float wk = Wk[(size_t)blk * 65536 + i * 256 + j];
    float wv = Wv[(size_t)blk * 65536 + i * 256 + j];
    const float* wi = Wi + blk * 3072;
    const float* wf = Wf + blk * 3072;
    float pc[8], pv[8];
    #pragma unroll
    for (int o = 0; o < 4; ++o) {
      pc[o]     = wq * wi[j * 4 + o] + wk * wi[(256 + j) * 4 + o];
      pc[4 + o] = wq * wf[j * 4 + o] + wk * wf[(256 + j) * 4 + o];
      pv[o]     = wv * wi[(512 + j) * 4 + o];
      pv[4 + o] = wv * wf[(512 + j) * 4 + o];
    }
    #pragma unroll
    for (int o = 0; o < 8; ++o)
      #pragma unroll
      for (int d = 1; d < 64; d <<= 1) {
        pc[o] += __shfl_xor(pc[o], d);
        pv[o] += __shfl_xor(pv[o], d);
      }
    int wv_ = j >> 6, lane = j & 63;
    if (lane == 0) {
      #pragma unroll
      for (int o = 0; o < 8; ++o) { red[wv_][o] = pc[o]; red[wv_][8 + o] = pv[o]; }
    }
    __syncthreads();
    if (j < 16) {
      float s4 = red[0][j] + red[1][j] + red[2][j] + red[3][j];
      if (j < 8) Gc[((size_t)blk * 256 + i) * 8 + j] = s4;
      else       Gv[((size_t)blk * 256 + i) * 8 + j - 8] = s4;
    }
  }
}

// ---------------------------------------------------------------------------
// bf16 MFMA GEMM core loop as a device function (BK=64, 64x64 tile)
// ---------------------------------------------------------------------------
__device__ __forceinline__ void gemm_core(
    const u16* __restrict__ A, int lda, const u16* __restrict__ BT, int ldbt,
    int M, int K, int m0, int n0, int tid,
    u16 (*As0)[40], u16 (*As1)[40], u16 (*Bs0)[40], u16 (*Bs1)[40],
    f32x4 acc[2][2])
{
  int wv = tid >> 6, lane = tid & 63;
  int wr = wv >> 1, wc = wv & 1;
  int lrow = lane & 15, lk = lane >> 4;
  int arow = tid >> 2, aseg = tid & 3;
  for (int k0 = 0; k0 < K; k0 += 64) {
    int gm = m0 + arow; if (gm > M - 1) gm = M - 1;
    const u16* ap = &A[(size_t)gm * lda + k0 + aseg * 8];
    *(uint4*)&As0[arow][aseg * 8] = *(const uint4*)ap;
    *(uint4*)&As1[arow][aseg * 8] = *(const uint4*)(ap + 32);
    const u16* bp = &BT[(size_t)(n0 + arow) * ldbt + k0 + aseg * 8];
    *(uint4*)&Bs0[arow][aseg * 8] = *(const uint4*)bp;
    *(uint4*)&Bs1[arow][aseg * 8] = *(const uint4*)(bp + 32);
    __syncthreads();
    bf16x8 af[2], bfr[2];
    #pragma unroll
    for (int fm = 0; fm < 2; ++fm) af[fm] = *(const bf16x8*)&As0[wr * 32 + fm * 16 + lrow][lk * 8];
    #pragma unroll
    for (int fn = 0; fn < 2; ++fn) bfr[fn] = *(const bf16x8*)&Bs0[wc * 32 + fn * 16 + lrow][lk * 8];
    #pragma unroll
    for (int fm = 0; fm < 2; ++fm)
      #pragma unroll
      for (int fn = 0; fn < 2; ++fn)
        acc[fm][fn] = __builtin_amdgcn_mfma_f32_16x16x32_bf16(af[fm], bfr[fn], acc[fm][fn], 0, 0, 0);
    #pragma unroll
    for (int fm = 0; fm < 2; ++fm) af[fm] = *(const bf16x8*)&As1[wr * 32 + fm * 16 + lrow][lk * 8];
    #pragma unroll
    for (int fn = 0; fn < 2; ++fn) bfr[fn] = *(const bf16x8*)&Bs1[wc * 32 + fn * 16 + lrow][lk * 8];
    #pragma unroll
    for (int fm = 0; fm < 2; ++fm)
      #pragma unroll
      for (int fn = 0; fn < 2; ++fn)
        acc[fm][fn] = __builtin_amdgcn_mfma_f32_16x16x32_bf16(af[fm], bfr[fn], acc[fm][fn], 0, 0, 0);
    __syncthreads();
  }
}

// ---------------------------------------------------------------------------
// generic 64x64 GEMM kernel. MODE 0: C=AB+bias; 1: C+=AB+bias
// ---------------------------------------------------------------------------
template<int MODE>
__global__ __launch_bounds__(256) void gemm_bf16(
    const u16* __restrict__ A, int lda,
    const u16* __restrict__ BT, int ldbt,
    float* __restrict__ C, int ldc, const float* __restrict__ bias,
    int M, int N, int K)
{
  __shared__ u16 As0[64][40], As1[64][40];
  __shared__ u16 Bs0[64][40], Bs1[64][40];
  int tid = threadIdx.x;
  int m0 = blockIdx.y * 64, n0 = blockIdx.x * 64;
  f32x4 acc[2][2] = {};
  gemm_core(A, lda, BT, ldbt, M, K, m0, n0, tid, As0, As1, Bs0, Bs1, acc);
  int wv = tid >> 6, lane = tid & 63;
  int wr = wv >> 1, wc = wv & 1;
  int lrow = lane & 15, lk = lane >> 4;
  #pragma unroll
  for (int fm = 0; fm < 2; ++fm) {
    #pragma unroll
    for (int fn = 0; fn < 2; ++fn) {
      int col = n0 + wc * 32 + fn * 16 + lrow;
      #pragma unroll
      for (int r = 0; r < 4; ++r) {
        int row = m0 + wr * 32 + fm * 16 + lk * 4 + r;
        if (row < M) {
          float vv = acc[fm][fn][r];
          if (bias) vv += bias[col];
          float* cp = &C[(size_t)row * ldc + col];
          if (MODE == 1) vv += *cp;
          *cp = vv;
        }
      }
    }
  }
}

// ---------------------------------------------------------------------------
// fused GEMM(N=128) + residual + row-LayerNorm (+ optional final projection),
// with register-prefetch staging pipeline (T14: issue next chunk's loads
// before the barrier; latency hides under MFMA).  32x128 tile, 216 blocks.
// MODE 0: x = A@BT + bias; 1: x += A@BT + bias.
// FUSEC 1: A computed on the fly from attention partials (combine+mhln).
// FINAL 0: LN -> y_bf (OUTF32=0) or y fp32 (OUTF32=1).
// FINAL 1: LN -> LDS, then out[b,p,c] = LN(x)@Wp2^T + bp2.
// ---------------------------------------------------------------------------
template<int MODE, int OUTF32, int FUSEC, int FINAL>
__global__ __launch_bounds__(256) void gemm_ln(
    const u16* __restrict__ A, int lda,
    const u16* __restrict__ BT, int ldbt,
    float* __restrict__ x, const float* __restrict__ bias,
    const float* __restrict__ g,
    float* __restrict__ y, u16* __restrict__ y_bf,
    int M, int K,
    const float* __restrict__ pacc, const float* __restrict__ pw,
    const float* __restrict__ cumf, const float* __restrict__ MMb,
    const float* __restrict__ up2, const float* __restrict__ xc2,
    const float* __restrict__ mhg, const float* __restrict__ skip,
    const float* __restrict__ Wp2, const float* __restrict__ bp2,
    float* __restrict__ out)
{
  __shared__ u16 As0[32][40], As1[32][40];
  __shared__ u16 Bs0[128][40], Bs1[128][40];
  __shared__ float red_s[32][2], red_q[32][2];
  __shared__ float yl[32][132];
  int tid = threadIdx.x;
  int m0 = blockIdx.x * 32;
  int wv = tid >> 6, lane = tid & 63;
  int wr = wv >> 1, wc = wv & 1;       // wr: row half (16), wc: col half (64)
  int lrow = lane & 15, lk = lane >> 4;
  f32x4 acc[4] = {};
  int arow = tid >> 3, aseg7 = tid & 7;        // A: 32 rows x 8 segs
  int brow = tid >> 1, bhalf = tid & 1;        // B: 128 rows x 2 seg-pairs
  int gm = m0 + arow; if (gm > M - 1) gm = M - 1;
  int bbr = 0, sxr = 0;
  if (FUSEC) { bbr = gm / SS; sxr = gm - bbr * SS; }
  const u16* bbase = &BT[(size_t)brow * ldbt];
  int bseg = bhalf * 2;

  // prefetch registers
  uint4 ra;
  float4 rp0a, rp0b, rp1a, rp1b, rupa, rupb, rxca, rxcb;
  float rpwA, rpwB, rcum, rmm;
  uint4 rb0, rb1, rb2, rb3;

  // load chunk 0
  {
    const int k0 = 0;
    if (FUSEC == 0) {
      ra = *(const uint4*)(&A[(size_t)gm * lda + k0] + aseg7 * 8);
    } else {
      int hh = k0 >> 6;
      size_t bhS = ((size_t)bbr * NHH + hh) * SS + sxr;
      rpwA = pw[bhS]; rpwB = pw[(size_t)BB * NHH * SS + bhS];
      rcum = cumf[bhS]; rmm = MMb[bhS];
      int colb = k0 + aseg7 * 8;
      const float* p0 = &pacc[(size_t)gm * II + colb];
      rp0a = *(const float4*)p0; rp0b = *(const float4*)(p0 + 4);
      const float* p1 = p0 + (size_t)BC * II;
      rp1a = *(const float4*)p1; rp1b = *(const float4*)(p1 + 4);
      const float* upp = &up2[(size_t)gm * 512 + 256 + colb];
      rupa = *(const float4*)upp; rupb = *(const float4*)(upp + 4);
      const float* xcp = &xc2[(size_t)gm * II + colb];
      rxca = *(const float4*)xcp; rxcb = *(const float4*)(xcp + 4);
    }
    const u16* bp = bbase + k0;
    rb0 = *(const uint4*)(bp + bseg * 8);
    rb1 = *(const uint4*)(bp + (bseg + 1) * 8);
    rb2 = *(const uint4*)(bp + 32 + bseg * 8);
    rb3 = *(const uint4*)(bp + 32 + (bseg + 1) * 8);
  }

  for (int k0 = 0; k0 < K; k0 += 64) {
    // ---- write staged regs -> LDS ----
    if (FUSEC == 0) {
      if (aseg7 < 4) *(uint4*)&As0[arow][aseg7 * 8] = ra;
      else           *(uint4*)&As1[arow][(aseg7 - 4) * 8] = ra;
    } else {
      float rden = 1.f / fmaxf(fabsf(rpwA + rpwB), __expf(-(rcum + rmm)));
      float a0[8] = {rp0a.x, rp0a.y, rp0a.z, rp0a.w, rp0b.x, rp0b.y, rp0b.z, rp0b.w};
      float a1[8] = {rp1a.x, rp1a.y, rp1a.z, rp1a.w, rp1b.x, rp1b.y, rp1b.z, rp1b.w};
      float uu[8] = {rupa.x, rupa.y, rupa.z, rupa.w, rupb.x, rupb.y, rupb.z, rupb.w};
      float xx[8] = {rxca.x, rxca.y, rxca.z, rxca.w, rxcb.x, rxcb.y, rxcb.z, rxcb.w};
      float hv[8], sr = 0.f, sq2 = 0.f;
      #pragma unroll
      for (int j = 0; j < 8; ++j) {
        hv[j] = (a0[j] + a1[j]) * rden;
        sr += hv[j]; sq2 += hv[j] * hv[j];
      }
      sr += __shfl_xor(sr, 1); sq2 += __shfl_xor(sq2, 1);
      sr += __shfl_xor(sr, 2); sq2 += __shfl_xor(sq2, 2);
      sr += __shfl_xor(sr, 4); sq2 += __shfl_xor(sq2, 4);
      float mu = sr * (1.f / 64.f);
      float var = sq2 * (1.f / 64.f) - mu * mu;
      float rr2 = rsqrtf(var + 1e-5f);
      int colb = k0 + aseg7 * 8;
      u16 o8[8];
      #pragma unroll
      for (int j = 0; j < 8; ++j) {
        int col = colb + j;
        float hn = (hv[j] - mu) * rr2 * mhg[col];
        float sil = uu[j] / (1.f + __expf(-uu[j]));
        o8[j] = f2b((hn + skip[col] * xx[j]) * sil);
      }
      if (aseg7 < 4) *(uint4*)&As0[arow][aseg7 * 8] = *(const uint4*)o8;
      else           *(uint4*)&As1[arow][(aseg7 - 4) * 8] = *(const uint4*)o8;
    }
    *(uint4*)&Bs0[brow][bseg * 8] = rb0;
    *(uint4*)&Bs0[brow][(bseg + 1) * 8] = rb1;
    *(uint4*)&Bs1[brow][bseg * 8] = rb2;
    *(uint4*)&Bs1[brow][(bseg + 1) * 8] = rb3;
    // ---- issue next chunk's loads (latency hides under MFMA) ----
    if (k0 + 64 < K) {
      int kn = k0 + 64;
      if (FUSEC == 0) {
        ra = *(const uint4*)(&A[(size_t)gm * lda + kn] + aseg7 * 8);
      } else {
        int hh = kn >> 6;
        size_t bhS = ((size_t)bbr * NHH + hh) * SS + sxr;
        rpwA = pw[bhS]; rpwB = pw[(size_t)BB * NHH * SS + bhS];
        rcum = cumf[bhS]; rmm = MMb[bhS];
        int colb = kn + aseg7 * 8;
        const float* p0 = &pacc[(size_t)gm * II + colb];
        rp0a = *(const float4*)p0; rp0b = *(const float4*)(p0 + 4);
        const float* p1 = p0 + (size_t)BC * II;
        rp1a = *(const float4*)p1; rp1b = *(const float4*)(p1 + 4);
        const float* upp = &up2[(size_t)gm * 512 + 256 + colb];
        rupa = *(const float4*)upp; rupb = *(const float4*)(upp + 4);
        const float* xcp = &xc2[(size_t)gm * II + colb];
        rxca = *(const float4*)xcp; rxcb = *(const float4*)(xcp + 4);
      }
      const u16* bp = bbase + kn;
      rb0 = *(const uint4*)(bp + bseg * 8);
      rb1 = *(const uint4*)(bp + (bseg + 1) * 8);
      rb2 = *(const uint4*)(bp + 32 + bseg * 8);
      rb3 = *(const uint4*)(bp + 32 + (bseg + 1) * 8);
    }
    __syncthreads();
    bf16x8 af, bfr[4];
    af = *(const bf16x8*)&As0[wr * 16 + lrow][lk * 8];
    #pragma unroll
    for (int fn = 0; fn < 4; ++fn) bfr[fn] = *(const bf16x8*)&Bs0[wc * 64 + fn * 16 + lrow][lk * 8];
    #pragma unroll
    for (int fn = 0; fn < 4; ++fn)
      acc[fn] = __builtin_amdgcn_mfma_f32_16x16x32_bf16(af, bfr[fn], acc[fn], 0, 0, 0);
    af = *(const bf16x8*)&As1[wr * 16 + lrow][lk * 8];
    #pragma unroll
    for (int fn = 0; fn < 4; ++fn) bfr[fn] = *(const bf16x8*)&Bs1[wc * 64 + fn * 16 + lrow][lk * 8];
    #pragma unroll
    for (int fn = 0; fn < 4; ++fn)
      acc[fn] = __builtin_amdgcn_mfma_f32_16x16x32_bf16(af, bfr[fn], acc[fn], 0, 0, 0);
    __syncthreads();
  }
  // epilogue: bias + residual, fp32 x write, row sums
  #pragma unroll
  for (int r = 0; r < 4; ++r) {
    int lrid = wr * 16 + lk * 4 + r;
    int grow = m0 + lrid;
    float sr = 0.f, sq = 0.f;
    #pragma unroll
    for (int fn = 0; fn < 4; ++fn) {
      int col = wc * 64 + fn * 16 + lrow;
      float vv = acc[fn][r] + bias[col];
      if (MODE == 1) vv += x[(size_t)grow * DD + col];
      acc[fn][r] = vv;
      if (grow < M) x[(size_t)grow * DD + col] = vv;
      sr += vv; sq += vv * vv;
    }
    sr += __shfl_xor(sr, 1); sq += __shfl_xor(sq, 1);
    sr += __shfl_xor(sr, 2); sq += __shfl_xor(sq, 2);
    sr += __shfl_xor(sr, 4); sq += __shfl_xor(sq, 4);
    sr += __shfl_xor(sr, 8); sq += __shfl_xor(sq, 8);
    if (lrow == 0) { red_s[lrid][wc] = sr; red_q[lrid][wc] = sq; }
  }
  __syncthreads();
  #pragma unroll
  for (int r = 0; r < 4; ++r) {
    int lrid = wr * 16 + lk * 4 + r;
    int grow = m0 + lrid;
    if (FINAL == 0 && grow >= M) continue;
    float s = red_s[lrid][0] + red_s[lrid][1];
    float q = red_q[lrid][0] + red_q[lrid][1];
    float mean = s * (1.f / 128.f);
    float var = q * (1.f / 128.f) - mean * mean;
    float rr = rsqrtf(var + 1e-5f);
    #pragma unroll
    for (int fn = 0; fn < 4; ++fn) {
      int col = wc * 64 + fn * 16 + lrow;
      float outv = (acc[fn][r] - mean) * rr * g[col];
      if (FINAL) {
        yl[lrid][col] = outv;
      } else if (OUTF32) {
        y[(size_t)grow * DD + col] = outv;
      } else {
        y_bf[(size_t)grow * DD + col] = f2b(outv);
      }
    }
  }
  if (FINAL) {
    __syncthreads();
    // out[b,p,c] = yl@Wp2^T + bp2 (same dot order as old final_kernel)
    for (int j = 0; j < 12; ++j) {
      int o = tid + j * 256;          // 3072 = 96 p x 32 rows
      int p = o >> 5, cl = o & 31;
      int grow = m0 + cl;
      if (grow >= M) continue;
      const float* wr2 = Wp2 + p * 128;
      float accf = bp2[p];
      #pragma unroll 8
      for (int d0 = 0; d0 < 128; d0 += 4) {
        float4 yv = *(const float4*)&yl[cl][d0];
        float4 wv2 = *(const float4*)&wr2[d0];
        accf += yv.x * wv2.x + yv.y * wv2.y + yv.z * wv2.z + yv.w * wv2.w;
      }
      int b = grow / SS, c = grow - b * SS;
      out[(size_t)b * PP * CC + (size_t)p * CC + c] = accf;
    }
  }
}

// ---------------------------------------------------------------------------
// per-(b,h) scan helper
// ---------------------------------------------------------------------------
__device__ __forceinline__ float logsig(float x) {
  return fminf(x, 0.f) - log1pf(__expf(-fabsf(x)));
}

// ---------------------------------------------------------------------------
// merged qk+v GEMM + gate scan.  bx<1296: GEMM (nrole=bx%12, m=bx/12);
// bx>=1296: per-(b,h) scan with 64 threads.  Rows >= BC skipped.
// ---------------------------------------------------------------------------
__global__ __launch_bounds__(256) void qkv_scan_kernel(
    const u16* __restrict__ xc_bf, const u16* __restrict__ xin_bf,
    const u16* __restrict__ WqkT, const u16* __restrict__ WvT,
    u16* __restrict__ qkh, u16* __restrict__ qkl,
    u16* __restrict__ vhT, u16* __restrict__ vlT,
    const float* __restrict__ fg, const float* __restrict__ ig,
    float* __restrict__ cumf, float* __restrict__ aa, float* __restrict__ MMb)
{
  __shared__ u16 As0[64][40], As1[64][40];
  __shared__ u16 Bs0[64][40], Bs1[64][40];
  int tid = threadIdx.x;
  int bx = blockIdx.x;
  if (bx >= 1296) {
    if (tid >= 64) return;
    int bh = bx - 1296;
    int lane = tid;
    const float* f = fg + (size_t)bh * SS;
    const float* gg = ig + (size_t)bh * SS;
    int s0 = lane * 14, s1 = s0 + 14; if (s1 > SS) s1 = SS;
    float loc = 0.f;
    for (int s = s0; s < s1; ++s) loc += logsig(f[s]);
    float v = loc;
    #pragma unroll
    for (int d = 1; d < 64; d <<= 1) { float o = __shfl_up(v, d); if (lane >= d) v += o; }
    float run = v - loc;
    float lmax = -1e30f;
    for (int s = s0; s < s1; ++s) {
      run += logsig(f[s]);
      cumf[(size_t)bh * SS + s] = run;
      float a = gg[s] - run;
      aa[(size_t)bh * SS + s] = a;
      lmax = fmaxf(lmax, a);
    }
    float mv = lmax;
    #pragma unroll
    for (int d = 1; d < 64; d <<= 1) { float o = __shfl_up(mv, d); if (lane >= d) mv = fmaxf(mv, o); }
    float em = __shfl_up(mv, 1);
    if (lane == 0) em = -1e30f;
    float runm = em;
    for (int s = s0; s < s1; ++s) {
      runm = fmaxf(runm, aa[(size_t)bh * SS + s]);
      MMb[(size_t)bh * SS + s] = runm;
    }
    return;
  }
  int m0 = (bx / 12) * 64;
  int nrole = bx % 12;
  bool is_qk = nrole < 8;
  int n0 = (is_qk ? nrole : nrole - 8) * 64;
  const u16* A  = is_qk ? xc_bf : xin_bf;
  const u16* BT = is_qk ? WqkT : WvT;
  f32x4 acc[2][2] = {};
  gemm_core(A, 256, BT, 256, BC, 256, m0, n0, tid, As0, As1, Bs0, Bs1, acc);
  int wv = tid >> 6, lane = tid & 63;
  int wr = wv >> 1, wc = wv & 1;
  int lrow = lane & 15, lk = lane >> 4;
  #pragma unroll
  for (int fm = 0; fm < 2; ++fm) {
    #pragma unroll
    for (int fn = 0; fn < 2; ++fn) {
      int col = n0 + wc * 32 + fn * 16 + lrow;
      int rbase = m0 + wr * 32 + fm * 16 + lk * 4;
      if (is_qk) {
        #pragma unroll
        for (int r = 0; r < 4; ++r) {
          int row = rbase + r;
          if (row < BC) {
            float vv = acc[fm][fn][r];
            u16 hi = f2b(vv);
            u16 lo = f2b(vv - b2f(hi));
            qkh[(size_t)row * 512 + col] = hi;
            qkl[(size_t)row * 512 + col] = lo;
          }
        }
      } else {
        u16 hi4[4], lo4[4];
        #pragma unroll
        for (int r = 0; r < 4; ++r) {
          float vv = acc[fm][fn][r];
          hi4[r] = f2b(vv);
          lo4[r] = f2b(vv - b2f(hi4[r]));
        }
        int bb0 = rbase / SS, s0_ = rbase - bb0 * SS;
        int bb3 = (rbase + 3) / SS;
        if (bb0 == bb3 && rbase + 3 < BC) {   // s0_ always even (SS=862)
          size_t o = ((size_t)bb0 * II + col) * VTS + s0_;
          *(unsigned*)&vhT[o]     = (unsigned)hi4[0] | ((unsigned)hi4[1] << 16);
          *(unsigned*)&vhT[o + 2] = (unsigned)hi4[2] | ((unsigned)hi4[3] << 16);
          *(unsigned*)&vlT[o]     = (unsigned)lo4[0] | ((unsigned)lo4[1] << 16);
          *(unsigned*)&vlT[o + 2] = (unsigned)lo4[2] | ((unsigned)lo4[3] << 16);
        } else {
          #pragma unroll
          for (int r = 0; r < 4; ++r) {
            int row = rbase + r;
            if (row < BC) {
              int bb = row / SS, s = row - bb * SS;
              size_t o = ((size_t)bb * II + col) * VTS + s;
              vhT[o] = hi4[r];
              vlT[o] = lo4[r];
            }
          }
        }
      }
    }
  }
}

// ---------------------------------------------------------------------------
// causal conv (k=4) + SiLU + fused gate preacts (via Gc/Gv)
// ---------------------------------------------------------------------------
__global__ __launch_bounds__(256) void conv_gates_kernel(
    const float* __restrict__ up, const float* __restrict__ Wc,
    const float* __restrict__ bc, const float* __restrict__ Gc,
    const float* __restrict__ Gv, const float* __restrict__ bi,
    const float* __restrict__ bfp,
    float* __restrict__ xc, u16* __restrict__ xc_bf, u16* __restrict__ xin_bf,
    float* __restrict__ ig, float* __restrict__ fg)
{
  __shared__ float red[4][8];
  int row = blockIdx.x;
  int i = threadIdx.x;
  int b = row / SS, s = row - b * SS;
  float acc = bc[i];
  float xin = 0.f;
  #pragma unroll
  for (int w2 = 0; w2 < 4; ++w2) {
    int sp = s - 3 + w2;
    if (sp >= 0) {
      float uv = up[((size_t)b * SS + sp) * 512 + i];
      acc += uv * Wc[w2 * 256 + i];
      if (w2 == 3) xin = uv;
    }
  }
  float sg = 1.f / (1.f + __expf(-acc));
  float val = acc * sg;
  xc[(size_t)row * II + i] = val;
  xc_bf[(size_t)row * II + i] = f2b(val);
  xin_bf[(size_t)row * II + i] = f2b(xin);
  float p[8];
  const float* gci = &Gc[i * 8];
  const float* gvi = &Gv[i * 8];
  #pragma unroll
  for (int o = 0; o < 8; ++o) p[o] = val * gci[o] + xin * gvi[o];
  #pragma unroll
  for (int o = 0; o < 8; ++o)
    #pragma unroll
    for (int d = 1; d < 64; d <<= 1) p[o] += __shfl_xor(p[o], d);
  int wv = i >> 6, lane = i & 63;
  if (lane == 0) {
    #pragma unroll
    for (int o = 0; o < 8; ++o) red[wv][o] = p[o];
  }
  __syncthreads();
  if (i < 8) {
    float sum = red[0][i] + red[1][i] + red[2][i] + red[3][i];
    if (i < 4) ig[((size_t)b * NHH + i) * SS + s] = sum + bi[i];
    else       fg[((size_t)b * NHH + i - 4) * SS + s] = sum + bfp[i - 4];
  }
}

// ---------------------------------------------------------------------------
// masked decay attention — split-precision MFMA, register-prefetch, 2-way
// s-split partials, W-overlay on K LDS tiles (4 barriers/tile).
// ---------------------------------------------------------------------------
__global__ __launch_bounds__(256) void attn_kernel(
    const u16* __restrict__ qkh, const u16* __restrict__ qkl,
    const u16* __restrict__ vhT, const u16* __restrict__ vlT,
    const float* __restrict__ aab, const float* __restrict__ MMb,
    float* __restrict__ pacc, float* __restrict__ pw)
{
  __shared__ u16 KWh[64][64], KWl[64][64];  // K during QK^T, then W for PV
  __shared__ u16 Vh[64][64], Vl[64][64];    // [d][s]
  __shared__ float a_lds[64];
  int tid = threadIdx.x;
  int wv = tid >> 6, lane = tid & 63;
  int lr = lane & 15, lg = lane >> 4;
  int item = blockIdx.x;
  int pp = item >> 5;                     // 0..27, heavy-first
  int tb = 13 - (pp >> 1);
  int part = pp & 1;
  int h = item & 3, b = (item >> 2) & 7;
  int t0 = tb * 64;
  int nt = tb + 1;
  int nt0 = (nt + 1) >> 1;
  int st_begin = part ? nt0 : 0;
  int st_end   = part ? nt : nt0;
  const float* aabh = aab + ((size_t)b * NHH + h) * SS;
  const float* Mbh  = MMb + ((size_t)b * NHH + h) * SS;

  int tq = t0 + wv * 16 + lr; if (tq > SS - 1) tq = SS - 1;
  const u16* qrow_h = qkh + ((size_t)b * SS + tq) * 512 + h * 64;
  const u16* qrow_l = qkl + ((size_t)b * SS + tq) * 512 + h * 64;
  bf16x8 qh0 = *(const bf16x8*)(qrow_h + lg * 8);
  bf16x8 qh1 = *(const bf16x8*)(qrow_h + 32 + lg * 8);
  bf16x8 ql0 = *(const bf16x8*)(qrow_l + lg * 8);
  bf16x8 ql1 = *(const bf16x8*)(qrow_l + 32 + lg * 8);

  float Mt[4];
  #pragma unroll
  for (int r = 0; r < 4; ++r) {
    int t = t0 + wv * 16 + lg * 4 + r; int tc = t < SS ? t : SS - 1;
    Mt[r] = Mbh[tc];
  }

  int row = tid >> 2, seg = tid & 3;
  const u16* vrow_h = vhT + ((size_t)(b * II + h * 64 + row)) * VTS + seg * 16;
  const u16* vrow_l = vlT + ((size_t)(b * II + h * 64 + row)) * VTS + seg * 16;

  f32x4 hacc[4] = {};
  float wsum[4] = {0.f, 0.f, 0.f, 0.f};

  uint4 rk0, rk1, rk2, rk3, rv0, rv1, rv2, rv3;
  float ra = -1e30f;
  if (st_begin < st_end) {
    int sg = st_begin * 64 + row;
    int sc = sg < SS ? sg : SS - 1;
    const u16* kp  = qkh + ((size_t)b * SS + sc) * 512 + 256 + h * 64 + seg * 16;
    const u16* klp = qkl + ((size_t)b * SS + sc) * 512 + 256 + h * 64 + seg * 16;
    rk0 = *(const uint4*)kp;  rk1 = *(const uint4*)(kp + 8);
    rk2 = *(const uint4*)klp; rk3 = *(const uint4*)(klp + 8);
    int sn = st_begin * 64;
    rv0 = *(const uint4*)(vrow_h + sn); rv1 = *(const uint4*)(vrow_h + sn + 8);
    rv2 = *(const uint4*)(vrow_l + sn); rv3 = *(const uint4*)(vrow_l + sn + 8);
    if (tid < 64) ra = (sn + tid < SS) ? aabh[sn + tid] : -1e30f;
  }

  for (int st = st_begin; st < st_end; ++st) {
    int s0 = st * 64;
    __syncthreads();
    *(uint4*)&KWh[row][XCH(row, 2 * seg)]     = rk0;
    *(uint4*)&KWh[row][XCH(row, 2 * seg + 1)] = rk1;
    *(uint4*)&KWl[row][XCH(row, 2 * seg)]     = rk2;
    *(uint4*)&KWl[row][XCH(row, 2 * seg + 1)] = rk3;
    *(uint4*)&Vh[row][XCH(row, 2 * seg)]     = rv0;
    *(uint4*)&Vh[row][XCH(row, 2 * seg + 1)] = rv1;
    *(uint4*)&Vl[row][XCH(row, 2 * seg)]     = rv2;
    *(uint4*)&Vl[row][XCH(row, 2 * seg + 1)] = rv3;
    if (tid < 64) a_lds[tid] = ra;
    if (st + 1 < st_end) {
      int sn = s0 + 64;
      int sg = sn + row;
      int sc = sg < SS ? sg : SS - 1;
      const u16* kp  = qkh + ((size_t)b * SS + sc) * 512 + 256 + h * 64 + seg * 16;
      const u16* klp = qkl + ((size_t)b * SS + sc) * 512 + 256 + h * 64 + seg * 16;
      rk0 = *(const uint4*)kp;  rk1 = *(const uint4*)(kp + 8);
      rk2 = *(const uint4*)klp; rk3 = *(const uint4*)(klp + 8);
      rv0 = *(const uint4*)(vrow_h + sn); rv1 = *(const uint4*)(vrow_h + sn + 8);
      rv2 = *(const uint4*)(vrow_l + sn); rv3 = *(const uint4*)(vrow_l + sn + 8);
      if (tid < 64) ra = (sn + tid < SS) ? aabh[sn + tid] : -1e30f;
    }
    __syncthreads();
    float am = a_lds[lane];
    #pragma unroll
    for (int dd = 1; dd < 64; dd <<= 1) am = fmaxf(am, __shfl_xor(am, dd));
    f32x4 p[4];
    #pragma unroll
    for (int sf = 0; sf < 4; ++sf) {
      int sr = sf * 16 + lr;
      bf16x8 kh0 = *(const bf16x8*)&KWh[sr][XCH(sr, lg)];
      bf16x8 kh1 = *(const bf16x8*)&KWh[sr][XCH(sr, lg + 4)];
      bf16x8 kl0 = *(const bf16x8*)&KWl[sr][XCH(sr, lg)];
      bf16x8 kl1 = *(const bf16x8*)&KWl[sr][XCH(sr, lg + 4)];
      f32x4 acc = {};
      acc = __builtin_amdgcn_mfma_f32_16x16x32_bf16(qh0, kl0, acc, 0, 0, 0);
      acc = __builtin_amdgcn_mfma_f32_16x16x32_bf16(qh1, kl1, acc, 0, 0, 0);
      acc = __builtin_amdgcn_mfma_f32_16x16x32_bf16(ql0, kh0, acc, 0, 0, 0);
      acc = __builtin_amdgcn_mfma_f32_16x16x32_bf16(ql1, kh1, acc, 0, 0, 0);
      acc = __builtin_amdgcn_mfma_f32_16x16x32_bf16(qh0, kh0, acc, 0, 0, 0);
      acc = __builtin_amdgcn_mfma_f32_16x16x32_bf16(qh1, kh1, acc, 0, 0, 0);
      p[sf] = acc;
    }
    __syncthreads();
    float ee[4], ft[4];
    #pragma unroll
    for (int sf = 0; sf < 4; ++sf) ee[sf] = __expf(a_lds[sf * 16 + lr] - am);
    #pragma unroll
    for (int r = 0; r < 4; ++r) ft[r] = __expf(fminf(am - Mt[r], 80.f));
    #pragma unroll
    for (int sf = 0; sf < 4; ++sf) {
      int s = s0 + sf * 16 + lr;
      int sc_ = sf * 2 + (lr >> 3), sb = lr & 7;
      #pragma unroll
      for (int r = 0; r < 4; ++r) {
        int tl_ = wv * 16 + lg * 4 + r;
        int t = t0 + tl_;
        float wval = (s <= t) ? p[sf][r] * ee[sf] * ft[r] : 0.f;
        wsum[r] += wval;
        u16 hi_ = f2b(wval);
        u16 lo_ = f2b(wval - b2f(hi_));
        KWh[tl_][XCH(tl_, sc_) + sb] = hi_;
        KWl[tl_][XCH(tl_, sc_) + sb] = lo_;
      }
    }
    __syncthreads();
    int tr = wv * 16 + lr;
    bf16x8 wh0 = *(const bf16x8*)&KWh[tr][XCH(tr, lg)];
    bf16x8 wh1 = *(const bf16x8*)&KWh[tr][XCH(tr, lg + 4)];
    bf16x8 wl0 = *(const bf16x8*)&KWl[tr][XCH(tr, lg)];
    bf16x8 wl1 = *(const bf16x8*)&KWl[tr][XCH(tr, lg + 4)];
    #pragma unroll
    for (int df = 0; df < 4; ++df) {
      int dr = df * 16 + lr;
      bf16x8 vh0 = *(const bf16x8*)&Vh[dr][XCH(dr, lg)];
      bf16x8 vh1 = *(const bf16x8*)&Vh[dr][XCH(dr, lg + 4)];
      bf16x8 vl0 = *(const bf16x8*)&Vl[dr][XCH(dr, lg)];
      bf16x8 vl1 = *(const bf16x8*)&Vl[dr][XCH(dr, lg + 4)];
      f32x4 a2 = hacc[df];
      a2 = __builtin_amdgcn_mfma_f32_16x16x32_bf16(wh0, vl0, a2, 0, 0, 0);
      a2 = __builtin_amdgcn_mfma_f32_16x16x32_bf16(wh1, vl1, a2, 0, 0, 0);
      a2 = __builtin_amdgcn_mfma_f32_16x16x32_bf16(wl0, vh0, a2, 0, 0, 0);
      a2 = __builtin_amdgcn_mfma_f32_16x16x32_bf16(wl1, vh1, a2, 0, 0, 0);
      a2 = __builtin_amdgcn_mfma_f32_16x16x32_bf16(wh0, vh0, a2, 0, 0, 0);
      a2 = __builtin_amdgcn_mfma_f32_16x16x32_bf16(wh1, vh1, a2, 0, 0, 0);
      hacc[df] = a2;
    }
  }
  #pragma unroll
  for (int r = 0; r < 4; ++r) {
    float sgn = wsum[r];
    sgn += __shfl_xor(sgn, 1); sgn += __shfl_xor(sgn, 2);
    sgn += __shfl_xor(sgn, 4); sgn += __shfl_xor(sgn, 8);
    wsum[r] = sgn;
  }
  float* pa = pacc + (size_t)part * BC * II;
  #pragma unroll
  for (int r = 0; r < 4; ++r) {
    int t = t0 + wv * 16 + lg * 4 + r;
    if (t < SS) {
      #pragma unroll
      for (int df = 0; df < 4; ++df)
        pa[((size_t)b * SS + t) * II + h * 64 + df * 16 + lr] = hacc[df][r];
      if (lr == 0)
        pw[(((size_t)part * BB + b) * NHH + h) * SS + t] = wsum[r];
    }
  }
}

// ---------------------------------------------------------------------------
extern "C" void kernel_launch(void* const* d_in, const int* in_sizes, int n_in,
                              void* d_out, int out_size, void* d_ws, size_t ws_size,
                              hipStream_t stream) {
  const float* xe   = (const float*)d_in[0];
  const float* Ws   = (const float*)d_in[4];
  const float* bs   = (const float*)d_in[5];
  const float* Wt_  = (const float*)d_in[6];
  const float* bt   = (const float*)d_in[7];
  const float* Wp1  = (const float*)d_in[8];
  const float* bp1  = (const float*)d_in[9];
  const float* Wp2  = (const float*)d_in[10];
  const float* bp2  = (const float*)d_in[11];
  const float* lng  = (const float*)d_in[12];
  const float* Wup  = (const float*)d_in[13];
  const float* bup  = (const float*)d_in[14];
  const float* Wcv  = (const float*)d_in[15];
  const float* bcv  = (const float*)d_in[16];
  const float* Wq   = (const float*)d_in[17];
  const float* Wk   = (const float*)d_in[18];
  const float* Wv   = (const float*)d_in[19];
  const float* Wi   = (const float*)d_in[20];
  const float* bi   = (const float*)d_in[21];
  const float* Wf   = (const float*)d_in[22];
  const float* bf_  = (const float*)d_in[23];
  const float* mhg  = (const float*)d_in[24];
  const float* skp  = (const float*)d_in[25];
  const float* Wdn  = (const float*)d_in[26];
  const float* bdn  = (const float*)d_in[27];
  const float* pg   = (const float*)d_in[28];
  float* out = (float*)d_out;

  float* w   = (float*)d_ws;
  float* x   = w;                       // [6896,128]
  float* y   = x   + 882688;
  float* up  = y   + 882688;            // [6896,512]  (aliased by A_head bf16)
  float* xc  = up  + 3530752;           // [6896,256]
  float* pacc = xc + 1765376;           // [2][6896,256] partial attn acc
  float* pw  = pacc + 3530752;          // [2][8][4][862]
  float* ig  = pw  + 55168;
  float* fg  = ig  + 27584;
  float* cum = fg  + 27584;
  float* aab = cum + 27584;
  float* MMb = aab + 27584;
  float* hbias = MMb + 27584;
  float* Gc  = hbias + 128;             // [2][256][8]
  float* Gv  = Gc + 4096;
  u16* ub    = (u16*)(Gv + 4096);
  u16* y_bf  = ub;            ub += 6896 * 128;
  u16* xc_bf = ub;            ub += 6896 * 256;
  u16* xin_bf = ub;           ub += 6896 * 256;
  u16* qkh   = ub;            ub += 6896 * 512;
  u16* qkl   = ub;            ub += 6896 * 512;
  u16* vhT   = ub;            ub += 8 * 256 * VTS;
  u16* vlT   = ub;            ub += 8 * 256 * VTS;
  u16* BTh   = ub;            ub += 131072;
  u16* WupT  = ub;            ub += 131072;
  u16* WqkT  = ub;            ub += 262144;
  u16* WvT   = ub;            ub += 131072;
  u16* WdnT  = ub;            ub += 65536;
  u16* Ah = (u16*)up;                   // A_head aliases up

  // merged weight prep + ta (independent roles, one dispatch)
  prep_ta_kernel<<<2097, 256, 0, stream>>>(
      Wup, Wq, Wk, Wv, Wdn, Ws, Wt_, Wp1, bs, bt, bp1, Wi, Wf, xe,
      WupT, WqkT, WvT, WdnT, BTh, hbias, Gc, Gv, Ah);

  // head: x = A_head @ BTh + hbias, then y_bf = LN(x) with blk0 gains
  gemm_ln<0, 0, 0, 0><<<216, 256, 0, stream>>>(
      Ah, 1024, BTh, 1024, x, hbias, lng, nullptr, y_bf, BC, 1024,
      nullptr, nullptr, nullptr, nullptr, nullptr, nullptr, nullptr, nullptr,
      nullptr, nullptr, nullptr);

  for (int blk = 0; blk < 2; ++blk) {
    gemm_bf16<0><<<dim3(8, 108), 256, 0, stream>>>(
        y_bf, 128, WupT + blk * 65536, 128, up, 512, bup + blk * 512, BC, 512, 128);
    conv_gates_kernel<<<6896, 256, 0, stream>>>(
        up, Wcv + blk * 1024, bcv + blk * 256, Gc + blk * 2048, Gv + blk * 2048,
        bi + blk * 4, bf_ + blk * 4, xc, xc_bf, xin_bf, ig, fg);
    qkv_scan_kernel<<<1328, 256, 0, stream>>>(
        xc_bf, xin_bf, WqkT + blk * 131072, WvT + blk * 65536,
        qkh, qkl, vhT, vlT, fg, ig, cum, aab, MMb);
    attn_kernel<<<NITEMS2, 256, 0, stream>>>(qkh, qkl, vhT, vlT, aab, MMb, pacc, pw);
    // dn GEMM + fused combine/mhln + residual + LN (+ final projection on blk1)
    if (blk == 0)
      gemm_ln<1, 0, 1, 0><<<216, 256, 0, stream>>>(
          nullptr, 0, WdnT, 256, x, bdn, lng + 128, nullptr, y_bf, BC, 256,
          pacc, pw, cum, MMb, up, xc, mhg, skp, nullptr, nullptr, nullptr);
    else
      gemm_ln<1, 0, 1, 1><<<216, 256, 0, stream>>>(
          nullptr, 0, WdnT + 32768, 256, x, bdn + 128, pg, nullptr, nullptr, BC, 256,
          pacc, pw, cum, MMb, up, xc, mhg + 256, skp + 256, Wp2, bp2, out);
  }
}

// Round 18
// 236.943 us; speedup vs baseline: 1.1676x; 1.0127x over previous
//
#include <hip/hip_runtime.h>
#include <math.h>

#define BB 8
#define LL 512
#define CC 862
#define PP 96
#define DD 128
#define II 256
#define NHH 4
#define DHH 64
#define SS 862
#define BC (BB*CC)
#define VTS 864          // padded V^T row stride
#define NITEMS2 896      // attn work items = 28 pairs * 32 bh

typedef unsigned short u16;
using bf16x8 = __attribute__((ext_vector_type(8))) short;
using f32x4  = __attribute__((ext_vector_type(4))) float;

__device__ __forceinline__ u16 f2b(float x) {
  union { float f; unsigned u; } v; v.f = x;
  unsigned r = v.u + 0x7FFF + ((v.u >> 16) & 1);
  return (u16)(r >> 16);
}
__device__ __forceinline__ float b2f(u16 h) {
  union { unsigned u; float f; } v; v.u = ((unsigned)h) << 16;
  return v.f;
}

// chunk-XOR swizzle: u16 offset of 16B-chunk c within row r of a [64][64] tile
#define XCH(r, c) ((((c) ^ ((r) & 7)) << 3))

// ---------------------------------------------------------------------------
// merged prep + ta kernel.  gb<640: tc; <1152: gcomb; ==1152: hbias;
// <1665: gprep; >=1665: ta (transpose + moving-average -> A_head bf16).
// ---------------------------------------------------------------------------
__global__ __launch_bounds__(256) void prep_ta_kernel(
    const float* __restrict__ Wup, const float* __restrict__ Wq,
    const float* __restrict__ Wk, const float* __restrict__ Wv,
    const float* __restrict__ Wdn, const float* __restrict__ Ws,
    const float* __restrict__ Wt, const float* __restrict__ Wp1,
    const float* __restrict__ bs, const float* __restrict__ bt,
    const float* __restrict__ bp1, const float* __restrict__ Wi,
    const float* __restrict__ Wf, const float* __restrict__ xe,
    u16* __restrict__ WupT, u16* __restrict__ WqkT,
    u16* __restrict__ WvT, u16* __restrict__ WdnT,
    u16* __restrict__ BTh, float* __restrict__ hbias,
    float* __restrict__ Gc, float* __restrict__ Gv,
    u16* __restrict__ Ah)
{
  __shared__ float smem[16 * 545 + 16 * 517];
  int gb = blockIdx.x;
  int tid = threadIdx.x;
  if (gb >= 1665) {
    // ---- ta role ----
    float (*xel)[545] = (float(*)[545])smem;
    float (*mml)[517] = (float(*)[517])(smem + 16 * 545);
    int bx = gb - 1665;
    int b = bx / 54, ct = bx % 54;
    int c0 = ct * 16;
    for (int j = 0; j < 34; ++j) {
      int idx = tid + j * 256;
      if (idx < 8576) {
        int li = idx >> 4, cc = idx & 15;
        int l = li - 12; l = l < 0 ? 0 : (l > 511 ? 511 : l);
        int c = c0 + cc; if (c > 861) c = 861;
        xel[cc][li] = xe[((size_t)b * LL + l) * CC + c];
      }
    }
    __syncthreads();
    {
      int cl = tid & 15;
      int l0 = (tid >> 4) * 32;
      float win = 0.f;
      #pragma unroll 5
      for (int o = 0; o < 25; ++o) win += xel[cl][l0 + o];
      mml[cl][l0] = win * (1.f / 25.f);
      for (int i = 1; i < 32; ++i) {
        win += xel[cl][l0 + 24 + i] - xel[cl][l0 + i - 1];
        mml[cl][l0 + i] = win * (1.f / 25.f);
      }
    }
    __syncthreads();
    for (int j = 0; j < 32; ++j) {
      int idx = tid + j * 256;
      int cr = idx >> 9, l = idx & 511;
      int c = c0 + cr;
      if (c < CC) {
        size_t base = ((size_t)b * CC + c) * 1024;
        Ah[base + l] = f2b(xel[cr][12 + l]);
        Ah[base + 512 + l] = f2b(mml[cr][l]);
      }
    }
    return;
  }
  if (gb < 640) {
    float (*t)[33] = (float(*)[33])smem;
    int bx = gb & 63, by = gb >> 6;
    const float* src; u16* dst; int R, Cn; float scl = 1.f;
    switch (by) {
      case 0: src = Wup;          dst = WupT;            R = 128; Cn = 512; break;
      case 1: src = Wup + 65536;  dst = WupT + 65536;    R = 128; Cn = 512; break;
      case 2: src = Wq;           dst = WqkT;            R = 256; Cn = 256; scl = 0.125f; break;
      case 3: src = Wk;           dst = WqkT + 65536;    R = 256; Cn = 256; break;
      case 4: src = Wq + 65536;   dst = WqkT + 131072;   R = 256; Cn = 256; scl = 0.125f; break;
      case 5: src = Wk + 65536;   dst = WqkT + 196608;   R = 256; Cn = 256; break;
      case 6: src = Wv;           dst = WvT;             R = 256; Cn = 256; break;
      case 7: src = Wv + 65536;   dst = WvT + 65536;     R = 256; Cn = 256; break;
      case 8: src = Wdn;          dst = WdnT;            R = 256; Cn = 128; break;
      default: src = Wdn + 32768; dst = WdnT + 32768;    R = 256; Cn = 128; break;
    }
    int tpr = Cn >> 5;
    int tx = bx % tpr, ty_ = bx / tpr;
    if (ty_ >= (R >> 5)) return;
    int r0 = ty_ * 32, c0 = tx * 32;
    int cr = tid >> 5, cc = tid & 31;
    #pragma unroll
    for (int rr = 0; rr < 4; ++rr)
      t[cr + rr * 8][cc] = src[(size_t)(r0 + cr + rr * 8) * Cn + c0 + cc];
    __syncthreads();
    #pragma unroll
    for (int rr = 0; rr < 4; ++rr)
      dst[(size_t)(c0 + cr + rr * 8) * R + r0 + cc] = f2b(t[cc][cr + rr * 8] * scl);
  } else if (gb < 1152) {
    int i2 = gb - 640;
    int d = i2 & 127, byy = i2 >> 7;
    int lp = byy * 256 + tid;
    const float* wp = Wp1 + d * 96;
    float acc = 0.f;
    if (lp < 512) {
      for (int p = 0; p < 96; ++p) acc += Ws[p * 512 + lp] * wp[p];
    } else {
      int l = lp - 512;
      for (int p = 0; p < 96; ++p) acc += (Wt[p * 512 + l] - Ws[p * 512 + l]) * wp[p];
    }
    BTh[(size_t)d * 1024 + lp] = f2b(acc);
  } else if (gb == 1152) {
    if (tid < 128) {
      float acc = bp1[tid];
      for (int p = 0; p < 96; ++p) acc += (bs[p] + bt[p]) * Wp1[tid * 96 + p];
      hbias[tid] = acc;
    }
  } else {
    float (*red)[16] = (float(*)[16])smem;
    int i2 = gb - 1153;
    int i = i2 & 255, blk = i2 >> 8;
    int j = tid;
    float wq = Wq[(size_t)blk * 65536 + i * 256 + j];
    float wk = Wk[(size_t)blk * 65536 + i * 256 + j];
    float wv = Wv[(size_t)blk * 65536 + i * 256 + j];
    const float* wi = Wi + blk * 3072;
    const float* wf = Wf + blk * 3072;
    float pc[8], pv[8];
    #pragma unroll
    for (int o = 0; o < 4; ++o) {
      pc[o]     = wq * wi[j * 4 + o] + wk * wi[(256 + j) * 4 + o];
      pc[4 + o] = wq * wf[j * 4 + o] + wk * wf[(256 + j) * 4 + o];
      pv[o]     = wv * wi[(512 + j) * 4 + o];
      pv[4 + o] = wv * wf[(512 + j) * 4 + o];
    }
    #pragma unroll
    for (int o = 0; o < 8; ++o)
      #pragma unroll
      for (int d = 1; d < 64; d <<= 1) {
        pc[o] += __shfl_xor(pc[o], d);
        pv[o] += __shfl_xor(pv[o], d);
      }
    int wv_ = j >> 6, lane = j & 63;
    if (lane == 0) {
      #pragma unroll
      for (int o = 0; o < 8; ++o) { red[wv_][o] = pc[o]; red[wv_][8 + o] = pv[o]; }
    }
    __syncthreads();
    if (j < 16) {
      float s4 = red[0][j] + red[1][j] + red[2][j] + red[3][j];
      if (j < 8) Gc[((size_t)blk * 256 + i) * 8 + j] = s4;
      else       Gv[((size_t)blk * 256 + i) * 8 + j - 8] = s4;
    }
  }
}

// ---------------------------------------------------------------------------
// bf16 MFMA GEMM core loop (BK=64, 64x64 tile) with register-prefetch
// pipeline (T14): chunk k+1's global loads issue before the barrier, hiding
// latency under the MFMA phase.
// ---------------------------------------------------------------------------
__device__ __forceinline__ void gemm_core(
    const u16* __restrict__ A, int lda, const u16* __restrict__ BT, int ldbt,
    int M, int K, int m0, int n0, int tid,
    u16 (*As0)[40], u16 (*As1)[40], u16 (*Bs0)[40], u16 (*Bs1)[40],
    f32x4 acc[2][2])
{
  int wv = tid >> 6, lane = tid & 63;
  int wr = wv >> 1, wc = wv & 1;
  int lrow = lane & 15, lk = lane >> 4;
  int arow = tid >> 2, aseg = tid & 3;
  int gm = m0 + arow; if (gm > M - 1) gm = M - 1;
  const u16* aptr = &A[(size_t)gm * lda + aseg * 8];
  const u16* bptr = &BT[(size_t)(n0 + arow) * ldbt + aseg * 8];
  uint4 ra0 = *(const uint4*)aptr;
  uint4 ra1 = *(const uint4*)(aptr + 32);
  uint4 rb0 = *(const uint4*)bptr;
  uint4 rb1 = *(const uint4*)(bptr + 32);
  for (int k0 = 0; k0 < K; k0 += 64) {
    *(uint4*)&As0[arow][aseg * 8] = ra0;
    *(uint4*)&As1[arow][aseg * 8] = ra1;
    *(uint4*)&Bs0[arow][aseg * 8] = rb0;
    *(uint4*)&Bs1[arow][aseg * 8] = rb1;
    if (k0 + 64 < K) {
      ra0 = *(const uint4*)(aptr + k0 + 64);
      ra1 = *(const uint4*)(aptr + k0 + 96);
      rb0 = *(const uint4*)(bptr + k0 + 64);
      rb1 = *(const uint4*)(bptr + k0 + 96);
    }
    __syncthreads();
    bf16x8 af[2], bfr[2];
    #pragma unroll
    for (int fm = 0; fm < 2; ++fm) af[fm] = *(const bf16x8*)&As0[wr * 32 + fm * 16 + lrow][lk * 8];
    #pragma unroll
    for (int fn = 0; fn < 2; ++fn) bfr[fn] = *(const bf16x8*)&Bs0[wc * 32 + fn * 16 + lrow][lk * 8];
    #pragma unroll
    for (int fm = 0; fm < 2; ++fm)
      #pragma unroll
      for (int fn = 0; fn < 2; ++fn)
        acc[fm][fn] = __builtin_amdgcn_mfma_f32_16x16x32_bf16(af[fm], bfr[fn], acc[fm][fn], 0, 0, 0);
    #pragma unroll
    for (int fm = 0; fm < 2; ++fm) af[fm] = *(const bf16x8*)&As1[wr * 32 + fm * 16 + lrow][lk * 8];
    #pragma unroll
    for (int fn = 0; fn < 2; ++fn) bfr[fn] = *(const bf16x8*)&Bs1[wc * 32 + fn * 16 + lrow][lk * 8];
    #pragma unroll
    for (int fm = 0; fm < 2; ++fm)
      #pragma unroll
      for (int fn = 0; fn < 2; ++fn)
        acc[fm][fn] = __builtin_amdgcn_mfma_f32_16x16x32_bf16(af[fm], bfr[fn], acc[fm][fn], 0, 0, 0);
    __syncthreads();
  }
}

// ---------------------------------------------------------------------------
// generic 64x64 GEMM kernel. MODE 0: C=AB+bias; 1: C+=AB+bias
// ---------------------------------------------------------------------------
template<int MODE>
__global__ __launch_bounds__(256) void gemm_bf16(
    const u16* __restrict__ A, int lda,
    const u16* __restrict__ BT, int ldbt,
    float* __restrict__ C, int ldc, const float* __restrict__ bias,
    int M, int N, int K)
{
  __shared__ u16 As0[64][40], As1[64][40];
  __shared__ u16 Bs0[64][40], Bs1[64][40];
  int tid = threadIdx.x;
  int m0 = blockIdx.y * 64, n0 = blockIdx.x * 64;
  f32x4 acc[2][2] = {};
  gemm_core(A, lda, BT, ldbt, M, K, m0, n0, tid, As0, As1, Bs0, Bs1, acc);
  int wv = tid >> 6, lane = tid & 63;
  int wr = wv >> 1, wc = wv & 1;
  int lrow = lane & 15, lk = lane >> 4;
  #pragma unroll
  for (int fm = 0; fm < 2; ++fm) {
    #pragma unroll
    for (int fn = 0; fn < 2; ++fn) {
      int col = n0 + wc * 32 + fn * 16 + lrow;
      #pragma unroll
      for (int r = 0; r < 4; ++r) {
        int row = m0 + wr * 32 + fm * 16 + lk * 4 + r;
        if (row < M) {
          float vv = acc[fm][fn][r];
          if (bias) vv += bias[col];
          float* cp = &C[(size_t)row * ldc + col];
          if (MODE == 1) vv += *cp;
          *cp = vv;
        }
      }
    }
  }
}

// ---------------------------------------------------------------------------
// fused GEMM(N=128) + residual + row-LayerNorm (+ optional final projection),
// with register-prefetch staging pipeline.  32x128 tile, 216 blocks.
// MODE 0: x = A@BT + bias; 1: x += A@BT + bias.
// FUSEC 1: A computed on the fly from attention partials (combine+mhln).
// FINAL 0: LN -> y_bf (OUTF32=0) or y fp32 (OUTF32=1).
// FINAL 1: LN -> LDS, then out[b,p,c] = LN(x)@Wp2^T + bp2.
// ---------------------------------------------------------------------------
template<int MODE, int OUTF32, int FUSEC, int FINAL>
__global__ __launch_bounds__(256) void gemm_ln(
    const u16* __restrict__ A, int lda,
    const u16* __restrict__ BT, int ldbt,
    float* __restrict__ x, const float* __restrict__ bias,
    const float* __restrict__ g,
    float* __restrict__ y, u16* __restrict__ y_bf,
    int M, int K,
    const float* __restrict__ pacc, const float* __restrict__ pw,
    const float* __restrict__ cumf, const float* __restrict__ MMb,
    const float* __restrict__ up2, const float* __restrict__ xc2,
    const float* __restrict__ mhg, const float* __restrict__ skip,
    const float* __restrict__ Wp2, const float* __restrict__ bp2,
    float* __restrict__ out)
{
  __shared__ u16 As0[32][40], As1[32][40];
  __shared__ u16 Bs0[128][40], Bs1[128][40];
  __shared__ float red_s[32][2], red_q[32][2];
  __shared__ float yl[32][132];
  int tid = threadIdx.x;
  int m0 = blockIdx.x * 32;
  int wv = tid >> 6, lane = tid & 63;
  int wr = wv >> 1, wc = wv & 1;       // wr: row half (16), wc: col half (64)
  int lrow = lane & 15, lk = lane >> 4;
  f32x4 acc[4] = {};
  int arow = tid >> 3, aseg7 = tid & 7;        // A: 32 rows x 8 segs
  int brow = tid >> 1, bhalf = tid & 1;        // B: 128 rows x 2 seg-pairs
  int gm = m0 + arow; if (gm > M - 1) gm = M - 1;
  int bbr = 0, sxr = 0;
  if (FUSEC) { bbr = gm / SS; sxr = gm - bbr * SS; }
  const u16* bbase = &BT[(size_t)brow * ldbt];
  int bseg = bhalf * 2;

  // prefetch registers
  uint4 ra;
  float4 rp0a, rp0b, rp1a, rp1b, rupa, rupb, rxca, rxcb;
  float rpwA, rpwB, rcum, rmm;
  uint4 rb0, rb1, rb2, rb3;

  // load chunk 0
  {
    const int k0 = 0;
    if (FUSEC == 0) {
      ra = *(const uint4*)(&A[(size_t)gm * lda + k0] + aseg7 * 8);
    } else {
      int hh = k0 >> 6;
      size_t bhS = ((size_t)bbr * NHH + hh) * SS + sxr;
      rpwA = pw[bhS]; rpwB = pw[(size_t)BB * NHH * SS + bhS];
      rcum = cumf[bhS]; rmm = MMb[bhS];
      int colb = k0 + aseg7 * 8;
      const float* p0 = &pacc[(size_t)gm * II + colb];
      rp0a = *(const float4*)p0; rp0b = *(const float4*)(p0 + 4);
      const float* p1 = p0 + (size_t)BC * II;
      rp1a = *(const float4*)p1; rp1b = *(const float4*)(p1 + 4);
      const float* upp = &up2[(size_t)gm * 512 + 256 + colb];
      rupa = *(const float4*)upp; rupb = *(const float4*)(upp + 4);
      const float* xcp = &xc2[(size_t)gm * II + colb];
      rxca = *(const float4*)xcp; rxcb = *(const float4*)(xcp + 4);
    }
    const u16* bp = bbase + k0;
    rb0 = *(const uint4*)(bp + bseg * 8);
    rb1 = *(const uint4*)(bp + (bseg + 1) * 8);
    rb2 = *(const uint4*)(bp + 32 + bseg * 8);
    rb3 = *(const uint4*)(bp + 32 + (bseg + 1) * 8);
  }

  for (int k0 = 0; k0 < K; k0 += 64) {
    // ---- write staged regs -> LDS ----
    if (FUSEC == 0) {
      if (aseg7 < 4) *(uint4*)&As0[arow][aseg7 * 8] = ra;
      else           *(uint4*)&As1[arow][(aseg7 - 4) * 8] = ra;
    } else {
      float rden = 1.f / fmaxf(fabsf(rpwA + rpwB), __expf(-(rcum + rmm)));
      float a0[8] = {rp0a.x, rp0a.y, rp0a.z, rp0a.w, rp0b.x, rp0b.y, rp0b.z, rp0b.w};
      float a1[8] = {rp1a.x, rp1a.y, rp1a.z, rp1a.w, rp1b.x, rp1b.y, rp1b.z, rp1b.w};
      float uu[8] = {rupa.x, rupa.y, rupa.z, rupa.w, rupb.x, rupb.y, rupb.z, rupb.w};
      float xx[8] = {rxca.x, rxca.y, rxca.z, rxca.w, rxcb.x, rxcb.y, rxcb.z, rxcb.w};
      float hv[8], sr = 0.f, sq2 = 0.f;
      #pragma unroll
      for (int j = 0; j < 8; ++j) {
        hv[j] = (a0[j] + a1[j]) * rden;
        sr += hv[j]; sq2 += hv[j] * hv[j];
      }
      sr += __shfl_xor(sr, 1); sq2 += __shfl_xor(sq2, 1);
      sr += __shfl_xor(sr, 2); sq2 += __shfl_xor(sq2, 2);
      sr += __shfl_xor(sr, 4); sq2 += __shfl_xor(sq2, 4);
      float mu = sr * (1.f / 64.f);
      float var = sq2 * (1.f / 64.f) - mu * mu;
      float rr2 = rsqrtf(var + 1e-5f);
      int colb = k0 + aseg7 * 8;
      u16 o8[8];
      #pragma unroll
      for (int j = 0; j < 8; ++j) {
        int col = colb + j;
        float hn = (hv[j] - mu) * rr2 * mhg[col];
        float sil = uu[j] / (1.f + __expf(-uu[j]));
        o8[j] = f2b((hn + skip[col] * xx[j]) * sil);
      }
      if (aseg7 < 4) *(uint4*)&As0[arow][aseg7 * 8] = *(const uint4*)o8;
      else           *(uint4*)&As1[arow][(aseg7 - 4) * 8] = *(const uint4*)o8;
    }
    *(uint4*)&Bs0[brow][bseg * 8] = rb0;
    *(uint4*)&Bs0[brow][(bseg + 1) * 8] = rb1;
    *(uint4*)&Bs1[brow][bseg * 8] = rb2;
    *(uint4*)&Bs1[brow][(bseg + 1) * 8] = rb3;
    // ---- issue next chunk's loads (latency hides under MFMA) ----
    if (k0 + 64 < K) {
      int kn = k0 + 64;
      if (FUSEC == 0) {
        ra = *(const uint4*)(&A[(size_t)gm * lda + kn] + aseg7 * 8);
      } else {
        int hh = kn >> 6;
        size_t bhS = ((size_t)bbr * NHH + hh) * SS + sxr;
        rpwA = pw[bhS]; rpwB = pw[(size_t)BB * NHH * SS + bhS];
        rcum = cumf[bhS]; rmm = MMb[bhS];
        int colb = kn + aseg7 * 8;
        const float* p0 = &pacc[(size_t)gm * II + colb];
        rp0a = *(const float4*)p0; rp0b = *(const float4*)(p0 + 4);
        const float* p1 = p0 + (size_t)BC * II;
        rp1a = *(const float4*)p1; rp1b = *(const float4*)(p1 + 4);
        const float* upp = &up2[(size_t)gm * 512 + 256 + colb];
        rupa = *(const float4*)upp; rupb = *(const float4*)(upp + 4);
        const float* xcp = &xc2[(size_t)gm * II + colb];
        rxca = *(const float4*)xcp; rxcb = *(const float4*)(xcp + 4);
      }
      const u16* bp = bbase + kn;
      rb0 = *(const uint4*)(bp + bseg * 8);
      rb1 = *(const uint4*)(bp + (bseg + 1) * 8);
      rb2 = *(const uint4*)(bp + 32 + bseg * 8);
      rb3 = *(const uint4*)(bp + 32 + (bseg + 1) * 8);
    }
    __syncthreads();
    bf16x8 af, bfr[4];
    af = *(const bf16x8*)&As0[wr * 16 + lrow][lk * 8];
    #pragma unroll
    for (int fn = 0; fn < 4; ++fn) bfr[fn] = *(const bf16x8*)&Bs0[wc * 64 + fn * 16 + lrow][lk * 8];
    #pragma unroll
    for (int fn = 0; fn < 4; ++fn)
      acc[fn] = __builtin_amdgcn_mfma_f32_16x16x32_bf16(af, bfr[fn], acc[fn], 0, 0, 0);
    af = *(const bf16x8*)&As1[wr * 16 + lrow][lk * 8];
    #pragma unroll
    for (int fn = 0; fn < 4; ++fn) bfr[fn] = *(const bf16x8*)&Bs1[wc * 64 + fn * 16 + lrow][lk * 8];
    #pragma unroll
    for (int fn = 0; fn < 4; ++fn)
      acc[fn] = __builtin_amdgcn_mfma_f32_16x16x32_bf16(af, bfr[fn], acc[fn], 0, 0, 0);
    __syncthreads();
  }
  // epilogue: bias + residual, fp32 x write, row sums
  #pragma unroll
  for (int r = 0; r < 4; ++r) {
    int lrid = wr * 16 + lk * 4 + r;
    int grow = m0 + lrid;
    float sr = 0.f, sq = 0.f;
    #pragma unroll
    for (int fn = 0; fn < 4; ++fn) {
      int col = wc * 64 + fn * 16 + lrow;
      float vv = acc[fn][r] + bias[col];
      if (MODE == 1) vv += x[(size_t)grow * DD + col];
      acc[fn][r] = vv;
      if (grow < M) x[(size_t)grow * DD + col] = vv;
      sr += vv; sq += vv * vv;
    }
    sr += __shfl_xor(sr, 1); sq += __shfl_xor(sq, 1);
    sr += __shfl_xor(sr, 2); sq += __shfl_xor(sq, 2);
    sr += __shfl_xor(sr, 4); sq += __shfl_xor(sq, 4);
    sr += __shfl_xor(sr, 8); sq += __shfl_xor(sq, 8);
    if (lrow == 0) { red_s[lrid][wc] = sr; red_q[lrid][wc] = sq; }
  }
  __syncthreads();
  #pragma unroll
  for (int r = 0; r < 4; ++r) {
    int lrid = wr * 16 + lk * 4 + r;
    int grow = m0 + lrid;
    if (FINAL == 0 && grow >= M) continue;
    float s = red_s[lrid][0] + red_s[lrid][1];
    float q = red_q[lrid][0] + red_q[lrid][1];
    float mean = s * (1.f / 128.f);
    float var = q * (1.f / 128.f) - mean * mean;
    float rr = rsqrtf(var + 1e-5f);
    #pragma unroll
    for (int fn = 0; fn < 4; ++fn) {
      int col = wc * 64 + fn * 16 + lrow;
      float outv = (acc[fn][r] - mean) * rr * g[col];
      if (FINAL) {
        yl[lrid][col] = outv;
      } else if (OUTF32) {
        y[(size_t)grow * DD + col] = outv;
      } else {
        y_bf[(size_t)grow * DD + col] = f2b(outv);
      }
    }
  }
  if (FINAL) {
    __syncthreads();
    // out[b,p,c] = yl@Wp2^T + bp2 (same dot order as old final_kernel)
    for (int j = 0; j < 12; ++j) {
      int o = tid + j * 256;          // 3072 = 96 p x 32 rows
      int p = o >> 5, cl = o & 31;
      int grow = m0 + cl;
      if (grow >= M) continue;
      const float* wr2 = Wp2 + p * 128;
      float accf = bp2[p];
      #pragma unroll 8
      for (int d0 = 0; d0 < 128; d0 += 4) {
        float4 yv = *(const float4*)&yl[cl][d0];
        float4 wv2 = *(const float4*)&wr2[d0];
        accf += yv.x * wv2.x + yv.y * wv2.y + yv.z * wv2.z + yv.w * wv2.w;
      }
      int b = grow / SS, c = grow - b * SS;
      out[(size_t)b * PP * CC + (size_t)p * CC + c] = accf;
    }
  }
}

// ---------------------------------------------------------------------------
// per-(b,h) scan helper
// ---------------------------------------------------------------------------
__device__ __forceinline__ float logsig(float x) {
  return fminf(x, 0.f) - log1pf(__expf(-fabsf(x)));
}

// ---------------------------------------------------------------------------
// merged qk+v GEMM + gate scan.  bx<1296: GEMM (nrole=bx%12, m=bx/12);
// bx>=1296: per-(b,h) scan with 64 threads.  Rows >= BC skipped.
// ---------------------------------------------------------------------------
__global__ __launch_bounds__(256) void qkv_scan_kernel(
    const u16* __restrict__ xc_bf, const u16* __restrict__ xin_bf,
    const u16* __restrict__ WqkT, const u16* __restrict__ WvT,
    u16* __restrict__ qkh, u16* __restrict__ qkl,
    u16* __restrict__ vhT, u16* __restrict__ vlT,
    const float* __restrict__ fg, const float* __restrict__ ig,
    float* __restrict__ cumf, float* __restrict__ aa, float* __restrict__ MMb)
{
  __shared__ u16 As0[64][40], As1[64][40];
  __shared__ u16 Bs0[64][40], Bs1[64][40];
  int tid = threadIdx.x;
  int bx = blockIdx.x;
  if (bx >= 1296) {
    if (tid >= 64) return;
    int bh = bx - 1296;
    int lane = tid;
    const float* f = fg + (size_t)bh * SS;
    const float* gg = ig + (size_t)bh * SS;
    int s0 = lane * 14, s1 = s0 + 14; if (s1 > SS) s1 = SS;
    float loc = 0.f;
    for (int s = s0; s < s1; ++s) loc += logsig(f[s]);
    float v = loc;
    #pragma unroll
    for (int d = 1; d < 64; d <<= 1) { float o = __shfl_up(v, d); if (lane >= d) v += o; }
    float run = v - loc;
    float lmax = -1e30f;
    for (int s = s0; s < s1; ++s) {
      run += logsig(f[s]);
      cumf[(size_t)bh * SS + s] = run;
      float a = gg[s] - run;
      aa[(size_t)bh * SS + s] = a;
      lmax = fmaxf(lmax, a);
    }
    float mv = lmax;
    #pragma unroll
    for (int d = 1; d < 64; d <<= 1) { float o = __shfl_up(mv, d); if (lane >= d) mv = fmaxf(mv, o); }
    float em = __shfl_up(mv, 1);
    if (lane == 0) em = -1e30f;
    float runm = em;
    for (int s = s0; s < s1; ++s) {
      runm = fmaxf(runm, aa[(size_t)bh * SS + s]);
      MMb[(size_t)bh * SS + s] = runm;
    }
    return;
  }
  int m0 = (bx / 12) * 64;
  int nrole = bx % 12;
  bool is_qk = nrole < 8;
  int n0 = (is_qk ? nrole : nrole - 8) * 64;
  const u16* A  = is_qk ? xc_bf : xin_bf;
  const u16* BT = is_qk ? WqkT : WvT;
  f32x4 acc[2][2] = {};
  gemm_core(A, 256, BT, 256, BC, 256, m0, n0, tid, As0, As1, Bs0, Bs1, acc);
  int wv = tid >> 6, lane = tid & 63;
  int wr = wv >> 1, wc = wv & 1;
  int lrow = lane & 15, lk = lane >> 4;
  #pragma unroll
  for (int fm = 0; fm < 2; ++fm) {
    #pragma unroll
    for (int fn = 0; fn < 2; ++fn) {
      int col = n0 + wc * 32 + fn * 16 + lrow;
      int rbase = m0 + wr * 32 + fm * 16 + lk * 4;
      if (is_qk) {
        #pragma unroll
        for (int r = 0; r < 4; ++r) {
          int row = rbase + r;
          if (row < BC) {
            float vv = acc[fm][fn][r];
            u16 hi = f2b(vv);
            u16 lo = f2b(vv - b2f(hi));
            qkh[(size_t)row * 512 + col] = hi;
            qkl[(size_t)row * 512 + col] = lo;
          }
        }
      } else {
        u16 hi4[4], lo4[4];
        #pragma unroll
        for (int r = 0; r < 4; ++r) {
          float vv = acc[fm][fn][r];
          hi4[r] = f2b(vv);
          lo4[r] = f2b(vv - b2f(hi4[r]));
        }
        int bb0 = rbase / SS, s0_ = rbase - bb0 * SS;
        int bb3 = (rbase + 3) / SS;
        if (bb0 == bb3 && rbase + 3 < BC) {   // s0_ always even (SS=862)
          size_t o = ((size_t)bb0 * II + col) * VTS + s0_;
          *(unsigned*)&vhT[o]     = (unsigned)hi4[0] | ((unsigned)hi4[1] << 16);
          *(unsigned*)&vhT[o + 2] = (unsigned)hi4[2] | ((unsigned)hi4[3] << 16);
          *(unsigned*)&vlT[o]     = (unsigned)lo4[0] | ((unsigned)lo4[1] << 16);
          *(unsigned*)&vlT[o + 2] = (unsigned)lo4[2] | ((unsigned)lo4[3] << 16);
        } else {
          #pragma unroll
          for (int r = 0; r < 4; ++r) {
            int row = rbase + r;
            if (row < BC) {
              int bb = row / SS, s = row - bb * SS;
              size_t o = ((size_t)bb * II + col) * VTS + s;
              vhT[o] = hi4[r];
              vlT[o] = lo4[r];
            }
          }
        }
      }
    }
  }
}

// ---------------------------------------------------------------------------
// causal conv (k=4) + SiLU + fused gate preacts (via Gc/Gv)
// ---------------------------------------------------------------------------
__global__ __launch_bounds__(256) void conv_gates_kernel(
    const float* __restrict__ up, const float* __restrict__ Wc,
    const float* __restrict__ bc, const float* __restrict__ Gc,
    const float* __restrict__ Gv, const float* __restrict__ bi,
    const float* __restrict__ bfp,
    float* __restrict__ xc, u16* __restrict__ xc_bf, u16* __restrict__ xin_bf,
    float* __restrict__ ig, float* __restrict__ fg)
{
  __shared__ float red[4][8];
  int row = blockIdx.x;
  int i = threadIdx.x;
  int b = row / SS, s = row - b * SS;
  float acc = bc[i];
  float xin = 0.f;
  #pragma unroll
  for (int w2 = 0; w2 < 4; ++w2) {
    int sp = s - 3 + w2;
    if (sp >= 0) {
      float uv = up[((size_t)b * SS + sp) * 512 + i];
      acc += uv * Wc[w2 * 256 + i];
      if (w2 == 3) xin = uv;
    }
  }
  float sg = 1.f / (1.f + __expf(-acc));
  float val = acc * sg;
  xc[(size_t)row * II + i] = val;
  xc_bf[(size_t)row * II + i] = f2b(val);
  xin_bf[(size_t)row * II + i] = f2b(xin);
  float p[8];
  const float* gci = &Gc[i * 8];
  const float* gvi = &Gv[i * 8];
  #pragma unroll
  for (int o = 0; o < 8; ++o) p[o] = val * gci[o] + xin * gvi[o];
  #pragma unroll
  for (int o = 0; o < 8; ++o)
    #pragma unroll
    for (int d = 1; d < 64; d <<= 1) p[o] += __shfl_xor(p[o], d);
  int wv = i >> 6, lane = i & 63;
  if (lane == 0) {
    #pragma unroll
    for (int o = 0; o < 8; ++o) red[wv][o] = p[o];
  }
  __syncthreads();
  if (i < 8) {
    float sum = red[0][i] + red[1][i] + red[2][i] + red[3][i];
    if (i < 4) ig[((size_t)b * NHH + i) * SS + s] = sum + bi[i];
    else       fg[((size_t)b * NHH + i - 4) * SS + s] = sum + bfp[i - 4];
  }
}

// ---------------------------------------------------------------------------
// masked decay attention — split-precision MFMA, register-prefetch, 2-way
// s-split partials, W-overlay on K LDS tiles (4 barriers/tile).
// ---------------------------------------------------------------------------
__global__ __launch_bounds__(256) void attn_kernel(
    const u16* __restrict__ qkh, const u16* __restrict__ qkl,
    const u16* __restrict__ vhT, const u16* __restrict__ vlT,
    const float* __restrict__ aab, const float* __restrict__ MMb,
    float* __restrict__ pacc, float* __restrict__ pw)
{
  __shared__ u16 KWh[64][64], KWl[64][64];  // K during QK^T, then W for PV
  __shared__ u16 Vh[64][64], Vl[64][64];    // [d][s]
  __shared__ float a_lds[64];
  int tid = threadIdx.x;
  int wv = tid >> 6, lane = tid & 63;
  int lr = lane & 15, lg = lane >> 4;
  int item = blockIdx.x;
  int pp = item >> 5;                     // 0..27, heavy-first
  int tb = 13 - (pp >> 1);
  int part = pp & 1;
  int h = item & 3, b = (item >> 2) & 7;
  int t0 = tb * 64;
  int nt = tb + 1;
  int nt0 = (nt + 1) >> 1;
  int st_begin = part ? nt0 : 0;
  int st_end   = part ? nt : nt0;
  const float* aabh = aab + ((size_t)b * NHH + h) * SS;
  const float* Mbh  = MMb + ((size_t)b * NHH + h) * SS;

  int tq = t0 + wv * 16 + lr; if (tq > SS - 1) tq = SS - 1;
  const u16* qrow_h = qkh + ((size_t)b * SS + tq) * 512 + h * 64;
  const u16* qrow_l = qkl + ((size_t)b * SS + tq) * 512 + h * 64;
  bf16x8 qh0 = *(const bf16x8*)(qrow_h + lg * 8);
  bf16x8 qh1 = *(const bf16x8*)(qrow_h + 32 + lg * 8);
  bf16x8 ql0 = *(const bf16x8*)(qrow_l + lg * 8);
  bf16x8 ql1 = *(const bf16x8*)(qrow_l + 32 + lg * 8);

  float Mt[4];
  #pragma unroll
  for (int r = 0; r < 4; ++r) {
    int t = t0 + wv * 16 + lg * 4 + r; int tc = t < SS ? t : SS - 1;
    Mt[r] = Mbh[tc];
  }

  int row = tid >> 2, seg = tid & 3;
  const u16* vrow_h = vhT + ((size_t)(b * II + h * 64 + row)) * VTS + seg * 16;
  const u16* vrow_l = vlT + ((size_t)(b * II + h * 64 + row)) * VTS + seg * 16;

  f32x4 hacc[4] = {};
  float wsum[4] = {0.f, 0.f, 0.f, 0.f};

  uint4 rk0, rk1, rk2, rk3, rv0, rv1, rv2, rv3;
  float ra = -1e30f;
  if (st_begin < st_end) {
    int sg = st_begin * 64 + row;
    int sc = sg < SS ? sg : SS - 1;
    const u16* kp  = qkh + ((size_t)b * SS + sc) * 512 + 256 + h * 64 + seg * 16;
    const u16* klp = qkl + ((size_t)b * SS + sc) * 512 + 256 + h * 64 + seg * 16;
    rk0 = *(const uint4*)kp;  rk1 = *(const uint4*)(kp + 8);
    rk2 = *(const uint4*)klp; rk3 = *(const uint4*)(klp + 8);
    int sn = st_begin * 64;
    rv0 = *(const uint4*)(vrow_h + sn); rv1 = *(const uint4*)(vrow_h + sn + 8);
    rv2 = *(const uint4*)(vrow_l + sn); rv3 = *(const uint4*)(vrow_l + sn + 8);
    if (tid < 64) ra = (sn + tid < SS) ? aabh[sn + tid] : -1e30f;
  }

  for (int st = st_begin; st < st_end; ++st) {
    int s0 = st * 64;
    __syncthreads();
    *(uint4*)&KWh[row][XCH(row, 2 * seg)]     = rk0;
    *(uint4*)&KWh[row][XCH(row, 2 * seg + 1)] = rk1;
    *(uint4*)&KWl[row][XCH(row, 2 * seg)]     = rk2;
    *(uint4*)&KWl[row][XCH(row, 2 * seg + 1)] = rk3;
    *(uint4*)&Vh[row][XCH(row, 2 * seg)]     = rv0;
    *(uint4*)&Vh[row][XCH(row, 2 * seg + 1)] = rv1;
    *(uint4*)&Vl[row][XCH(row, 2 * seg)]     = rv2;
    *(uint4*)&Vl[row][XCH(row, 2 * seg + 1)] = rv3;
    if (tid < 64) a_lds[tid] = ra;
    if (st + 1 < st_end) {
      int sn = s0 + 64;
      int sg = sn + row;
      int sc = sg < SS ? sg : SS - 1;
      const u16* kp  = qkh + ((size_t)b * SS + sc) * 512 + 256 + h * 64 + seg * 16;
      const u16* klp = qkl + ((size_t)b * SS + sc) * 512 + 256 + h * 64 + seg * 16;
      rk0 = *(const uint4*)kp;  rk1 = *(const uint4*)(kp + 8);
      rk2 = *(const uint4*)klp; rk3 = *(const uint4*)(klp + 8);
      rv0 = *(const uint4*)(vrow_h + sn); rv1 = *(const uint4*)(vrow_h + sn + 8);
      rv2 = *(const uint4*)(vrow_l + sn); rv3 = *(const uint4*)(vrow_l + sn + 8);
      if (tid < 64) ra = (sn + tid < SS) ? aabh[sn + tid] : -1e30f;
    }
    __syncthreads();
    float am = a_lds[lane];
    #pragma unroll
    for (int dd = 1; dd < 64; dd <<= 1) am = fmaxf(am, __shfl_xor(am, dd));
    f32x4 p[4];
    #pragma unroll
    for (int sf = 0; sf < 4; ++sf) {
      int sr = sf * 16 + lr;
      bf16x8 kh0 = *(const bf16x8*)&KWh[sr][XCH(sr, lg)];
      bf16x8 kh1 = *(const bf16x8*)&KWh[sr][XCH(sr, lg + 4)];
      bf16x8 kl0 = *(const bf16x8*)&KWl[sr][XCH(sr, lg)];
      bf16x8 kl1 = *(const bf16x8*)&KWl[sr][XCH(sr, lg + 4)];
      f32x4 acc = {};
      acc = __builtin_amdgcn_mfma_f32_16x16x32_bf16(qh0, kl0, acc, 0, 0, 0);
      acc = __builtin_amdgcn_mfma_f32_16x16x32_bf16(qh1, kl1, acc, 0, 0, 0);
      acc = __builtin_amdgcn_mfma_f32_16x16x32_bf16(ql0, kh0, acc, 0, 0, 0);
      acc = __builtin_amdgcn_mfma_f32_16x16x32_bf16(ql1, kh1, acc, 0, 0, 0);
      acc = __builtin_amdgcn_mfma_f32_16x16x32_bf16(qh0, kh0, acc, 0, 0, 0);
      acc = __builtin_amdgcn_mfma_f32_16x16x32_bf16(qh1, kh1, acc, 0, 0, 0);
      p[sf] = acc;
    }
    __syncthreads();
    float ee[4], ft[4];
    #pragma unroll
    for (int sf = 0; sf < 4; ++sf) ee[sf] = __expf(a_lds[sf * 16 + lr] - am);
    #pragma unroll
    for (int r = 0; r < 4; ++r) ft[r] = __expf(fminf(am - Mt[r], 80.f));
    #pragma unroll
    for (int sf = 0; sf < 4; ++sf) {
      int s = s0 + sf * 16 + lr;
      int sc_ = sf * 2 + (lr >> 3), sb = lr & 7;
      #pragma unroll
      for (int r = 0; r < 4; ++r) {
        int tl_ = wv * 16 + lg * 4 + r;
        int t = t0 + tl_;
        float wval = (s <= t) ? p[sf][r] * ee[sf] * ft[r] : 0.f;
        wsum[r] += wval;
        u16 hi_ = f2b(wval);
        u16 lo_ = f2b(wval - b2f(hi_));
        KWh[tl_][XCH(tl_, sc_) + sb] = hi_;
        KWl[tl_][XCH(tl_, sc_) + sb] = lo_;
      }
    }
    __syncthreads();
    int tr = wv * 16 + lr;
    bf16x8 wh0 = *(const bf16x8*)&KWh[tr][XCH(tr, lg)];
    bf16x8 wh1 = *(const bf16x8*)&KWh[tr][XCH(tr, lg + 4)];
    bf16x8 wl0 = *(const bf16x8*)&KWl[tr][XCH(tr, lg)];
    bf16x8 wl1 = *(const bf16x8*)&KWl[tr][XCH(tr, lg + 4)];
    #pragma unroll
    for (int df = 0; df < 4; ++df) {
      int dr = df * 16 + lr;
      bf16x8 vh0 = *(const bf16x8*)&Vh[dr][XCH(dr, lg)];
      bf16x8 vh1 = *(const bf16x8*)&Vh[dr][XCH(dr, lg + 4)];
      bf16x8 vl0 = *(const bf16x8*)&Vl[dr][XCH(dr, lg)];
      bf16x8 vl1 = *(const bf16x8*)&Vl[dr][XCH(dr, lg + 4)];
      f32x4 a2 = hacc[df];
      a2 = __builtin_amdgcn_mfma_f32_16x16x32_bf16(wh0, vl0, a2, 0, 0, 0);
      a2 = __builtin_amdgcn_mfma_f32_16x16x32_bf16(wh1, vl1, a2, 0, 0, 0);
      a2 = __builtin_amdgcn_mfma_f32_16x16x32_bf16(wl0, vh0, a2, 0, 0, 0);
      a2 = __builtin_amdgcn_mfma_f32_16x16x32_bf16(wl1, vh1, a2, 0, 0, 0);
      a2 = __builtin_amdgcn_mfma_f32_16x16x32_bf16(wh0, vh0, a2, 0, 0, 0);
      a2 = __builtin_amdgcn_mfma_f32_16x16x32_bf16(wh1, vh1, a2, 0, 0, 0);
      hacc[df] = a2;
    }
  }
  #pragma unroll
  for (int r = 0; r < 4; ++r) {
    float sgn = wsum[r];
    sgn += __shfl_xor(sgn, 1); sgn += __shfl_xor(sgn, 2);
    sgn += __shfl_xor(sgn, 4); sgn += __shfl_xor(sgn, 8);
    wsum[r] = sgn;
  }
  float* pa = pacc + (size_t)part * BC * II;
  #pragma unroll
  for (int r = 0; r < 4; ++r) {
    int t = t0 + wv * 16 + lg * 4 + r;
    if (t < SS) {
      #pragma unroll
      for (int df = 0; df < 4; ++df)
        pa[((size_t)b * SS + t) * II + h * 64 + df * 16 + lr] = hacc[df][r];
      if (lr == 0)
        pw[(((size_t)part * BB + b) * NHH + h) * SS + t] = wsum[r];
    }
  }
}

// ---------------------------------------------------------------------------
extern "C" void kernel_launch(void* const* d_in, const int* in_sizes, int n_in,
                              void* d_out, int out_size, void* d_ws, size_t ws_size,
                              hipStream_t stream) {
  const float* xe   = (const float*)d_in[0];
  const float* Ws   = (const float*)d_in[4];
  const float* bs   = (const float*)d_in[5];
  const float* Wt_  = (const float*)d_in[6];
  const float* bt   = (const float*)d_in[7];
  const float* Wp1  = (const float*)d_in[8];
  const float* bp1  = (const float*)d_in[9];
  const float* Wp2  = (const float*)d_in[10];
  const float* bp2  = (const float*)d_in[11];
  const float* lng  = (const float*)d_in[12];
  const float* Wup  = (const float*)d_in[13];
  const float* bup  = (const float*)d_in[14];
  const float* Wcv  = (const float*)d_in[15];
  const float* bcv  = (const float*)d_in[16];
  const float* Wq   = (const float*)d_in[17];
  const float* Wk   = (const float*)d_in[18];
  const float* Wv   = (const float*)d_in[19];
  const float* Wi   = (const float*)d_in[20];
  const float* bi   = (const float*)d_in[21];
  const float* Wf   = (const float*)d_in[22];
  const float* bf_  = (const float*)d_in[23];
  const float* mhg  = (const float*)d_in[24];
  const float* skp  = (const float*)d_in[25];
  const float* Wdn  = (const float*)d_in[26];
  const float* bdn  = (const float*)d_in[27];
  const float* pg   = (const float*)d_in[28];
  float* out = (float*)d_out;

  float* w   = (float*)d_ws;
  float* x   = w;                       // [6896,128]
  float* y   = x   + 882688;
  float* up  = y   + 882688;            // [6896,512]  (aliased by A_head bf16)
  float* xc  = up  + 3530752;           // [6896,256]
  float* pacc = xc + 1765376;           // [2][6896,256] partial attn acc
  float* pw  = pacc + 3530752;          // [2][8][4][862]
  float* ig  = pw  + 55168;
  float* fg  = ig  + 27584;
  float* cum = fg  + 27584;
  float* aab = cum + 27584;
  float* MMb = aab + 27584;
  float* hbias = MMb + 27584;
  float* Gc  = hbias + 128;             // [2][256][8]
  float* Gv  = Gc + 4096;
  u16* ub    = (u16*)(Gv + 4096);
  u16* y_bf  = ub;            ub += 6896 * 128;
  u16* xc_bf = ub;            ub += 6896 * 256;
  u16* xin_bf = ub;           ub += 6896 * 256;
  u16* qkh   = ub;            ub += 6896 * 512;
  u16* qkl   = ub;            ub += 6896 * 512;
  u16* vhT   = ub;            ub += 8 * 256 * VTS;
  u16* vlT   = ub;            ub += 8 * 256 * VTS;
  u16* BTh   = ub;            ub += 131072;
  u16* WupT  = ub;            ub += 131072;
  u16* WqkT  = ub;            ub += 262144;
  u16* WvT   = ub;            ub += 131072;
  u16* WdnT  = ub;            ub += 65536;
  u16* Ah = (u16*)up;                   // A_head aliases up

  // merged weight prep + ta (independent roles, one dispatch)
  prep_ta_kernel<<<2097, 256, 0, stream>>>(
      Wup, Wq, Wk, Wv, Wdn, Ws, Wt_, Wp1, bs, bt, bp1, Wi, Wf, xe,
      WupT, WqkT, WvT, WdnT, BTh, hbias, Gc, Gv, Ah);

  // head: x = A_head @ BTh + hbias, then y_bf = LN(x) with blk0 gains
  gemm_ln<0, 0, 0, 0><<<216, 256, 0, stream>>>(
      Ah, 1024, BTh, 1024, x, hbias, lng, nullptr, y_bf, BC, 1024,
      nullptr, nullptr, nullptr, nullptr, nullptr, nullptr, nullptr, nullptr,
      nullptr, nullptr, nullptr);

  for (int blk = 0; blk < 2; ++blk) {
    gemm_bf16<0><<<dim3(8, 108), 256, 0, stream>>>(
        y_bf, 128, WupT + blk * 65536, 128, up, 512, bup + blk * 512, BC, 512, 128);
    conv_gates_kernel<<<6896, 256, 0, stream>>>(
        up, Wcv + blk * 1024, bcv + blk * 256, Gc + blk * 2048, Gv + blk * 2048,
        bi + blk * 4, bf_ + blk * 4, xc, xc_bf, xin_bf, ig, fg);
    qkv_scan_kernel<<<1328, 256, 0, stream>>>(
        xc_bf, xin_bf, WqkT + blk * 131072, WvT + blk * 65536,
        qkh, qkl, vhT, vlT, fg, ig, cum, aab, MMb);
    attn_kernel<<<NITEMS2, 256, 0, stream>>>(qkh, qkl, vhT, vlT, aab, MMb, pacc, pw);
    // dn GEMM + fused combine/mhln + residual + LN (+ final projection on blk1)
    if (blk == 0)
      gemm_ln<1, 0, 1, 0><<<216, 256, 0, stream>>>(
          nullptr, 0, WdnT, 256, x, bdn, lng + 128, nullptr, y_bf, BC, 256,
          pacc, pw, cum, MMb, up, xc, mhg, skp, nullptr, nullptr, nullptr);
    else
      gemm_ln<1, 0, 1, 1><<<216, 256, 0, stream>>>(
          nullptr, 0, WdnT + 32768, 256, x, bdn + 128, pg, nullptr, nullptr, BC, 256,
          pacc, pw, cum, MMb, up, xc, mhg + 256, skp + 256, Wp2, bp2, out);
  }
}